// Round 5
// baseline (469.020 us; speedup 1.0000x reference)
//
#include <hip/hip_runtime.h>
#include <hip/hip_bf16.h>
#include <stdint.h>

// ---------------------------------------------------------------------------
// PFGAT. R23: k_attn_mfma stall surgery.
//   - All __syncthreads -> {s_waitcnt lgkmcnt(0); s_barrier} (raw): no vmcnt(0)
//     drain, so T14 prefetch loads genuinely stay in flight across barriers
//     (compiler inserts the counted vmcnt at the next ds_write's register dep).
//   - Ks row stride 136 -> 140 el: key-paired reads (rows 2*l16) move from
//     4-way bank conflict (bank step l16*4%32) to 2-way-free (l16*12%32).
//     8.3M conflicts/dispatch expected to drop ~3x.
//   - Unified SM buffer keeps LDS at exactly 28672 B (grid-bound residency=4).
// Rest identical to R22.
// ---------------------------------------------------------------------------

#define BB     4
#define TT     8
#define NN     2048
#define FIN    16
#define HID    128
#define BM     (BB*TT)            // 32 attention slices
#define PROWS  (BM*NN)            // 65536 rows
#define NHEADS 4
#define OUTCH  64
#define OUTF   14
#define NEDGE  32768
#define NEDGEB (NEDGE*BB)         // 131072
#define NNODE  (BB*NN)            // 8192
#define NETOT  (NEDGEB + NNODE)   // 139264 (edges + self loops)

#define TQ     64                 // query tile (rows per block)
#define NTILE  (NN/TQ)            // 32 query tiles per slice
#define KSTR   140                // Ks row stride (el) — conflict-free pairing

typedef __hip_bfloat16 bf16;
typedef __attribute__((ext_vector_type(8))) short bf16x8;   // MFMA A/B frag
typedef __attribute__((ext_vector_type(4))) float f32x4;    // MFMA C/D frag

__device__ __forceinline__ float b2f(bf16 v){ return __bfloat162float(v); }
__device__ __forceinline__ bf16  f2b(float f){ return __float2bfloat16(f); }
__device__ __forceinline__ unsigned short bfbits(float f){
    union { bf16 h; unsigned short u; } cv; cv.h = f2b(f); return cv.u;
}

// raw barrier: LDS visibility (lgkmcnt) + workgroup sync, NO vmcnt drain.
#define BAR() do { \
    asm volatile("s_waitcnt lgkmcnt(0)" ::: "memory"); \
    __builtin_amdgcn_s_barrier(); \
    asm volatile("" ::: "memory"); \
} while (0)

// ---------------------------------------------------------------------------
// K1 (R20): 32 rows/block, 256 threads. LN1 -> K (row-major) + Vt (key-tiled),
// both written as packed u32, fully coalesced.
// ---------------------------------------------------------------------------
__global__ __launch_bounds__(256)
void k_kv(const float* __restrict__ x,
          const float* __restrict__ g1, const float* __restrict__ bb1,
          const float* __restrict__ wk, const float* __restrict__ bk,
          const float* __restrict__ wv, const float* __restrict__ bv,
          int in_off, bf16* __restrict__ K, bf16* __restrict__ Vt)
{
    const int r0 = blockIdx.x * 32;            // first local row of this block
    const int t  = threadIdx.x;

    __shared__ float wk_s[FIN][HID];           // 8 KB
    __shared__ float wv_s[FIN][HID];           // 8 KB
    __shared__ float xr_s[32][FIN+1];          // padded vs bank conflicts
    __shared__ float ln_s[32][FIN+1];

    // stage weights (float4) + x tile
    #pragma unroll
    for (int it = 0; it < 2; ++it){
        const int u = t + it*256;              // 512 float4 = 2048 floats
        ((float4*)wk_s)[u] = ((const float4*)wk)[u];
        ((float4*)wv_s)[u] = ((const float4*)wv)[u];
    }
    #pragma unroll
    for (int it = 0; it < 2; ++it){
        const int u = t + it*256;              // 512 floats = 32 rows x 16
        xr_s[u >> 4][u & 15] = x[(size_t)(r0 + in_off)*FIN + u];
    }
    __syncthreads();

    // LN1 per row (one thread per row)
    if (t < 32){
        float mu = 0.f;
        #pragma unroll
        for (int f = 0; f < FIN; ++f) mu += xr_s[t][f];
        mu *= (1.f/FIN);
        float var = 0.f;
        #pragma unroll
        for (int f = 0; f < FIN; ++f){ float d = xr_s[t][f]-mu; var += d*d; }
        var *= (1.f/FIN);
        const float inv = rsqrtf(var + 1e-5f);
        #pragma unroll
        for (int f = 0; f < FIN; ++f)
            ln_s[t][f] = (xr_s[t][f]-mu)*inv*g1[f] + bb1[f];
    }
    __syncthreads();

    // ---- K: thread covers channel pair hk/hk+1; key varies over passes ----
    {
        const int hk = (t & 63)*2;             // 0..126 even
        const float2 bkv = *(const float2*)&bk[hk];
        #pragma unroll
        for (int pass = 0; pass < 8; ++pass){
            const int key = pass*4 + (t >> 6);
            float a0 = bkv.x, a1 = bkv.y;
            #pragma unroll
            for (int f = 0; f < FIN; ++f){
                const float l = ln_s[key][f];
                const float2 wkv = ((const float2*)&wk_s[f][0])[t & 63];
                a0 += l*wkv.x; a1 += l*wkv.y;
            }
            const unsigned int pk =
                (unsigned int)bfbits(a0) | ((unsigned int)bfbits(a1) << 16);
            *(unsigned int*)(void*)&K[((size_t)(r0 + key))*HID + hk] = pk;
        }
    }

    // ---- V: thread covers key pair kk/kk+1; channel varies over passes ----
    {
        const int slice = r0 >> 11;
        const int kg    = (r0 & (NN-1)) >> 5;  // 32-key group within slice
        const size_t vbase = ((size_t)slice*(NN/32) + kg)*(size_t)HID*32;
        const int kk = (t & 15)*2;
        #pragma unroll
        for (int pass = 0; pass < 8; ++pass){
            const int h = (t >> 4) + 16*pass;
            float a0 = bv[h], a1 = a0;
            #pragma unroll
            for (int f = 0; f < FIN; ++f){
                const float wvf = wv_s[f][h];
                a0 += ln_s[kk  ][f] * wvf;
                a1 += ln_s[kk+1][f] * wvf;
            }
            const unsigned int pk =
                (unsigned int)bfbits(a0) | ((unsigned int)bfbits(a1) << 16);
            *(unsigned int*)(void*)&Vt[vbase + (size_t)h*32 + kk] = pk;
        }
    }
}

// ---------------------------------------------------------------------------
// K2 (MFMA flash, R23): raw barriers + conflict-free Ks stride.
// ---------------------------------------------------------------------------
__global__ __launch_bounds__(256)
void k_attn_mfma(const float* __restrict__ x,
                 const bf16* __restrict__ K, const bf16* __restrict__ Vt,
                 const float* __restrict__ g1, const float* __restrict__ bb1,
                 const float* __restrict__ wq, const float* __restrict__ bq,
                 int slice_off, bf16* __restrict__ CX)
{
    const int tile  = (NTILE-1) - (int)blockIdx.y;   // big tiles first
    const int q0    = tile*TQ;
    const int slice = blockIdx.x + slice_off;
    const int t     = threadIdx.x;
    const int w     = t >> 6;
    const int lane  = t & 63;
    const int quad  = lane >> 4;
    const int l16   = lane & 15;
    const int wr0   = w*16;

    // scale * log2(e) folded into Q so the softmax exp is a bare v_exp_f32.
    const float qscale = 0.08838834764831845f * 1.4426950408889634f;

    __shared__ float xs [TQ][FIN+1];               // 4352 B
    __shared__ __align__(16) bf16 SM[32*KSTR + 128*40 + 4*16*40];  // 24320 B
    bf16* Ks = SM;                                  // [32][KSTR]
    bf16* Vs = SM + 32*KSTR;                        // [128][40]
    bf16* Pb = SM + 32*KSTR + 128*40;               // Ps [4][16][40]
    // overlays (time-multiplexed, barrier-protected):
    bf16 (*wqs)[32] = (bf16(*)[32])(&SM[0]);        // preamble: [128 ch][32 k]
    bf16 (*xsb)[32] = (bf16(*)[32])(&SM[4096]);     // preamble: [64 row][32 k]
    bf16 (*Qv)[136] = (bf16(*)[136])(&SM[0]);       // Q staging + epilogue O

    // ---- issue K/V tile-0 loads immediately (hidden under preamble) ----
    const size_t kb = (size_t)blockIdx.x * NN * HID;
    const size_t vb = (size_t)blockIdx.x * (size_t)(NN/32) * HID*32;
    const bf16* kptr = K  + kb + (size_t)t*8;
    const bf16* vptr = Vt + vb + (size_t)t*8;
    bf16x8 kreg0, kreg1, vreg0, vreg1;
    kreg0 = *(const bf16x8*)(const void*)(kptr);
    kreg1 = *(const bf16x8*)(const void*)(kptr + 2048);
    vreg0 = *(const bf16x8*)(const void*)(vptr);
    vreg1 = *(const bf16x8*)(const void*)(vptr + 2048);

    // ---- stage x (fp32) and wq (bf16, pre-scaled, k-padded to 32) ----
    #pragma unroll
    for (int it = 0; it < 4; ++it){
        const int u = t + it*256;                  // 1024 = 64*16
        xs[u >> 4][u & 15] = x[((size_t)slice*NN + q0)*FIN + u];
    }
    #pragma unroll
    for (int it = 0; it < 8; ++it){
        const int u = t + it*256;                  // 2048 = 16*128
        const int f = u >> 7, ch = u & 127;
        wqs[ch][f] = f2b(wq[u] * qscale);
    }
    {   // zero-pad k = 16..31 of wqs
        const bf16x8 z8 = {0,0,0,0,0,0,0,0};
        const int ch = t >> 1, k0 = 16 + (t & 1)*8;
        *(bf16x8*)(void*)&wqs[ch][k0] = z8;
    }
    BAR();

    // ---- LN1 into xsb (bf16, k-padded) ----
    if (t < TQ){
        float mu = 0.f;
        #pragma unroll
        for (int f = 0; f < FIN; ++f) mu += xs[t][f];
        mu *= (1.f/FIN);
        float var = 0.f;
        #pragma unroll
        for (int f = 0; f < FIN; ++f){ float d = xs[t][f]-mu; var += d*d; }
        var *= (1.f/FIN);
        const float inv = rsqrtf(var + 1e-5f);
        bf16x8 v0, v1;
        #pragma unroll
        for (int f = 0; f < 8; ++f)
            v0[f] = (short)bfbits((xs[t][f]-mu)*inv*g1[f] + bb1[f]);
        #pragma unroll
        for (int f = 0; f < 8; ++f)
            v1[f] = (short)bfbits((xs[t][8+f]-mu)*inv*g1[8+f] + bb1[8+f]);
        const bf16x8 z8 = {0,0,0,0,0,0,0,0};
        *(bf16x8*)(void*)&xsb[t][0]  = v0;
        *(bf16x8*)(void*)&xsb[t][8]  = v1;
        *(bf16x8*)(void*)&xsb[t][16] = z8;
        *(bf16x8*)(void*)&xsb[t][24] = z8;
    }
    BAR();

    // ---- Q projection via MFMA: Qv = (LN1(x) @ wq + bq) * qscale ----
    {
        const bf16x8 af = *(const bf16x8*)(const void*)&xsb[wr0 + l16][quad*8];
        f32x4 Cq[8];
        #pragma unroll
        for (int ct = 0; ct < 8; ++ct){
            const bf16x8 bfv = *(const bf16x8*)(const void*)&wqs[ct*16 + l16][quad*8];
            Cq[ct] = __builtin_amdgcn_mfma_f32_16x16x32_bf16(
                         af, bfv, (f32x4){0.f,0.f,0.f,0.f}, 0, 0, 0);
        }
        BAR();   // all waves done READING wqs/xsb before Qv overwrite
        #pragma unroll
        for (int ct = 0; ct < 8; ++ct){
            const int col = ct*16 + l16;
            const float bqs = bq[col] * qscale;
            #pragma unroll
            for (int r = 0; r < 4; ++r)
                Qv[wr0 + quad*4 + r][col] = f2b(Cq[ct][r] + bqs);
        }
    }
    BAR();   // Qv ready

    bf16x8 qf[4];
    #pragma unroll
    for (int ks = 0; ks < 4; ++ks)
        qf[ks] = *(const bf16x8*)(const void*)&Qv[wr0 + l16][ks*32 + quad*8];
    BAR();   // qf reads done; SM may be overwritten by K/V staging

    f32x4 O[8];
    #pragma unroll
    for (int ct = 0; ct < 8; ++ct) O[ct] = (f32x4){0.f,0.f,0.f,0.f};
    float l_[4] = {0.f,0.f,0.f,0.f};

    const int jend_blk = q0 + TQ - 1;
    const int my_jmax  = q0 + wr0 + 15;
    const int brow = q0 + wr0 + quad*4;

    // precomputed LDS staging addresses (constant across iterations)
    bf16* ksA = &Ks[((t      ) >> 4)*KSTR + ((t      ) & 15)*8];
    bf16* ksB = &Ks[((t + 256) >> 4)*KSTR + ((t + 256) & 15)*8];
    bf16* vsA = &Vs[((t      ) >> 2)*40  + ((t      ) &  3)*8];
    bf16* vsB = &Vs[((t + 256) >> 2)*40  + ((t + 256) &  3)*8];
    const bf16* kr0 = &Ks[(2*l16    )*KSTR + quad*8];
    const bf16* kr1 = &Ks[(2*l16 + 1)*KSTR + quad*8];
    const bf16* vr  = &Vs[l16*40 + quad*8];
    bf16* psw = &Pb[w*640 + (quad*4)*40 + 2*l16];   // packed u32 writes (+r*40)
    const bf16* psr = &Pb[w*640 + l16*40 + quad*8];

    for (int j0 = 0; j0 <= jend_blk; j0 += 32){
        // regs -> LDS (compiler inserts counted vmcnt for the reg deps)
        *(bf16x8*)(void*)ksA = kreg0;
        *(bf16x8*)(void*)ksB = kreg1;
        *(bf16x8*)(void*)vsA = vreg0;
        *(bf16x8*)(void*)vsB = vreg1;
        BAR();

        // issue next tile's loads — stay in flight across compute AND barriers
        if (j0 + 32 <= jend_blk){
            const size_t off = (size_t)(j0 + 32)*128;
            kreg0 = *(const bf16x8*)(const void*)(kptr + off);
            kreg1 = *(const bf16x8*)(const void*)(kptr + off + 2048);
            vreg0 = *(const bf16x8*)(const void*)(vptr + off);
            vreg1 = *(const bf16x8*)(const void*)(vptr + off + 2048);
        }

        if (j0 <= my_jmax){
            f32x4 S0 = (f32x4){0.f,0.f,0.f,0.f}, S1 = S0;
            #pragma unroll
            for (int ks = 0; ks < 4; ++ks){
                const bf16x8 kf0 = *(const bf16x8*)(const void*)(kr0 + ks*32);
                const bf16x8 kf1 = *(const bf16x8*)(const void*)(kr1 + ks*32);
                S0 = __builtin_amdgcn_mfma_f32_16x16x32_bf16(qf[ks], kf0, S0, 0, 0, 0);
                S1 = __builtin_amdgcn_mfma_f32_16x16x32_bf16(qf[ks], kf1, S1, 0, 0, 0);
            }
            // lane's two keys are adjacent: c0 = j0+2*l16, c1 = c0+1
            float sv0[4], sv1[4];
            if (j0 + 31 > q0 + wr0){                 // diagonal block: mask
                const int c0j = j0 + 2*l16, c1j = c0j + 1;
                #pragma unroll
                for (int r = 0; r < 4; ++r){
                    sv0[r] = (c0j <= brow + r) ? S0[r] : -1e30f;
                    sv1[r] = (c1j <= brow + r) ? S1[r] : -1e30f;
                }
            } else {                                  // strictly-lower: no mask
                #pragma unroll
                for (int r = 0; r < 4; ++r){ sv0[r] = S0[r]; sv1[r] = S1[r]; }
            }
            #pragma unroll
            for (int r = 0; r < 4; ++r){
                const float e0 = __builtin_amdgcn_exp2f(sv0[r]);
                const float e1 = __builtin_amdgcn_exp2f(sv1[r]);
                l_[r] += e0 + e1;
                const unsigned int pk =
                    (unsigned int)bfbits(e0) | ((unsigned int)bfbits(e1) << 16);
                *(unsigned int*)(void*)(psw + r*40) = pk;
            }
            const bf16x8 pf = *(const bf16x8*)(const void*)psr;
            #pragma unroll
            for (int ct = 0; ct < 8; ++ct){
                const bf16x8 vf = *(const bf16x8*)(const void*)(vr + ct*16*40);
                O[ct] = __builtin_amdgcn_mfma_f32_16x16x32_bf16(pf, vf, O[ct], 0, 0, 0);
            }
        }
        BAR();
    }

    {
        float inv[4];
        #pragma unroll
        for (int r = 0; r < 4; ++r){
            float rs = l_[r];
            rs += __shfl_xor(rs, 1);
            rs += __shfl_xor(rs, 2);
            rs += __shfl_xor(rs, 4);
            rs += __shfl_xor(rs, 8);
            inv[r] = 1.f/rs;
        }
        #pragma unroll
        for (int ct = 0; ct < 8; ++ct)
        #pragma unroll
        for (int r = 0; r < 4; ++r)
            Qv[wr0 + quad*4 + r][ct*16 + l16] = f2b(O[ct][r]*inv[r]);
    }
    BAR();
    {
        const int row = t >> 2, ch0 = (t & 3)*32;
        bf16* dst = CX + ((size_t)slice*NN + q0 + row)*HID + ch0;
        #pragma unroll
        for (int c = 0; c < 4; ++c)
            *(bf16x8*)(void*)(dst + c*8) =
                *(const bf16x8*)(const void*)&Qv[row][ch0 + c*8];
    }
}

// ---------------------------------------------------------------------------
// K_H1 (R22): B fragments read directly from pre-built bf16 BH1 [128][168].
// ---------------------------------------------------------------------------
__global__ __launch_bounds__(256)
void k_h1(const float* __restrict__ x,
          const bf16* __restrict__ BH1,
          const float* __restrict__ t_bo, const float* __restrict__ skb,
          int slice_off, bf16* __restrict__ CXH1)
{
    const int slice = blockIdx.x + slice_off;
    const int q0    = blockIdx.y * TQ;
    const int t     = threadIdx.x;
    const int w     = t >> 6;
    const int lane  = t & 63;
    const int quad  = lane >> 4;
    const int l16   = lane & 15;
    const int wr0   = w*16;

    __shared__ bf16 Aext[TQ][168];

    {
        const bf16* src = CXH1 + ((size_t)slice*NN + q0)*HID;
        #pragma unroll
        for (int it = 0; it < 4; ++it){
            const int c = t + it*256;
            *(bf16x8*)(void*)&Aext[c>>4][(c&15)*8] =
                *(const bf16x8*)(const void*)(src + c*8);
        }
    }
    #pragma unroll
    for (int it = 0; it < 4; ++it){
        const int u = t + it*256;
        const int row = u >> 4, f = u & 15;
        Aext[row][128 + f] = f2b(x[((size_t)slice*NN + q0 + row)*FIN + f]);
    }
    #pragma unroll
    for (int it = 0; it < 4; ++it){
        const int u = t + it*256;
        Aext[u>>4][144 + (u&15)] = f2b(0.f);
    }
    __syncthreads();

    f32x4 O[8];
    #pragma unroll
    for (int ct = 0; ct < 8; ++ct) O[ct] = (f32x4){0.f,0.f,0.f,0.f};
    #pragma unroll
    for (int ks = 0; ks < 5; ++ks){
        const bf16x8 af = *(const bf16x8*)(const void*)&Aext[wr0 + l16][ks*32 + quad*8];
        #pragma unroll
        for (int ct = 0; ct < 8; ++ct){
            const bf16x8 bf = *(const bf16x8*)(const void*)
                (BH1 + (size_t)(ct*16 + l16)*168 + ks*32 + quad*8);
            O[ct] = __builtin_amdgcn_mfma_f32_16x16x32_bf16(af, bf, O[ct], 0, 0, 0);
        }
    }
    __syncthreads();
    #pragma unroll
    for (int ct = 0; ct < 8; ++ct){
        const int col = ct*16 + l16;
        const float bias = t_bo[col] + skb[col];
        #pragma unroll
        for (int r = 0; r < 4; ++r)
            Aext[wr0 + quad*4 + r][col] = f2b(O[ct][r] + bias);
    }
    __syncthreads();
    {
        const int row = t >> 2, ch0 = (t & 3)*32;
        bf16* dst = CXH1 + ((size_t)slice*NN + q0 + row)*HID + ch0;
        #pragma unroll
        for (int c = 0; c < 4; ++c)
            *(bf16x8*)(void*)(dst + c*8) =
                *(const bf16x8*)(const void*)&Aext[row][ch0 + c*8];
    }
}

// ---------------------------------------------------------------------------
// K_PREP: blocks 0-15: Mt; block 16: vk/vq/sbb; 17-21: bf16 transposed weight
// copies; block 22: BH1; all 32 blocks zero the CSR counter region.
// ---------------------------------------------------------------------------
__global__ __launch_bounds__(256)
void k_prep(const float* __restrict__ s_wq, const float* __restrict__ s_wk,
            const float* __restrict__ bq, const float* __restrict__ bk,
            const float* __restrict__ s_wv, const float* __restrict__ s_wo,
            const float* __restrict__ g1w, const float* __restrict__ w1,
            const float* __restrict__ w2,
            const float* __restrict__ t_wo, const float* __restrict__ skw,
            bf16* __restrict__ Mt, bf16* __restrict__ wvT, bf16* __restrict__ woT,
            bf16* __restrict__ g1wT, bf16* __restrict__ w1T, bf16* __restrict__ w2T,
            bf16* __restrict__ BH1,
            float* __restrict__ vk, float* __restrict__ vq, float* __restrict__ sbb,
            float* __restrict__ zp, int zn)
{
    const int b = blockIdx.x;          // 0..31
    const int t = threadIdx.x;
    for (int u = b*256 + t; u < zn; u += 32*256) zp[u] = 0.f;
    __shared__ float wq_s[HID*HID];    // 64 KB
    __shared__ float wk_s[8][HID];
    if (b < 16){
        for (int u = t; u < HID*HID; u += 256) wq_s[u] = s_wq[u];
        for (int u = t; u < 8*HID;   u += 256) ((float*)wk_s)[u] = s_wk[b*8*HID + u];
        __syncthreads();
        #pragma unroll
        for (int i = 0; i < 4; ++i){
            const int e = t + i*256;
            const int cl = e >> 7, a = e & 127;     // Mt row c = b*8+cl, col a
            float acc = 0.f;
            for (int hh = 0; hh < HID; ++hh) acc += wk_s[cl][hh]*wq_s[a*HID + hh];
            Mt[(size_t)(b*8 + cl)*HID + a] = f2b(acc);
        }
    } else if (b == 16){
        if (t < HID){
            float a1 = 0.f, a2 = 0.f;
            for (int hh = 0; hh < HID; ++hh){
                a1 += bq[hh]*s_wk[t*HID + hh];
                a2 += s_wq[t*HID + hh]*bk[hh];
            }
            vk[t] = a1; vq[t] = a2;
            if (t == 0){
                float s = 0.f;
                for (int hh = 0; hh < HID; ++hh) s += bq[hh]*bk[hh];
                *sbb = s;
            }
        }
    } else if (b == 17){
        for (int u = t; u < HID*HID; u += 256){
            const int c = u >> 7, h = u & 127;
            wvT[h*HID + c] = f2b(s_wv[u]);
        }
    } else if (b == 18){
        for (int u = t; u < HID*HID; u += 256){
            const int c = u >> 7, h = u & 127;
            woT[h*HID + c] = f2b(s_wo[u]);
        }
    } else if (b == 19){
        for (int u = t; u < HID*HID; u += 256){
            const int c = u >> 7, h = u & 127;
            g1wT[h*HID + c] = f2b(g1w[u]);
        }
    } else if (b == 20){
        for (int u = t; u < HID*2*HID; u += 256){
            const int k = u >> 8, n = u & 255;
            w1T[n*HID + k] = f2b(w1[u]);
        }
    } else if (b == 21){
        for (int u = t; u < 2*HID*HID; u += 256){
            const int k = u >> 7, n = u & 127;
            w2T[(size_t)n*2*HID + k] = f2b(w2[u]);
        }
    } else if (b == 22){
        // BH1[c][k]: k<128 -> t_wo[k][c]; 128<=k<144 -> skw[k-128][c]; else 0
        for (int u = t; u < HID*168; u += 256){
            const int c = u / 168, k = u - c*168;
            float v = 0.f;
            if (k < 128)      v = t_wo[k*HID + c];
            else if (k < 144) v = skw[(k-128)*HID + c];
            BH1[u] = f2b(v);
        }
    }
}

// ---------------------------------------------------------------------------
// K3 (R18, MFMA): 16 nodes/block, 256 thr (4 waves).
// ---------------------------------------------------------------------------
__global__ __launch_bounds__(256)
void k_mix(const bf16* __restrict__ H1,
           const float* __restrict__ ln2g, const float* __restrict__ ln2b,
           const bf16* __restrict__ Mt, const bf16* __restrict__ wvT,
           const bf16* __restrict__ woT, const bf16* __restrict__ g1wT,
           const bf16* __restrict__ w1T, const bf16* __restrict__ w2T,
           const float* __restrict__ vk, const float* __restrict__ vq,
           const float* __restrict__ sbbp,
           const float* __restrict__ s_bv, const float* __restrict__ s_bo,
           const float* __restrict__ bm1, const float* __restrict__ bm2,
           const float* __restrict__ ln3g, const float* __restrict__ ln3b,
           const float* __restrict__ g1as, const float* __restrict__ g1ad,
           bf16* __restrict__ hw1, float* __restrict__ als1, float* __restrict__ ald1)
{
    const int blk0 = blockIdx.x * 16;         // first node
    const int bb = blk0 >> 11, s0 = blk0 & (NN-1);
    const int t = threadIdx.x;
    const int w = t >> 6;
    const int lane = t & 63;
    const int quad = lane >> 4;
    const int l16  = lane & 15;

    __shared__ bf16  h1s[16][TT][136];   // 34816 B
    __shared__ bf16  ZA [16][136];       // 4352 B (A staging, reused)
    __shared__ bf16  HLs[16][264];       // 8448 B (MLP hidden)
    __shared__ float Cw [16][128];       // 8192 B (fp32 work)
    __shared__ float ln2gs[HID], ln2bs[HID];
    __shared__ float mu_s[16][TT], inv_s[16][TT];
    __shared__ float ps[16][TT];
    __shared__ float sbq_s[16], mu3[16], inv3[16];

    // ---- S1: stage h1 (bf16) + ln2 params ----
    for (int m = 0; m < TT; ++m){
        const bf16* src = H1 + ((size_t)(bb*TT + m)*NN + s0)*HID;
        const int node = t >> 4, c8 = t & 15;
        *(bf16x8*)(void*)&h1s[node][m][c8*8] =
            *(const bf16x8*)(const void*)(src + (size_t)node*HID + c8*8);
    }
    if (t < HID){ ln2gs[t] = ln2g[t]; ln2bs[t] = ln2b[t]; }
    __syncthreads();

    // ---- S2: LN2 stats (pair of threads per (node,m)) ----
    {
        const int idx = t >> 1, half = t & 1;
        const int node = idx >> 3, m = idx & 7;
        float sum = 0.f, sq = 0.f;
        for (int c = half; c < HID; c += 2){
            const float v = b2f(h1s[node][m][c]);
            sum += v; sq += v*v;
        }
        sum += __shfl_xor(sum, 1); sq += __shfl_xor(sq, 1);
        if (half == 0){
            const float mu = sum*(1.f/HID);
            const float var = sq*(1.f/HID) - mu*mu;
            mu_s[node][m] = mu;
            inv_s[node][m] = rsqrtf(var + 1e-5f);
        }
    }
    __syncthreads();

    // ---- S3: Z7 -> ZA; sbq partial ----
    #pragma unroll
    for (int i = 0; i < 8; ++i){
        const int idx = t + i*256;               // 2048
        const int n = idx >> 7, c = idx & 127;
        const float z = (b2f(h1s[n][7][c]) - mu_s[n][7])*inv_s[n][7]*ln2gs[c] + ln2bs[c];
        ZA[n][c] = f2b(z);
    }
    if (t < 128){
        const int node = t >> 3, l8 = t & 7;
        float sp = 0.f;
        for (int c = l8; c < HID; c += 8){
            const float z = (b2f(h1s[node][7][c]) - mu_s[node][7])*inv_s[node][7]*ln2gs[c] + ln2bs[c];
            sp += vq[c]*z;
        }
        sp += __shfl_xor(sp, 1);
        sp += __shfl_xor(sp, 2);
        sp += __shfl_xor(sp, 4);
        if (l8 == 0) sbq_s[node] = sp;
    }
    __syncthreads();

    // ---- S4: G1 rp = Z7@Mt + vk -> Cw ----
    {
        bf16x8 af[4];
        #pragma unroll
        for (int ks = 0; ks < 4; ++ks)
            af[ks] = *(const bf16x8*)(const void*)&ZA[l16][ks*32 + quad*8];
        __syncthreads();
        f32x4 C0 = (f32x4){0,0,0,0}, C1 = C0;
        #pragma unroll
        for (int ks = 0; ks < 4; ++ks){
            const bf16x8 b0 = *(const bf16x8*)(const void*)(Mt + (size_t)(w*32      + l16)*HID + ks*32 + quad*8);
            const bf16x8 b1 = *(const bf16x8*)(const void*)(Mt + (size_t)(w*32 + 16 + l16)*HID + ks*32 + quad*8);
            C0 = __builtin_amdgcn_mfma_f32_16x16x32_bf16(af[ks], b0, C0, 0, 0, 0);
            C1 = __builtin_amdgcn_mfma_f32_16x16x32_bf16(af[ks], b1, C1, 0, 0, 0);
        }
        const int c0 = w*32 + l16, c1 = c0 + 16;
        #pragma unroll
        for (int r = 0; r < 4; ++r){
            Cw[quad*4 + r][c0] = C0[r] + vk[c0];
            Cw[quad*4 + r][c1] = C1[r] + vk[c1];
        }
    }
    __syncthreads();

    // ---- S5: scr -> ps ----
    {
        const int idx = t >> 1, half = t & 1;
        const int node = idx >> 3, m = idx & 7;
        const float mu = mu_s[node][m], iv = inv_s[node][m];
        float d = 0.f;
        for (int c = half; c < HID; c += 2){
            const float z = (b2f(h1s[node][m][c]) - mu)*iv*ln2gs[c] + ln2bs[c];
            d += Cw[node][c]*z;
        }
        d += __shfl_xor(d, 1);
        if (half == 0)
            ps[node][m] = (d + sbq_s[node] + *sbbp) * 0.08838834764831845f;
    }
    __syncthreads();
    // ---- S6: softmax per node ----
    if (t < 16){
        float mx = -1e30f;
        #pragma unroll
        for (int m = 0; m < TT; ++m) mx = fmaxf(mx, ps[t][m]);
        float p[TT], se = 0.f;
        #pragma unroll
        for (int m = 0; m < TT; ++m){ p[m] = __expf(ps[t][m]-mx); se += p[m]; }
        const float isum = 1.f/se;
        #pragma unroll
        for (int m = 0; m < TT; ++m) ps[t][m] = p[m]*isum;
    }
    __syncthreads();
    // ---- S7: zbar -> ZA ----
    #pragma unroll
    for (int i = 0; i < 8; ++i){
        const int idx = t + i*256;
        const int n = idx >> 7, c = idx & 127;
        const float gc = ln2gs[c], bc = ln2bs[c];
        float acc = 0.f;
        #pragma unroll
        for (int m = 0; m < TT; ++m){
            const float z = (b2f(h1s[n][m][c]) - mu_s[n][m])*inv_s[n][m]*gc + bc;
            acc += ps[n][m]*z;
        }
        ZA[n][c] = f2b(acc);
    }
    __syncthreads();

    // ---- S8: G2 cx2 = ZB@wvT + bv -> ZA ----
    {
        bf16x8 af[4];
        #pragma unroll
        for (int ks = 0; ks < 4; ++ks)
            af[ks] = *(const bf16x8*)(const void*)&ZA[l16][ks*32 + quad*8];
        __syncthreads();
        f32x4 C0 = (f32x4){0,0,0,0}, C1 = C0;
        #pragma unroll
        for (int ks = 0; ks < 4; ++ks){
            const bf16x8 b0 = *(const bf16x8*)(const void*)(wvT + (size_t)(w*32      + l16)*HID + ks*32 + quad*8);
            const bf16x8 b1 = *(const bf16x8*)(const void*)(wvT + (size_t)(w*32 + 16 + l16)*HID + ks*32 + quad*8);
            C0 = __builtin_amdgcn_mfma_f32_16x16x32_bf16(af[ks], b0, C0, 0, 0, 0);
            C1 = __builtin_amdgcn_mfma_f32_16x16x32_bf16(af[ks], b1, C1, 0, 0, 0);
        }
        const int c0 = w*32 + l16, c1 = c0 + 16;
        #pragma unroll
        for (int r = 0; r < 4; ++r){
            ZA[quad*4 + r][c0] = f2b(C0[r] + s_bv[c0]);
            ZA[quad*4 + r][c1] = f2b(C1[r] + s_bv[c1]);
        }
    }
    __syncthreads();

    // ---- S9: G3 h2 = cx2@woT + bo + h1[7] -> Cw ----
    {
        bf16x8 af[4];
        #pragma unroll
        for (int ks = 0; ks < 4; ++ks)
            af[ks] = *(const bf16x8*)(const void*)&ZA[l16][ks*32 + quad*8];
        __syncthreads();
        f32x4 C0 = (f32x4){0,0,0,0}, C1 = C0;
        #pragma unroll
        for (int ks = 0; ks < 4; ++ks){
            const bf16x8 b0 = *(const bf16x8*)(const void*)(woT + (size_t)(w*32      + l16)*HID + ks*32 + quad*8);
            const bf16x8 b1 = *(const bf16x8*)(const void*)(woT + (size_t)(w*32 + 16 + l16)*HID + ks*32 + quad*8);
            C0 = __builtin_amdgcn_mfma_f32_16x16x32_bf16(af[ks], b0, C0, 0, 0, 0);
            C1 = __builtin_amdgcn_mfma_f32_16x16x32_bf16(af[ks], b1, C1, 0, 0, 0);
        }
        const int c0 = w*32 + l16, c1 = c0 + 16;
        #pragma unroll
        for (int r = 0; r < 4; ++r){
            const int node = quad*4 + r;
            Cw[node][c0] = C0[r] + s_bo[c0] + b2f(h1s[node][7][c0]);
            Cw[node][c1] = C1[r] + s_bo[c1] + b2f(h1s[node][7][c1]);
        }
    }
    __syncthreads();

    // ---- S10: LN3 stats (16-lane group per node) ----
    {
        const int node = t >> 4, part = t & 15;
        float sum = 0.f, sq = 0.f;
        for (int c = part; c < HID; c += 16){
            const float v = Cw[node][c];
            sum += v; sq += v*v;
        }
        sum += __shfl_xor(sum, 1); sq += __shfl_xor(sq, 1);
        sum += __shfl_xor(sum, 2); sq += __shfl_xor(sq, 2);
        sum += __shfl_xor(sum, 4); sq += __shfl_xor(sq, 4);
        sum += __shfl_xor(sum, 8); sq += __shfl_xor(sq, 8);
        if (part == 0){
            const float mu = sum*(1.f/HID);
            const float var = sq*(1.f/HID) - mu*mu;
            mu3[node] = mu;
            inv3[node] = rsqrtf(var + 1e-5f);
        }
    }
    __syncthreads();
    // ---- S11: z3 -> ZA ----
    #pragma unroll
    for (int i = 0; i < 8; ++i){
        const int idx = t + i*256;
        const int n = idx >> 7, c = idx & 127;
        ZA[n][c] = f2b((Cw[n][c] - mu3[n])*inv3[n]*ln3g[c] + ln3b[c]);
    }
    __syncthreads();

    // ---- S12: G4 hl = relu(z3@w1T + b1) -> HLs (ncols 256) ----
    {
        bf16x8 af[4];
        #pragma unroll
        for (int ks = 0; ks < 4; ++ks)
            af[ks] = *(const bf16x8*)(const void*)&ZA[l16][ks*32 + quad*8];
        __syncthreads();
        f32x4 C[4];
        #pragma unroll
        for (int u = 0; u < 4; ++u) C[u] = (f32x4){0,0,0,0};
        #pragma unroll
        for (int ks = 0; ks < 4; ++ks){
            #pragma unroll
            for (int u = 0; u < 4; ++u){
                const bf16x8 bfv = *(const bf16x8*)(const void*)
                    (w1T + (size_t)(w*64 + u*16 + l16)*HID + ks*32 + quad*8);
                C[u] = __builtin_amdgcn_mfma_f32_16x16x32_bf16(af[ks], bfv, C[u], 0, 0, 0);
            }
        }
        #pragma unroll
        for (int u = 0; u < 4; ++u){
            const int col = w*64 + u*16 + l16;
            const float bias = bm1[col];
            #pragma unroll
            for (int r = 0; r < 4; ++r)
                HLs[quad*4 + r][col] = f2b(fmaxf(C[u][r] + bias, 0.f));
        }
    }
    __syncthreads();

    // ---- S13: G5 hn = hl@w2T + b2 + h2 -> ZA (k=256) ----
    {
        bf16x8 af[8];
        #pragma unroll
        for (int ks = 0; ks < 8; ++ks)
            af[ks] = *(const bf16x8*)(const void*)&HLs[l16][ks*32 + quad*8];
        __syncthreads();
        f32x4 C0 = (f32x4){0,0,0,0}, C1 = C0;
        #pragma unroll
        for (int ks = 0; ks < 8; ++ks){
            const bf16x8 b0 = *(const bf16x8*)(const void*)(w2T + (size_t)(w*32      + l16)*2*HID + ks*32 + quad*8);
            const bf16x8 b1 = *(const bf16x8*)(const void*)(w2T + (size_t)(w*32 + 16 + l16)*2*HID + ks*32 + quad*8);
            C0 = __builtin_amdgcn_mfma_f32_16x16x32_bf16(af[ks], b0, C0, 0, 0, 0);
            C1 = __builtin_amdgcn_mfma_f32_16x16x32_bf16(af[ks], b1, C1, 0, 0, 0);
        }
        const int c0 = w*32 + l16, c1 = c0 + 16;
        #pragma unroll
        for (int r = 0; r < 4; ++r){
            const int node = quad*4 + r;
            ZA[node][c0] = f2b(C0[r] + bm2[c0] + Cw[node][c0]);
            ZA[node][c1] = f2b(C1[r] + bm2[c1] + Cw[node][c1]);
        }
    }
    __syncthreads();

    // ---- S14: G6 a = hn@g1wT -> Cw ----
    {
        bf16x8 af[4];
        #pragma unroll
        for (int ks = 0; ks < 4; ++ks)
            af[ks] = *(const bf16x8*)(const void*)&ZA[l16][ks*32 + quad*8];
        __syncthreads();
        f32x4 C0 = (f32x4){0,0,0,0}, C1 = C0;
        #pragma unroll
        for (int ks = 0; ks < 4; ++ks){
            const bf16x8 b0 = *(const bf16x8*)(const void*)(g1wT + (size_t)(w*32      + l16)*HID + ks*32 + quad*8);
            const bf16x8 b1 = *(const bf16x8*)(const void*)(g1wT + (size_t)(w*32 + 16 + l16)*HID + ks*32 + quad*8);
            C0 = __builtin_amdgcn_mfma_f32_16x16x32_bf16(af[ks], b0, C0, 0, 0, 0);
            C1 = __builtin_amdgcn_mfma_f32_16x16x32_bf16(af[ks], b1, C1, 0, 0, 0);
        }
        const int c0 = w*32 + l16, c1 = c0 + 16;
        #pragma unroll
        for (int r = 0; r < 4; ++r){
            Cw[quad*4 + r][c0] = C0[r];
            Cw[quad*4 + r][c1] = C1[r];
        }
    }
    __syncthreads();

    // ---- S15: outputs ----
    #pragma unroll
    for (int i = 0; i < 8; ++i){
        const int idx = t + i*256;                // node*128 + c
        hw1[(size_t)blk0*HID + idx] = f2b(((const float*)Cw)[idx]);
    }
    if (t < 64){
        const int node = t >> 2, hd = t & 3;
        float s1 = 0.f, s2 = 0.f;
        for (int j = 0; j < 32; ++j){
            const int c = hd*32 + j;
            const float a = Cw[node][c];
            s1 += a*g1as[c];
            s2 += a*g1ad[c];
        }
        als1[(blk0 + node)*NHEADS + hd] = s1;
        ald1[(blk0 + node)*NHEADS + hd] = s2;
    }
}

// ---------------------------------------------------------------------------
// CSR build (R21): edge list is batch-invariant -> build once.
// ---------------------------------------------------------------------------
__global__ void k_csr_hist(const int* __restrict__ ei, int* __restrict__ cnt)
{
    const int e = blockIdx.x*blockDim.x + threadIdx.x;
    if (e >= NEDGE) return;
    const int s = ei[e], d = ei[NEDGE + e];
    if (s != d) atomicAdd(&cnt[d], 1);
}

__global__ __launch_bounds__(256)
void k_csr_scan(const int* __restrict__ cnt, int* __restrict__ roff)
{
    const int t = threadIdx.x;                 // 256; 8 bins each
    __shared__ int part[256];
    int loc[8]; int s = 0;
    #pragma unroll
    for (int i = 0; i < 8; ++i){ loc[i] = s; s += cnt[t*8 + i]; }
    part[t] = s;
    __syncthreads();
    if (t == 0){
        int acc = 0;
        for (int i = 0; i < 256; ++i){ const int v = part[i]; part[i] = acc; acc += v; }
    }
    __syncthreads();
    const int base_ = part[t];
    #pragma unroll
    for (int i = 0; i < 8; ++i) roff[t*8 + i] = base_ + loc[i];
    if (t == 255) roff[2048] = base_ + s;
}

__global__ void k_csr_scatter(const int* __restrict__ ei, const int* __restrict__ roff,
                              int* __restrict__ fill, int* __restrict__ col)
{
    const int e = blockIdx.x*blockDim.x + threadIdx.x;
    if (e >= NEDGE) return;
    const int s = ei[e], d = ei[NEDGE + e];
    if (s != d){
        const int p = roff[d] + atomicAdd(&fill[d], 1);
        col[p] = s;
    }
}

// ---------------------------------------------------------------------------
// GAT layer 1 gather (R21): one block per (batch,node), 128 thr = channels.
// ---------------------------------------------------------------------------
__global__ __launch_bounds__(128)
void k_gat_gather1(const int* __restrict__ roff, const int* __restrict__ col,
                   const float* __restrict__ als, const float* __restrict__ ald,
                   const bf16* __restrict__ hw, const float* __restrict__ g1b,
                   float* __restrict__ hr)
{
    const int nid = blockIdx.x;                 // 0..NNODE-1
    const int d   = nid & (NN-1);
    const int gb  = nid & ~(NN-1);              // batch node offset
    const int c   = threadIdx.x;                // 0..127
    const int hd  = c >> 5;
    const float ad = ald[nid*NHEADS + hd];

    float accv = 0.f, accd = 0.f;
    const int e0 = roff[d], e1 = roff[d+1];
    int sn = (e0 < e1) ? col[e0] : 0;
    for (int e = e0; e < e1; ++e){
        const int s = sn + gb;
        sn = (e+1 < e1) ? col[e+1] : 0;         // prefetch next col
        float a = als[s*NHEADS + hd] + ad;
        a = a > 0.f ? a : 0.2f*a;
        const float ex = __expf(a);
        accv += ex * b2f(hw[(size_t)s*HID + c]);
        accd += ex;
    }
    {   // self loop
        float a = als[nid*NHEADS + hd] + ad;
        a = a > 0.f ? a : 0.2f*a;
        const float ex = __expf(a);
        accv += ex * b2f(hw[(size_t)nid*HID + c]);
        accd += ex;
    }
    const float v = accv/accd + g1b[c];
    hr[(size_t)nid*HID + c] = v > 0.f ? v : expm1f(v);
}

// ---------------------------------------------------------------------------
// GAT2 linear (R22): 4 nodes/block, wave-per-node, wave-private LDS.
// ---------------------------------------------------------------------------
__global__ __launch_bounds__(256)
void k_gat2_lin(const float* __restrict__ hr,
                const float* __restrict__ W,
                const float* __restrict__ asrc, const float* __restrict__ adst,
                bf16* __restrict__ hw2, float* __restrict__ al2s, float* __restrict__ al2d)
{
    const int wv  = threadIdx.x >> 6;               // node within group
    const int c   = threadIdx.x & 63;
    const int nid = blockIdx.x*4 + wv;
    __shared__ float hrs[4][HID];
    hrs[wv][c]      = hr[(size_t)nid*HID + c];
    hrs[wv][c + 64] = hr[(size_t)nid*HID + c + 64];
    // wave-private: each wave reads only what it wrote; no barrier needed
    float a = 0.f;
    for (int k = 0; k < HID; ++k) a += hrs[wv][k]*W[k*OUTCH + c];
    hw2[(size_t)nid*OUTCH + c] = f2b(a);
    float s1 = a*asrc[c], s2 = a*adst[c];
    #pragma unroll
    for (int off = 32; off > 0; off >>= 1){
        s1 += __shfl_down(s1, off);
        s2 += __shfl_down(s2, off);
    }
    if (c == 0){ al2s[nid] = s1; al2d[nid] = s2; }
}

// ---------------------------------------------------------------------------
// GAT layer 2 gather + final FFN (R21).
// ---------------------------------------------------------------------------
__global__ __launch_bounds__(64)
void k_gat_gather2f(const int* __restrict__ roff, const int* __restrict__ col,
                    const float* __restrict__ als, const float* __restrict__ ald,
                    const bf16* __restrict__ hw2, const float* __restrict__ g2b,
                    const float* __restrict__ fw, const float* __restrict__ fb,
                    float* __restrict__ out)
{
    const int nid = blockIdx.x;
    const int d   = nid & (NN-1);
    const int gb  = nid & ~(NN-1);
    const int c   = threadIdx.x;                // 0..63
    const float ad = ald[nid];

    float accv = 0.f, accd = 0.f;
    const int e0 = roff[d], e1 = roff[d+1];
    int sn = (e0 < e1) ? col[e0] : 0;
    for (int e = e0; e < e1; ++e){
        const int s = sn + gb;
        sn = (e+1 < e1) ? col[e+1] : 0;
        float a = als[s] + ad;
        a = a > 0.f ? a : 0.2f*a;
        const float ex = __expf(a);
        accv += ex * b2f(hw2[(size_t)s*OUTCH + c]);
        accd += ex;
    }
    {   // self loop
        float a = als[nid] + ad;
        a = a > 0.f ? a : 0.2f*a;
        const float ex = __expf(a);
        accv += ex * b2f(hw2[(size_t)nid*OUTCH + c]);
        accd += ex;
    }
    __shared__ float g[OUTCH];
    g[c] = accv/accd + g2b[c];
    __syncthreads();
    if (c < OUTF){
        float o = fb[c];
        #pragma unroll
        for (int k = 0; k < OUTCH; ++k) o += g[k]*fw[k*OUTF + c];
        const int b = nid >> 11, n = nid & (NN-1);
        out[((size_t)b*OUTF + c)*NN + n] = o;
    }
}

// ---------------------------------------------------------------------------
extern "C" void kernel_launch(void* const* d_in, const int* in_sizes, int n_in,
                              void* d_out, int out_size, void* d_ws, size_t ws_size,
                              hipStream_t stream)
{
    const float* x    = (const float*)d_in[0];
    const int*  ei    = (const int*)d_in[1];
    const float* ln1g = (const float*)d_in[2];  const float* ln1b = (const float*)d_in[3];
    const float* t_wq = (const float*)d_in[4];  const float* t_bq = (const float*)d_in[5];
    const float* t_wk = (const float*)d_in[6];  const float* t_bk = (const float*)d_in[7];
    const float* t_wv = (const float*)d_in[8];  const float* t_bv = (const float*)d_in[9];
    const float* t_wo = (const float*)d_in[10]; const float* t_bo = (const float*)d_in[11];
    const float* skw  = (const float*)d_in[12]; const float* skb  = (const float*)d_in[13];
    const float* ln2g = (const float*)d_in[14]; const float* ln2b = (const float*)d_in[15];
    const float* s_wq = (const float*)d_in[16]; const float* s_bq = (const float*)d_in[17];
    const float* s_wk = (const float*)d_in[18]; const float* s_bk = (const float*)d_in[19];
    const float* s_wv = (const float*)d_in[20]; const float* s_bv = (const float*)d_in[21];
    const float* s_wo = (const float*)d_in[22]; const float* s_bo = (const float*)d_in[23];
    const float* ln3g = (const float*)d_in[24]; const float* ln3b = (const float*)d_in[25];
    const float* w1   = (const float*)d_in[26]; const float* b1   = (const float*)d_in[27];
    const float* w2   = (const float*)d_in[28]; const float* b2   = (const float*)d_in[29];
    const float* g1w  = (const float*)d_in[30];
    const float* g1as = (const float*)d_in[31]; const float* g1ad = (const float*)d_in[32];
    const float* g1b  = (const float*)d_in[33];
    const float* g2w  = (const float*)d_in[34];
    const float* g2as = (const float*)d_in[35]; const float* g2ad = (const float*)d_in[36];
    const float* g2b  = (const float*)d_in[37];
    const float* ffw  = (const float*)d_in[38]; const float* ffb  = (const float*)d_in[39];
    float* out = (float*)d_out;

    const size_t MiB = 1024u*1024u;
    const bool wide = ws_size >= 48*MiB;

    char* base = (char*)d_ws;
    bf16 *Kb, *Vtb, *CXH1;
    char* gat_base;
    char* mbase;
    if (wide){
        Kb   = (bf16*)(base + 0*MiB);      // 16 MiB
        Vtb  = (bf16*)(base + 16*MiB);     // 16 MiB
        CXH1 = (bf16*)(base + 32*MiB);     // 16 MiB
        gat_base = base;                   // aliases Kb (dead after attn)
        mbase = base + 13*MiB;             // inside dead Kb, past GAT scratch
    } else {
        CXH1 = (bf16*)(base + 0*MiB);      // 16 MiB
        gat_base = base + 16*MiB;          // ~8 MiB (no aliasing)
        Kb   = (bf16*)(base + 26*MiB);     // 0.5 MiB (one slice)
        Vtb  = (bf16*)(base + 26*MiB + 512u*1024u);
        mbase = base + 27*MiB;
    }
    bf16*  Mt   = (bf16*)mbase;                       // 32 KB
    bf16*  wvT  = (bf16*)(mbase + 32*1024);           // 32 KB
    bf16*  woT  = (bf16*)(mbase + 64*1024);           // 32 KB
    bf16*  g1wT = (bf16*)(mbase + 96*1024);           // 32 KB
    bf16*  w1T  = (bf16*)(mbase + 128*1024);          // 64 KB
    bf16*  w2T  = (bf16*)(mbase + 192*1024);          // 64 KB
    float* vkw  = (float*)(mbase + 256*1024);         // 512 B
    float* vqw  = (float*)(mbase + 256*1024 + 512);   // 512 B
    float* sbb  = (float*)(mbase + 256*1024 + 1024);  // 4 B
    bf16*  BH1  = (bf16*)(mbase + 272*1024);          // 42 KB (128x168 bf16)

    // GAT scratch: CSR counters FIRST (zeroed by k_prep), then CSR + buffers
    char* w = gat_base;
    auto alloc = [&](size_t bytes){ void* p = (void*)w; w += (bytes + 255) & ~(size_t)255; return p; };
    int*   cnt  = (int*)  alloc(2048u*sizeof(int));
    int*   fill = (int*)  alloc(2048u*sizeof(int));
    char*  zend = w;                                   // zero region = cnt+fill
    int*   roff = (int*)  alloc(2049u*sizeof(int));
    int*   col  = (int*)  alloc((size_t)NEDGE*sizeof(int));
    float* hr   = (float*)alloc((size_t)NNODE*HID*sizeof(float));   // 4 MiB
    bf16*  hw1  = (bf16*) alloc((size_t)NNODE*HID*sizeof(bf16));    // 2 MiB
    float* als1 = (float*)alloc((size_t)NNODE*NHEADS*sizeof(float));
    float* ald1 = (float*)alloc((size_t)NNODE*NHEADS*sizeof(float));
    bf16*  hw2  = (bf16*) alloc((size_t)NNODE*OUTCH*sizeof(bf16));  // 1 MiB
    float* als2 = (float*)alloc((size_t)NNODE*sizeof(float));
    float* ald2 = (float*)alloc((size_t)NNODE*sizeof(float));
    const int zero_n = (int)((zend - (char*)cnt)/4);

    // ---- trunk ----
    if (wide){
        k_kv<<<PROWS/32, 256, 0, stream>>>(x, ln1g, ln1b, t_wk, t_bk, t_wv, t_bv, 0, Kb, Vtb);
        k_attn_mfma<<<dim3(BM, NTILE), 256, 0, stream>>>(x, Kb, Vtb, ln1g, ln1b,
                                                         t_wq, t_bq, 0, CXH1);
        // k_prep after attn (writes alias dead Kb), before k_h1 (builds BH1)
        k_prep<<<32, 256, 0, stream>>>(s_wq, s_wk, s_bq, s_bk, s_wv, s_wo, g1w, w1, w2,
                                       t_wo, skw,
                                       Mt, wvT, woT, g1wT, w1T, w2T, BH1,
                                       vkw, vqw, sbb, (float*)cnt, zero_n);
        k_h1<<<dim3(BM, NTILE), 256, 0, stream>>>(x, BH1, t_bo, skb, 0, CXH1);
    } else {
        for (int s = 0; s < BM; ++s){
            k_kv<<<NN/32, 256, 0, stream>>>(x, ln1g, ln1b, t_wk, t_bk, t_wv, t_bv, s*NN, Kb, Vtb);
            k_attn_mfma<<<dim3(1, NTILE), 256, 0, stream>>>(x, Kb, Vtb, ln1g, ln1b,
                                                            t_wq, t_bq, s, CXH1);
        }
        k_prep<<<32, 256, 0, stream>>>(s_wq, s_wk, s_bq, s_bk, s_wv, s_wo, g1w, w1, w2,
                                       t_wo, skw,
                                       Mt, wvT, woT, g1wT, w1T, w2T, BH1,
                                       vkw, vqw, sbb, (float*)cnt, zero_n);
        k_h1<<<dim3(BM, NTILE), 256, 0, stream>>>(x, BH1, t_bo, skb, 0, CXH1);
    }

    // CSR build (cnt/fill zeroed by k_prep; stream-serial ordering)
    k_csr_hist   <<<NEDGE/256, 256, 0, stream>>>(ei, cnt);
    k_csr_scan   <<<1,        256, 0, stream>>>(cnt, roff);
    k_csr_scatter<<<NEDGE/256, 256, 0, stream>>>(ei, roff, fill, col);

    k_mix<<<NNODE/16, 256, 0, stream>>>(CXH1, ln2g, ln2b, Mt, wvT, woT, g1wT, w1T, w2T,
                                        vkw, vqw, sbb, s_bv, s_bo, b1, b2,
                                        ln3g, ln3b, g1as, g1ad, hw1, als1, ald1);

    k_gat_gather1<<<NNODE, 128, 0, stream>>>(roff, col, als1, ald1, hw1, g1b, hr);
    k_gat2_lin   <<<NNODE/4, 256, 0, stream>>>(hr, g2w, g2as, g2ad, hw2, als2, ald2);
    k_gat_gather2f<<<NNODE, 64, 0, stream>>>(roff, col, als2, ald2, hw2, g2b, ffw, ffb, out);
}

// Round 6
// 406.930 us; speedup vs baseline: 1.1526x; 1.1526x over previous
//
#include <hip/hip_runtime.h>
#include <hip/hip_bf16.h>
#include <stdint.h>

// ---------------------------------------------------------------------------
// PFGAT. R24: revert R23's attn changes (KSTR=140 broke 16B alignment of
// ds_*_b128 -> 2x regression; raw barriers confounded). Back to R22 attn
// (74.9us verified), plus ONE safe change: XCD-aware block swizzle for
// k_attn_mfma — each XCD owns 4 slices, so its K/V working set (4MB) is
// L2-resident across all 32 tile iterations (was: all 32 slices = 32MB
// streaming through 4MB L2 -> L3 latency on every K/V load).
// Rest identical to R22.
// ---------------------------------------------------------------------------

#define BB     4
#define TT     8
#define NN     2048
#define FIN    16
#define HID    128
#define BM     (BB*TT)            // 32 attention slices
#define PROWS  (BM*NN)            // 65536 rows
#define NHEADS 4
#define OUTCH  64
#define OUTF   14
#define NEDGE  32768
#define NEDGEB (NEDGE*BB)         // 131072
#define NNODE  (BB*NN)            // 8192
#define NETOT  (NEDGEB + NNODE)   // 139264 (edges + self loops)

#define TQ     64                 // query tile (rows per block)
#define NTILE  (NN/TQ)            // 32 query tiles per slice

typedef __hip_bfloat16 bf16;
typedef __attribute__((ext_vector_type(8))) short bf16x8;   // MFMA A/B frag
typedef __attribute__((ext_vector_type(4))) float f32x4;    // MFMA C/D frag

__device__ __forceinline__ float b2f(bf16 v){ return __bfloat162float(v); }
__device__ __forceinline__ bf16  f2b(float f){ return __float2bfloat16(f); }
__device__ __forceinline__ unsigned short bfbits(float f){
    union { bf16 h; unsigned short u; } cv; cv.h = f2b(f); return cv.u;
}

// ---------------------------------------------------------------------------
// K1 (R20): 32 rows/block, 256 threads. LN1 -> K (row-major) + Vt (key-tiled),
// both written as packed u32, fully coalesced.
// ---------------------------------------------------------------------------
__global__ __launch_bounds__(256)
void k_kv(const float* __restrict__ x,
          const float* __restrict__ g1, const float* __restrict__ bb1,
          const float* __restrict__ wk, const float* __restrict__ bk,
          const float* __restrict__ wv, const float* __restrict__ bv,
          int in_off, bf16* __restrict__ K, bf16* __restrict__ Vt)
{
    const int r0 = blockIdx.x * 32;            // first local row of this block
    const int t  = threadIdx.x;

    __shared__ float wk_s[FIN][HID];           // 8 KB
    __shared__ float wv_s[FIN][HID];           // 8 KB
    __shared__ float xr_s[32][FIN+1];          // padded vs bank conflicts
    __shared__ float ln_s[32][FIN+1];

    // stage weights (float4) + x tile
    #pragma unroll
    for (int it = 0; it < 2; ++it){
        const int u = t + it*256;              // 512 float4 = 2048 floats
        ((float4*)wk_s)[u] = ((const float4*)wk)[u];
        ((float4*)wv_s)[u] = ((const float4*)wv)[u];
    }
    #pragma unroll
    for (int it = 0; it < 2; ++it){
        const int u = t + it*256;              // 512 floats = 32 rows x 16
        xr_s[u >> 4][u & 15] = x[(size_t)(r0 + in_off)*FIN + u];
    }
    __syncthreads();

    // LN1 per row (one thread per row)
    if (t < 32){
        float mu = 0.f;
        #pragma unroll
        for (int f = 0; f < FIN; ++f) mu += xr_s[t][f];
        mu *= (1.f/FIN);
        float var = 0.f;
        #pragma unroll
        for (int f = 0; f < FIN; ++f){ float d = xr_s[t][f]-mu; var += d*d; }
        var *= (1.f/FIN);
        const float inv = rsqrtf(var + 1e-5f);
        #pragma unroll
        for (int f = 0; f < FIN; ++f)
            ln_s[t][f] = (xr_s[t][f]-mu)*inv*g1[f] + bb1[f];
    }
    __syncthreads();

    // ---- K: thread covers channel pair hk/hk+1; key varies over passes ----
    {
        const int hk = (t & 63)*2;             // 0..126 even
        const float2 bkv = *(const float2*)&bk[hk];
        #pragma unroll
        for (int pass = 0; pass < 8; ++pass){
            const int key = pass*4 + (t >> 6);
            float a0 = bkv.x, a1 = bkv.y;
            #pragma unroll
            for (int f = 0; f < FIN; ++f){
                const float l = ln_s[key][f];
                const float2 wkv = ((const float2*)&wk_s[f][0])[t & 63];
                a0 += l*wkv.x; a1 += l*wkv.y;
            }
            const unsigned int pk =
                (unsigned int)bfbits(a0) | ((unsigned int)bfbits(a1) << 16);
            *(unsigned int*)(void*)&K[((size_t)(r0 + key))*HID + hk] = pk;
        }
    }

    // ---- V: thread covers key pair kk/kk+1; channel varies over passes ----
    {
        const int slice = r0 >> 11;
        const int kg    = (r0 & (NN-1)) >> 5;  // 32-key group within slice
        const size_t vbase = ((size_t)slice*(NN/32) + kg)*(size_t)HID*32;
        const int kk = (t & 15)*2;
        #pragma unroll
        for (int pass = 0; pass < 8; ++pass){
            const int h = (t >> 4) + 16*pass;
            float a0 = bv[h], a1 = a0;
            #pragma unroll
            for (int f = 0; f < FIN; ++f){
                const float wvf = wv_s[f][h];
                a0 += ln_s[kk  ][f] * wvf;
                a1 += ln_s[kk+1][f] * wvf;
            }
            const unsigned int pk =
                (unsigned int)bfbits(a0) | ((unsigned int)bfbits(a1) << 16);
            *(unsigned int*)(void*)&Vt[vbase + (size_t)h*32 + kk] = pk;
        }
    }
}

// ---------------------------------------------------------------------------
// K2 (MFMA flash, R24 = R22 + XCD swizzle): Q staged in KVs overlay; 28.4KB.
// Wide mode: 1D grid of BM*NTILE, decode so XCD n owns slices 4n..4n+3
// (K/V working set 4MB = L2-resident). Narrow mode: legacy 2D grid.
// ---------------------------------------------------------------------------
__global__ __launch_bounds__(256)
void k_attn_mfma(const float* __restrict__ x,
                 const bf16* __restrict__ K, const bf16* __restrict__ Vt,
                 const float* __restrict__ g1, const float* __restrict__ bb1,
                 const float* __restrict__ wq, const float* __restrict__ bq,
                 int slice_off, bf16* __restrict__ CX)
{
    int slice, tile, kvslice;
    if (gridDim.y == 1){
        // wide: 1D swizzled. bid%8 = XCD (dispatch round-robin); each XCD
        // sees slices (bid&7)*4 + ((bid>>3)&3); tiles big-first.
        const int bid = (int)blockIdx.x;
        slice   = (bid & 7)*4 + ((bid >> 3) & 3);
        tile    = (NTILE-1) - (bid >> 5);
        kvslice = slice;
    } else {
        tile    = (NTILE-1) - (int)blockIdx.y;
        slice   = (int)blockIdx.x + slice_off;
        kvslice = (int)blockIdx.x;
    }
    const int q0    = tile*TQ;
    const int t     = threadIdx.x;
    const int w     = t >> 6;
    const int lane  = t & 63;
    const int quad  = lane >> 4;
    const int l16   = lane & 15;
    const int wr0   = w*16;

    // scale * log2(e) folded into Q so the softmax exp is a bare v_exp_f32.
    const float qscale = 0.08838834764831845f * 1.4426950408889634f;

    __shared__ float xs [TQ][FIN+1];               // padded: LN1 per-thread reads
    __shared__ bf16  Ps [4][16][40];
    __shared__ __align__(16) bf16 KVs[32*136 + 128*40];   // Ks | Vs (main loop)
    bf16* Ks = KVs;
    bf16* Vs = KVs + 32*136;
    // overlays (time-multiplexed, barrier-protected):
    bf16 (*wqs)[32] = (bf16(*)[32])(&KVs[0]);      // preamble: [128 ch][32 k]
    bf16 (*xsb)[32] = (bf16(*)[32])(&KVs[4096]);   // preamble: [64 row][32 k]
    bf16 (*Qv)[136] = (bf16(*)[136])(&KVs[0]);     // Q staging + epilogue O

    // ---- issue K/V tile-0 loads immediately (hidden under preamble) ----
    const size_t kb = (size_t)kvslice * NN * HID;
    const size_t vb = (size_t)kvslice * (size_t)(NN/32) * HID*32;
    const bf16* kptr = K  + kb + (size_t)t*8;
    const bf16* vptr = Vt + vb + (size_t)t*8;
    bf16x8 kreg0, kreg1, vreg0, vreg1;
    kreg0 = *(const bf16x8*)(const void*)(kptr);
    kreg1 = *(const bf16x8*)(const void*)(kptr + 2048);
    vreg0 = *(const bf16x8*)(const void*)(vptr);
    vreg1 = *(const bf16x8*)(const void*)(vptr + 2048);

    // ---- stage x (fp32) and wq (bf16, pre-scaled, k-padded to 32) ----
    #pragma unroll
    for (int it = 0; it < 4; ++it){
        const int u = t + it*256;                  // 1024 = 64*16
        xs[u >> 4][u & 15] = x[((size_t)slice*NN + q0)*FIN + u];
    }
    #pragma unroll
    for (int it = 0; it < 8; ++it){
        const int u = t + it*256;                  // 2048 = 16*128
        const int f = u >> 7, ch = u & 127;
        wqs[ch][f] = f2b(wq[u] * qscale);
    }
    {   // zero-pad k = 16..31 of wqs
        const bf16x8 z8 = {0,0,0,0,0,0,0,0};
        const int ch = t >> 1, k0 = 16 + (t & 1)*8;
        *(bf16x8*)(void*)&wqs[ch][k0] = z8;
    }
    __syncthreads();

    // ---- LN1 into xsb (bf16, k-padded) ----
    if (t < TQ){
        float mu = 0.f;
        #pragma unroll
        for (int f = 0; f < FIN; ++f) mu += xs[t][f];
        mu *= (1.f/FIN);
        float var = 0.f;
        #pragma unroll
        for (int f = 0; f < FIN; ++f){ float d = xs[t][f]-mu; var += d*d; }
        var *= (1.f/FIN);
        const float inv = rsqrtf(var + 1e-5f);
        bf16x8 v0, v1;
        #pragma unroll
        for (int f = 0; f < 8; ++f)
            v0[f] = (short)bfbits((xs[t][f]-mu)*inv*g1[f] + bb1[f]);
        #pragma unroll
        for (int f = 0; f < 8; ++f)
            v1[f] = (short)bfbits((xs[t][8+f]-mu)*inv*g1[8+f] + bb1[8+f]);
        const bf16x8 z8 = {0,0,0,0,0,0,0,0};
        *(bf16x8*)(void*)&xsb[t][0]  = v0;
        *(bf16x8*)(void*)&xsb[t][8]  = v1;
        *(bf16x8*)(void*)&xsb[t][16] = z8;
        *(bf16x8*)(void*)&xsb[t][24] = z8;
    }
    __syncthreads();

    // ---- Q projection via MFMA: Qv = (LN1(x) @ wq + bq) * qscale ----
    {
        const bf16x8 af = *(const bf16x8*)(const void*)&xsb[wr0 + l16][quad*8];
        f32x4 Cq[8];
        #pragma unroll
        for (int ct = 0; ct < 8; ++ct){
            const bf16x8 bfv = *(const bf16x8*)(const void*)&wqs[ct*16 + l16][quad*8];
            Cq[ct] = __builtin_amdgcn_mfma_f32_16x16x32_bf16(
                         af, bfv, (f32x4){0.f,0.f,0.f,0.f}, 0, 0, 0);
        }
        __syncthreads();   // all waves done READING wqs/xsb before Qv overwrite
        #pragma unroll
        for (int ct = 0; ct < 8; ++ct){
            const int col = ct*16 + l16;
            const float bqs = bq[col] * qscale;
            #pragma unroll
            for (int r = 0; r < 4; ++r)
                Qv[wr0 + quad*4 + r][col] = f2b(Cq[ct][r] + bqs);
        }
    }
    __syncthreads();   // Qv ready

    bf16x8 qf[4];
    #pragma unroll
    for (int ks = 0; ks < 4; ++ks)
        qf[ks] = *(const bf16x8*)(const void*)&Qv[wr0 + l16][ks*32 + quad*8];
    __syncthreads();   // qf reads done; KVs may be overwritten by K/V staging

    f32x4 O[8];
    #pragma unroll
    for (int ct = 0; ct < 8; ++ct) O[ct] = (f32x4){0.f,0.f,0.f,0.f};
    float l_[4] = {0.f,0.f,0.f,0.f};

    const int jend_blk = q0 + TQ - 1;
    const int my_jmax  = q0 + wr0 + 15;
    const int brow = q0 + wr0 + quad*4;

    // precomputed LDS staging addresses (constant across iterations)
    bf16* ksA = &Ks[((t      ) >> 4)*136 + ((t      ) & 15)*8];
    bf16* ksB = &Ks[((t + 256) >> 4)*136 + ((t + 256) & 15)*8];
    bf16* vsA = &Vs[((t      ) >> 2)*40  + ((t      ) &  3)*8];
    bf16* vsB = &Vs[((t + 256) >> 2)*40  + ((t + 256) &  3)*8];
    const bf16* kr0 = &Ks[(2*l16    )*136 + quad*8];
    const bf16* kr1 = &Ks[(2*l16 + 1)*136 + quad*8];
    const bf16* vr  = &Vs[l16*40 + quad*8];

    for (int j0 = 0; j0 <= jend_blk; j0 += 32){
        // regs -> LDS (waits on the loads issued last iteration)
        *(bf16x8*)(void*)ksA = kreg0;
        *(bf16x8*)(void*)ksB = kreg1;
        *(bf16x8*)(void*)vsA = vreg0;
        *(bf16x8*)(void*)vsB = vreg1;
        __syncthreads();

        // issue next tile's loads (T14: in flight across compute + barrier)
        if (j0 + 32 <= jend_blk){
            const size_t off = (size_t)(j0 + 32)*128;
            kreg0 = *(const bf16x8*)(const void*)(kptr + off);
            kreg1 = *(const bf16x8*)(const void*)(kptr + off + 2048);
            vreg0 = *(const bf16x8*)(const void*)(vptr + off);
            vreg1 = *(const bf16x8*)(const void*)(vptr + off + 2048);
        }

        if (j0 <= my_jmax){
            f32x4 S0 = (f32x4){0.f,0.f,0.f,0.f}, S1 = S0;
            #pragma unroll
            for (int ks = 0; ks < 4; ++ks){
                const bf16x8 kf0 = *(const bf16x8*)(const void*)(kr0 + ks*32);
                const bf16x8 kf1 = *(const bf16x8*)(const void*)(kr1 + ks*32);
                S0 = __builtin_amdgcn_mfma_f32_16x16x32_bf16(qf[ks], kf0, S0, 0, 0, 0);
                S1 = __builtin_amdgcn_mfma_f32_16x16x32_bf16(qf[ks], kf1, S1, 0, 0, 0);
            }
            // lane's two keys are adjacent: c0 = j0+2*l16, c1 = c0+1
            float sv0[4], sv1[4];
            if (j0 + 31 > q0 + wr0){                 // diagonal block: mask
                const int c0j = j0 + 2*l16, c1j = c0j + 1;
                #pragma unroll
                for (int r = 0; r < 4; ++r){
                    sv0[r] = (c0j <= brow + r) ? S0[r] : -1e30f;
                    sv1[r] = (c1j <= brow + r) ? S1[r] : -1e30f;
                }
            } else {                                  // strictly-lower: no mask
                #pragma unroll
                for (int r = 0; r < 4; ++r){ sv0[r] = S0[r]; sv1[r] = S1[r]; }
            }
            #pragma unroll
            for (int r = 0; r < 4; ++r){
                const float e0 = __builtin_amdgcn_exp2f(sv0[r]);
                const float e1 = __builtin_amdgcn_exp2f(sv1[r]);
                l_[r] += e0 + e1;
                const unsigned int pk =
                    (unsigned int)bfbits(e0) | ((unsigned int)bfbits(e1) << 16);
                *(unsigned int*)(void*)&Ps[w][quad*4 + r][2*l16] = pk;
            }
            const bf16x8 pf = *(const bf16x8*)(const void*)&Ps[w][l16][quad*8];
            #pragma unroll
            for (int ct = 0; ct < 8; ++ct){
                const bf16x8 vf = *(const bf16x8*)(const void*)(vr + ct*16*40);
                O[ct] = __builtin_amdgcn_mfma_f32_16x16x32_bf16(pf, vf, O[ct], 0, 0, 0);
            }
        }
        __syncthreads();
    }

    {
        float inv[4];
        #pragma unroll
        for (int r = 0; r < 4; ++r){
            float rs = l_[r];
            rs += __shfl_xor(rs, 1);
            rs += __shfl_xor(rs, 2);
            rs += __shfl_xor(rs, 4);
            rs += __shfl_xor(rs, 8);
            inv[r] = 1.f/rs;
        }
        #pragma unroll
        for (int ct = 0; ct < 8; ++ct)
        #pragma unroll
        for (int r = 0; r < 4; ++r)
            Qv[wr0 + quad*4 + r][ct*16 + l16] = f2b(O[ct][r]*inv[r]);
    }
    __syncthreads();
    {
        const int row = t >> 2, ch0 = (t & 3)*32;
        bf16* dst = CX + ((size_t)slice*NN + q0 + row)*HID + ch0;
        #pragma unroll
        for (int c = 0; c < 4; ++c)
            *(bf16x8*)(void*)(dst + c*8) =
                *(const bf16x8*)(const void*)&Qv[row][ch0 + c*8];
    }
}

// ---------------------------------------------------------------------------
// K_H1 (R22): B fragments read directly from pre-built bf16 BH1 [128][168].
// ---------------------------------------------------------------------------
__global__ __launch_bounds__(256)
void k_h1(const float* __restrict__ x,
          const bf16* __restrict__ BH1,
          const float* __restrict__ t_bo, const float* __restrict__ skb,
          int slice_off, bf16* __restrict__ CXH1)
{
    const int slice = blockIdx.x + slice_off;
    const int q0    = blockIdx.y * TQ;
    const int t     = threadIdx.x;
    const int w     = t >> 6;
    const int lane  = t & 63;
    const int quad  = lane >> 4;
    const int l16   = lane & 15;
    const int wr0   = w*16;

    __shared__ bf16 Aext[TQ][168];

    {
        const bf16* src = CXH1 + ((size_t)slice*NN + q0)*HID;
        #pragma unroll
        for (int it = 0; it < 4; ++it){
            const int c = t + it*256;
            *(bf16x8*)(void*)&Aext[c>>4][(c&15)*8] =
                *(const bf16x8*)(const void*)(src + c*8);
        }
    }
    #pragma unroll
    for (int it = 0; it < 4; ++it){
        const int u = t + it*256;
        const int row = u >> 4, f = u & 15;
        Aext[row][128 + f] = f2b(x[((size_t)slice*NN + q0 + row)*FIN + f]);
    }
    #pragma unroll
    for (int it = 0; it < 4; ++it){
        const int u = t + it*256;
        Aext[u>>4][144 + (u&15)] = f2b(0.f);
    }
    __syncthreads();

    f32x4 O[8];
    #pragma unroll
    for (int ct = 0; ct < 8; ++ct) O[ct] = (f32x4){0.f,0.f,0.f,0.f};
    #pragma unroll
    for (int ks = 0; ks < 5; ++ks){
        const bf16x8 af = *(const bf16x8*)(const void*)&Aext[wr0 + l16][ks*32 + quad*8];
        #pragma unroll
        for (int ct = 0; ct < 8; ++ct){
            const bf16x8 bf = *(const bf16x8*)(const void*)
                (BH1 + (size_t)(ct*16 + l16)*168 + ks*32 + quad*8);
            O[ct] = __builtin_amdgcn_mfma_f32_16x16x32_bf16(af, bf, O[ct], 0, 0, 0);
        }
    }
    __syncthreads();
    #pragma unroll
    for (int ct = 0; ct < 8; ++ct){
        const int col = ct*16 + l16;
        const float bias = t_bo[col] + skb[col];
        #pragma unroll
        for (int r = 0; r < 4; ++r)
            Aext[wr0 + quad*4 + r][col] = f2b(O[ct][r] + bias);
    }
    __syncthreads();
    {
        const int row = t >> 2, ch0 = (t & 3)*32;
        bf16* dst = CXH1 + ((size_t)slice*NN + q0 + row)*HID + ch0;
        #pragma unroll
        for (int c = 0; c < 4; ++c)
            *(bf16x8*)(void*)(dst + c*8) =
                *(const bf16x8*)(const void*)&Aext[row][ch0 + c*8];
    }
}

// ---------------------------------------------------------------------------
// K_PREP: blocks 0-15: Mt; block 16: vk/vq/sbb; 17-21: bf16 transposed weight
// copies; block 22: BH1; all 32 blocks zero the CSR counter region.
// ---------------------------------------------------------------------------
__global__ __launch_bounds__(256)
void k_prep(const float* __restrict__ s_wq, const float* __restrict__ s_wk,
            const float* __restrict__ bq, const float* __restrict__ bk,
            const float* __restrict__ s_wv, const float* __restrict__ s_wo,
            const float* __restrict__ g1w, const float* __restrict__ w1,
            const float* __restrict__ w2,
            const float* __restrict__ t_wo, const float* __restrict__ skw,
            bf16* __restrict__ Mt, bf16* __restrict__ wvT, bf16* __restrict__ woT,
            bf16* __restrict__ g1wT, bf16* __restrict__ w1T, bf16* __restrict__ w2T,
            bf16* __restrict__ BH1,
            float* __restrict__ vk, float* __restrict__ vq, float* __restrict__ sbb,
            float* __restrict__ zp, int zn)
{
    const int b = blockIdx.x;          // 0..31
    const int t = threadIdx.x;
    for (int u = b*256 + t; u < zn; u += 32*256) zp[u] = 0.f;
    __shared__ float wq_s[HID*HID];    // 64 KB
    __shared__ float wk_s[8][HID];
    if (b < 16){
        for (int u = t; u < HID*HID; u += 256) wq_s[u] = s_wq[u];
        for (int u = t; u < 8*HID;   u += 256) ((float*)wk_s)[u] = s_wk[b*8*HID + u];
        __syncthreads();
        #pragma unroll
        for (int i = 0; i < 4; ++i){
            const int e = t + i*256;
            const int cl = e >> 7, a = e & 127;     // Mt row c = b*8+cl, col a
            float acc = 0.f;
            for (int hh = 0; hh < HID; ++hh) acc += wk_s[cl][hh]*wq_s[a*HID + hh];
            Mt[(size_t)(b*8 + cl)*HID + a] = f2b(acc);
        }
    } else if (b == 16){
        if (t < HID){
            float a1 = 0.f, a2 = 0.f;
            for (int hh = 0; hh < HID; ++hh){
                a1 += bq[hh]*s_wk[t*HID + hh];
                a2 += s_wq[t*HID + hh]*bk[hh];
            }
            vk[t] = a1; vq[t] = a2;
            if (t == 0){
                float s = 0.f;
                for (int hh = 0; hh < HID; ++hh) s += bq[hh]*bk[hh];
                *sbb = s;
            }
        }
    } else if (b == 17){
        for (int u = t; u < HID*HID; u += 256){
            const int c = u >> 7, h = u & 127;
            wvT[h*HID + c] = f2b(s_wv[u]);
        }
    } else if (b == 18){
        for (int u = t; u < HID*HID; u += 256){
            const int c = u >> 7, h = u & 127;
            woT[h*HID + c] = f2b(s_wo[u]);
        }
    } else if (b == 19){
        for (int u = t; u < HID*HID; u += 256){
            const int c = u >> 7, h = u & 127;
            g1wT[h*HID + c] = f2b(g1w[u]);
        }
    } else if (b == 20){
        for (int u = t; u < HID*2*HID; u += 256){
            const int k = u >> 8, n = u & 255;
            w1T[n*HID + k] = f2b(w1[u]);
        }
    } else if (b == 21){
        for (int u = t; u < 2*HID*HID; u += 256){
            const int k = u >> 7, n = u & 127;
            w2T[(size_t)n*2*HID + k] = f2b(w2[u]);
        }
    } else if (b == 22){
        // BH1[c][k]: k<128 -> t_wo[k][c]; 128<=k<144 -> skw[k-128][c]; else 0
        for (int u = t; u < HID*168; u += 256){
            const int c = u / 168, k = u - c*168;
            float v = 0.f;
            if (k < 128)      v = t_wo[k*HID + c];
            else if (k < 144) v = skw[(k-128)*HID + c];
            BH1[u] = f2b(v);
        }
    }
}

// ---------------------------------------------------------------------------
// K3 (R18, MFMA): 16 nodes/block, 256 thr (4 waves).
// ---------------------------------------------------------------------------
__global__ __launch_bounds__(256)
void k_mix(const bf16* __restrict__ H1,
           const float* __restrict__ ln2g, const float* __restrict__ ln2b,
           const bf16* __restrict__ Mt, const bf16* __restrict__ wvT,
           const bf16* __restrict__ woT, const bf16* __restrict__ g1wT,
           const bf16* __restrict__ w1T, const bf16* __restrict__ w2T,
           const float* __restrict__ vk, const float* __restrict__ vq,
           const float* __restrict__ sbbp,
           const float* __restrict__ s_bv, const float* __restrict__ s_bo,
           const float* __restrict__ bm1, const float* __restrict__ bm2,
           const float* __restrict__ ln3g, const float* __restrict__ ln3b,
           const float* __restrict__ g1as, const float* __restrict__ g1ad,
           bf16* __restrict__ hw1, float* __restrict__ als1, float* __restrict__ ald1)
{
    const int blk0 = blockIdx.x * 16;         // first node
    const int bb = blk0 >> 11, s0 = blk0 & (NN-1);
    const int t = threadIdx.x;
    const int w = t >> 6;
    const int lane = t & 63;
    const int quad = lane >> 4;
    const int l16  = lane & 15;

    __shared__ bf16  h1s[16][TT][136];   // 34816 B
    __shared__ bf16  ZA [16][136];       // 4352 B (A staging, reused)
    __shared__ bf16  HLs[16][264];       // 8448 B (MLP hidden)
    __shared__ float Cw [16][128];       // 8192 B (fp32 work)
    __shared__ float ln2gs[HID], ln2bs[HID];
    __shared__ float mu_s[16][TT], inv_s[16][TT];
    __shared__ float ps[16][TT];
    __shared__ float sbq_s[16], mu3[16], inv3[16];

    // ---- S1: stage h1 (bf16) + ln2 params ----
    for (int m = 0; m < TT; ++m){
        const bf16* src = H1 + ((size_t)(bb*TT + m)*NN + s0)*HID;
        const int node = t >> 4, c8 = t & 15;
        *(bf16x8*)(void*)&h1s[node][m][c8*8] =
            *(const bf16x8*)(const void*)(src + (size_t)node*HID + c8*8);
    }
    if (t < HID){ ln2gs[t] = ln2g[t]; ln2bs[t] = ln2b[t]; }
    __syncthreads();

    // ---- S2: LN2 stats (pair of threads per (node,m)) ----
    {
        const int idx = t >> 1, half = t & 1;
        const int node = idx >> 3, m = idx & 7;
        float sum = 0.f, sq = 0.f;
        for (int c = half; c < HID; c += 2){
            const float v = b2f(h1s[node][m][c]);
            sum += v; sq += v*v;
        }
        sum += __shfl_xor(sum, 1); sq += __shfl_xor(sq, 1);
        if (half == 0){
            const float mu = sum*(1.f/HID);
            const float var = sq*(1.f/HID) - mu*mu;
            mu_s[node][m] = mu;
            inv_s[node][m] = rsqrtf(var + 1e-5f);
        }
    }
    __syncthreads();

    // ---- S3: Z7 -> ZA; sbq partial ----
    #pragma unroll
    for (int i = 0; i < 8; ++i){
        const int idx = t + i*256;               // 2048
        const int n = idx >> 7, c = idx & 127;
        const float z = (b2f(h1s[n][7][c]) - mu_s[n][7])*inv_s[n][7]*ln2gs[c] + ln2bs[c];
        ZA[n][c] = f2b(z);
    }
    if (t < 128){
        const int node = t >> 3, l8 = t & 7;
        float sp = 0.f;
        for (int c = l8; c < HID; c += 8){
            const float z = (b2f(h1s[node][7][c]) - mu_s[node][7])*inv_s[node][7]*ln2gs[c] + ln2bs[c];
            sp += vq[c]*z;
        }
        sp += __shfl_xor(sp, 1);
        sp += __shfl_xor(sp, 2);
        sp += __shfl_xor(sp, 4);
        if (l8 == 0) sbq_s[node] = sp;
    }
    __syncthreads();

    // ---- S4: G1 rp = Z7@Mt + vk -> Cw ----
    {
        bf16x8 af[4];
        #pragma unroll
        for (int ks = 0; ks < 4; ++ks)
            af[ks] = *(const bf16x8*)(const void*)&ZA[l16][ks*32 + quad*8];
        __syncthreads();
        f32x4 C0 = (f32x4){0,0,0,0}, C1 = C0;
        #pragma unroll
        for (int ks = 0; ks < 4; ++ks){
            const bf16x8 b0 = *(const bf16x8*)(const void*)(Mt + (size_t)(w*32      + l16)*HID + ks*32 + quad*8);
            const bf16x8 b1 = *(const bf16x8*)(const void*)(Mt + (size_t)(w*32 + 16 + l16)*HID + ks*32 + quad*8);
            C0 = __builtin_amdgcn_mfma_f32_16x16x32_bf16(af[ks], b0, C0, 0, 0, 0);
            C1 = __builtin_amdgcn_mfma_f32_16x16x32_bf16(af[ks], b1, C1, 0, 0, 0);
        }
        const int c0 = w*32 + l16, c1 = c0 + 16;
        #pragma unroll
        for (int r = 0; r < 4; ++r){
            Cw[quad*4 + r][c0] = C0[r] + vk[c0];
            Cw[quad*4 + r][c1] = C1[r] + vk[c1];
        }
    }
    __syncthreads();

    // ---- S5: scr -> ps ----
    {
        const int idx = t >> 1, half = t & 1;
        const int node = idx >> 3, m = idx & 7;
        const float mu = mu_s[node][m], iv = inv_s[node][m];
        float d = 0.f;
        for (int c = half; c < HID; c += 2){
            const float z = (b2f(h1s[node][m][c]) - mu)*iv*ln2gs[c] + ln2bs[c];
            d += Cw[node][c]*z;
        }
        d += __shfl_xor(d, 1);
        if (half == 0)
            ps[node][m] = (d + sbq_s[node] + *sbbp) * 0.08838834764831845f;
    }
    __syncthreads();
    // ---- S6: softmax per node ----
    if (t < 16){
        float mx = -1e30f;
        #pragma unroll
        for (int m = 0; m < TT; ++m) mx = fmaxf(mx, ps[t][m]);
        float p[TT], se = 0.f;
        #pragma unroll
        for (int m = 0; m < TT; ++m){ p[m] = __expf(ps[t][m]-mx); se += p[m]; }
        const float isum = 1.f/se;
        #pragma unroll
        for (int m = 0; m < TT; ++m) ps[t][m] = p[m]*isum;
    }
    __syncthreads();
    // ---- S7: zbar -> ZA ----
    #pragma unroll
    for (int i = 0; i < 8; ++i){
        const int idx = t + i*256;
        const int n = idx >> 7, c = idx & 127;
        const float gc = ln2gs[c], bc = ln2bs[c];
        float acc = 0.f;
        #pragma unroll
        for (int m = 0; m < TT; ++m){
            const float z = (b2f(h1s[n][m][c]) - mu_s[n][m])*inv_s[n][m]*gc + bc;
            acc += ps[n][m]*z;
        }
        ZA[n][c] = f2b(acc);
    }
    __syncthreads();

    // ---- S8: G2 cx2 = ZB@wvT + bv -> ZA ----
    {
        bf16x8 af[4];
        #pragma unroll
        for (int ks = 0; ks < 4; ++ks)
            af[ks] = *(const bf16x8*)(const void*)&ZA[l16][ks*32 + quad*8];
        __syncthreads();
        f32x4 C0 = (f32x4){0,0,0,0}, C1 = C0;
        #pragma unroll
        for (int ks = 0; ks < 4; ++ks){
            const bf16x8 b0 = *(const bf16x8*)(const void*)(wvT + (size_t)(w*32      + l16)*HID + ks*32 + quad*8);
            const bf16x8 b1 = *(const bf16x8*)(const void*)(wvT + (size_t)(w*32 + 16 + l16)*HID + ks*32 + quad*8);
            C0 = __builtin_amdgcn_mfma_f32_16x16x32_bf16(af[ks], b0, C0, 0, 0, 0);
            C1 = __builtin_amdgcn_mfma_f32_16x16x32_bf16(af[ks], b1, C1, 0, 0, 0);
        }
        const int c0 = w*32 + l16, c1 = c0 + 16;
        #pragma unroll
        for (int r = 0; r < 4; ++r){
            ZA[quad*4 + r][c0] = f2b(C0[r] + s_bv[c0]);
            ZA[quad*4 + r][c1] = f2b(C1[r] + s_bv[c1]);
        }
    }
    __syncthreads();

    // ---- S9: G3 h2 = cx2@woT + bo + h1[7] -> Cw ----
    {
        bf16x8 af[4];
        #pragma unroll
        for (int ks = 0; ks < 4; ++ks)
            af[ks] = *(const bf16x8*)(const void*)&ZA[l16][ks*32 + quad*8];
        __syncthreads();
        f32x4 C0 = (f32x4){0,0,0,0}, C1 = C0;
        #pragma unroll
        for (int ks = 0; ks < 4; ++ks){
            const bf16x8 b0 = *(const bf16x8*)(const void*)(woT + (size_t)(w*32      + l16)*HID + ks*32 + quad*8);
            const bf16x8 b1 = *(const bf16x8*)(const void*)(woT + (size_t)(w*32 + 16 + l16)*HID + ks*32 + quad*8);
            C0 = __builtin_amdgcn_mfma_f32_16x16x32_bf16(af[ks], b0, C0, 0, 0, 0);
            C1 = __builtin_amdgcn_mfma_f32_16x16x32_bf16(af[ks], b1, C1, 0, 0, 0);
        }
        const int c0 = w*32 + l16, c1 = c0 + 16;
        #pragma unroll
        for (int r = 0; r < 4; ++r){
            const int node = quad*4 + r;
            Cw[node][c0] = C0[r] + s_bo[c0] + b2f(h1s[node][7][c0]);
            Cw[node][c1] = C1[r] + s_bo[c1] + b2f(h1s[node][7][c1]);
        }
    }
    __syncthreads();

    // ---- S10: LN3 stats (16-lane group per node) ----
    {
        const int node = t >> 4, part = t & 15;
        float sum = 0.f, sq = 0.f;
        for (int c = part; c < HID; c += 16){
            const float v = Cw[node][c];
            sum += v; sq += v*v;
        }
        sum += __shfl_xor(sum, 1); sq += __shfl_xor(sq, 1);
        sum += __shfl_xor(sum, 2); sq += __shfl_xor(sq, 2);
        sum += __shfl_xor(sum, 4); sq += __shfl_xor(sq, 4);
        sum += __shfl_xor(sum, 8); sq += __shfl_xor(sq, 8);
        if (part == 0){
            const float mu = sum*(1.f/HID);
            const float var = sq*(1.f/HID) - mu*mu;
            mu3[node] = mu;
            inv3[node] = rsqrtf(var + 1e-5f);
        }
    }
    __syncthreads();
    // ---- S11: z3 -> ZA ----
    #pragma unroll
    for (int i = 0; i < 8; ++i){
        const int idx = t + i*256;
        const int n = idx >> 7, c = idx & 127;
        ZA[n][c] = f2b((Cw[n][c] - mu3[n])*inv3[n]*ln3g[c] + ln3b[c]);
    }
    __syncthreads();

    // ---- S12: G4 hl = relu(z3@w1T + b1) -> HLs (ncols 256) ----
    {
        bf16x8 af[4];
        #pragma unroll
        for (int ks = 0; ks < 4; ++ks)
            af[ks] = *(const bf16x8*)(const void*)&ZA[l16][ks*32 + quad*8];
        __syncthreads();
        f32x4 C[4];
        #pragma unroll
        for (int u = 0; u < 4; ++u) C[u] = (f32x4){0,0,0,0};
        #pragma unroll
        for (int ks = 0; ks < 4; ++ks){
            #pragma unroll
            for (int u = 0; u < 4; ++u){
                const bf16x8 bfv = *(const bf16x8*)(const void*)
                    (w1T + (size_t)(w*64 + u*16 + l16)*HID + ks*32 + quad*8);
                C[u] = __builtin_amdgcn_mfma_f32_16x16x32_bf16(af[ks], bfv, C[u], 0, 0, 0);
            }
        }
        #pragma unroll
        for (int u = 0; u < 4; ++u){
            const int col = w*64 + u*16 + l16;
            const float bias = bm1[col];
            #pragma unroll
            for (int r = 0; r < 4; ++r)
                HLs[quad*4 + r][col] = f2b(fmaxf(C[u][r] + bias, 0.f));
        }
    }
    __syncthreads();

    // ---- S13: G5 hn = hl@w2T + b2 + h2 -> ZA (k=256) ----
    {
        bf16x8 af[8];
        #pragma unroll
        for (int ks = 0; ks < 8; ++ks)
            af[ks] = *(const bf16x8*)(const void*)&HLs[l16][ks*32 + quad*8];
        __syncthreads();
        f32x4 C0 = (f32x4){0,0,0,0}, C1 = C0;
        #pragma unroll
        for (int ks = 0; ks < 8; ++ks){
            const bf16x8 b0 = *(const bf16x8*)(const void*)(w2T + (size_t)(w*32      + l16)*2*HID + ks*32 + quad*8);
            const bf16x8 b1 = *(const bf16x8*)(const void*)(w2T + (size_t)(w*32 + 16 + l16)*2*HID + ks*32 + quad*8);
            C0 = __builtin_amdgcn_mfma_f32_16x16x32_bf16(af[ks], b0, C0, 0, 0, 0);
            C1 = __builtin_amdgcn_mfma_f32_16x16x32_bf16(af[ks], b1, C1, 0, 0, 0);
        }
        const int c0 = w*32 + l16, c1 = c0 + 16;
        #pragma unroll
        for (int r = 0; r < 4; ++r){
            const int node = quad*4 + r;
            ZA[node][c0] = f2b(C0[r] + bm2[c0] + Cw[node][c0]);
            ZA[node][c1] = f2b(C1[r] + bm2[c1] + Cw[node][c1]);
        }
    }
    __syncthreads();

    // ---- S14: G6 a = hn@g1wT -> Cw ----
    {
        bf16x8 af[4];
        #pragma unroll
        for (int ks = 0; ks < 4; ++ks)
            af[ks] = *(const bf16x8*)(const void*)&ZA[l16][ks*32 + quad*8];
        __syncthreads();
        f32x4 C0 = (f32x4){0,0,0,0}, C1 = C0;
        #pragma unroll
        for (int ks = 0; ks < 4; ++ks){
            const bf16x8 b0 = *(const bf16x8*)(const void*)(g1wT + (size_t)(w*32      + l16)*HID + ks*32 + quad*8);
            const bf16x8 b1 = *(const bf16x8*)(const void*)(g1wT + (size_t)(w*32 + 16 + l16)*HID + ks*32 + quad*8);
            C0 = __builtin_amdgcn_mfma_f32_16x16x32_bf16(af[ks], b0, C0, 0, 0, 0);
            C1 = __builtin_amdgcn_mfma_f32_16x16x32_bf16(af[ks], b1, C1, 0, 0, 0);
        }
        const int c0 = w*32 + l16, c1 = c0 + 16;
        #pragma unroll
        for (int r = 0; r < 4; ++r){
            Cw[quad*4 + r][c0] = C0[r];
            Cw[quad*4 + r][c1] = C1[r];
        }
    }
    __syncthreads();

    // ---- S15: outputs ----
    #pragma unroll
    for (int i = 0; i < 8; ++i){
        const int idx = t + i*256;                // node*128 + c
        hw1[(size_t)blk0*HID + idx] = f2b(((const float*)Cw)[idx]);
    }
    if (t < 64){
        const int node = t >> 2, hd = t & 3;
        float s1 = 0.f, s2 = 0.f;
        for (int j = 0; j < 32; ++j){
            const int c = hd*32 + j;
            const float a = Cw[node][c];
            s1 += a*g1as[c];
            s2 += a*g1ad[c];
        }
        als1[(blk0 + node)*NHEADS + hd] = s1;
        ald1[(blk0 + node)*NHEADS + hd] = s2;
    }
}

// ---------------------------------------------------------------------------
// CSR build (R21): edge list is batch-invariant -> build once.
// ---------------------------------------------------------------------------
__global__ void k_csr_hist(const int* __restrict__ ei, int* __restrict__ cnt)
{
    const int e = blockIdx.x*blockDim.x + threadIdx.x;
    if (e >= NEDGE) return;
    const int s = ei[e], d = ei[NEDGE + e];
    if (s != d) atomicAdd(&cnt[d], 1);
}

__global__ __launch_bounds__(256)
void k_csr_scan(const int* __restrict__ cnt, int* __restrict__ roff)
{
    const int t = threadIdx.x;                 // 256; 8 bins each
    __shared__ int part[256];
    int loc[8]; int s = 0;
    #pragma unroll
    for (int i = 0; i < 8; ++i){ loc[i] = s; s += cnt[t*8 + i]; }
    part[t] = s;
    __syncthreads();
    if (t == 0){
        int acc = 0;
        for (int i = 0; i < 256; ++i){ const int v = part[i]; part[i] = acc; acc += v; }
    }
    __syncthreads();
    const int base_ = part[t];
    #pragma unroll
    for (int i = 0; i < 8; ++i) roff[t*8 + i] = base_ + loc[i];
    if (t == 255) roff[2048] = base_ + s;
}

__global__ void k_csr_scatter(const int* __restrict__ ei, const int* __restrict__ roff,
                              int* __restrict__ fill, int* __restrict__ col)
{
    const int e = blockIdx.x*blockDim.x + threadIdx.x;
    if (e >= NEDGE) return;
    const int s = ei[e], d = ei[NEDGE + e];
    if (s != d){
        const int p = roff[d] + atomicAdd(&fill[d], 1);
        col[p] = s;
    }
}

// ---------------------------------------------------------------------------
// GAT layer 1 gather (R21): one block per (batch,node), 128 thr = channels.
// ---------------------------------------------------------------------------
__global__ __launch_bounds__(128)
void k_gat_gather1(const int* __restrict__ roff, const int* __restrict__ col,
                   const float* __restrict__ als, const float* __restrict__ ald,
                   const bf16* __restrict__ hw, const float* __restrict__ g1b,
                   float* __restrict__ hr)
{
    const int nid = blockIdx.x;                 // 0..NNODE-1
    const int d   = nid & (NN-1);
    const int gb  = nid & ~(NN-1);              // batch node offset
    const int c   = threadIdx.x;                // 0..127
    const int hd  = c >> 5;
    const float ad = ald[nid*NHEADS + hd];

    float accv = 0.f, accd = 0.f;
    const int e0 = roff[d], e1 = roff[d+1];
    int sn = (e0 < e1) ? col[e0] : 0;
    for (int e = e0; e < e1; ++e){
        const int s = sn + gb;
        sn = (e+1 < e1) ? col[e+1] : 0;         // prefetch next col
        float a = als[s*NHEADS + hd] + ad;
        a = a > 0.f ? a : 0.2f*a;
        const float ex = __expf(a);
        accv += ex * b2f(hw[(size_t)s*HID + c]);
        accd += ex;
    }
    {   // self loop
        float a = als[nid*NHEADS + hd] + ad;
        a = a > 0.f ? a : 0.2f*a;
        const float ex = __expf(a);
        accv += ex * b2f(hw[(size_t)nid*HID + c]);
        accd += ex;
    }
    const float v = accv/accd + g1b[c];
    hr[(size_t)nid*HID + c] = v > 0.f ? v : expm1f(v);
}

// ---------------------------------------------------------------------------
// GAT2 linear (R22): 4 nodes/block, wave-per-node, wave-private LDS.
// ---------------------------------------------------------------------------
__global__ __launch_bounds__(256)
void k_gat2_lin(const float* __restrict__ hr,
                const float* __restrict__ W,
                const float* __restrict__ asrc, const float* __restrict__ adst,
                bf16* __restrict__ hw2, float* __restrict__ al2s, float* __restrict__ al2d)
{
    const int wv  = threadIdx.x >> 6;               // node within group
    const int c   = threadIdx.x & 63;
    const int nid = blockIdx.x*4 + wv;
    __shared__ float hrs[4][HID];
    hrs[wv][c]      = hr[(size_t)nid*HID + c];
    hrs[wv][c + 64] = hr[(size_t)nid*HID + c + 64];
    // wave-private: each wave reads only what it wrote; no barrier needed
    float a = 0.f;
    for (int k = 0; k < HID; ++k) a += hrs[wv][k]*W[k*OUTCH + c];
    hw2[(size_t)nid*OUTCH + c] = f2b(a);
    float s1 = a*asrc[c], s2 = a*adst[c];
    #pragma unroll
    for (int off = 32; off > 0; off >>= 1){
        s1 += __shfl_down(s1, off);
        s2 += __shfl_down(s2, off);
    }
    if (c == 0){ al2s[nid] = s1; al2d[nid] = s2; }
}

// ---------------------------------------------------------------------------
// GAT layer 2 gather + final FFN (R21).
// ---------------------------------------------------------------------------
__global__ __launch_bounds__(64)
void k_gat_gather2f(const int* __restrict__ roff, const int* __restrict__ col,
                    const float* __restrict__ als, const float* __restrict__ ald,
                    const bf16* __restrict__ hw2, const float* __restrict__ g2b,
                    const float* __restrict__ fw, const float* __restrict__ fb,
                    float* __restrict__ out)
{
    const int nid = blockIdx.x;
    const int d   = nid & (NN-1);
    const int gb  = nid & ~(NN-1);
    const int c   = threadIdx.x;                // 0..63
    const float ad = ald[nid];

    float accv = 0.f, accd = 0.f;
    const int e0 = roff[d], e1 = roff[d+1];
    int sn = (e0 < e1) ? col[e0] : 0;
    for (int e = e0; e < e1; ++e){
        const int s = sn + gb;
        sn = (e+1 < e1) ? col[e+1] : 0;
        float a = als[s] + ad;
        a = a > 0.f ? a : 0.2f*a;
        const float ex = __expf(a);
        accv += ex * b2f(hw2[(size_t)s*OUTCH + c]);
        accd += ex;
    }
    {   // self loop
        float a = als[nid] + ad;
        a = a > 0.f ? a : 0.2f*a;
        const float ex = __expf(a);
        accv += ex * b2f(hw2[(size_t)nid*OUTCH + c]);
        accd += ex;
    }
    __shared__ float g[OUTCH];
    g[c] = accv/accd + g2b[c];
    __syncthreads();
    if (c < OUTF){
        float o = fb[c];
        #pragma unroll
        for (int k = 0; k < OUTCH; ++k) o += g[k]*fw[k*OUTF + c];
        const int b = nid >> 11, n = nid & (NN-1);
        out[((size_t)b*OUTF + c)*NN + n] = o;
    }
}

// ---------------------------------------------------------------------------
extern "C" void kernel_launch(void* const* d_in, const int* in_sizes, int n_in,
                              void* d_out, int out_size, void* d_ws, size_t ws_size,
                              hipStream_t stream)
{
    const float* x    = (const float*)d_in[0];
    const int*  ei    = (const int*)d_in[1];
    const float* ln1g = (const float*)d_in[2];  const float* ln1b = (const float*)d_in[3];
    const float* t_wq = (const float*)d_in[4];  const float* t_bq = (const float*)d_in[5];
    const float* t_wk = (const float*)d_in[6];  const float* t_bk = (const float*)d_in[7];
    const float* t_wv = (const float*)d_in[8];  const float* t_bv = (const float*)d_in[9];
    const float* t_wo = (const float*)d_in[10]; const float* t_bo = (const float*)d_in[11];
    const float* skw  = (const float*)d_in[12]; const float* skb  = (const float*)d_in[13];
    const float* ln2g = (const float*)d_in[14]; const float* ln2b = (const float*)d_in[15];
    const float* s_wq = (const float*)d_in[16]; const float* s_bq = (const float*)d_in[17];
    const float* s_wk = (const float*)d_in[18]; const float* s_bk = (const float*)d_in[19];
    const float* s_wv = (const float*)d_in[20]; const float* s_bv = (const float*)d_in[21];
    const float* s_wo = (const float*)d_in[22]; const float* s_bo = (const float*)d_in[23];
    const float* ln3g = (const float*)d_in[24]; const float* ln3b = (const float*)d_in[25];
    const float* w1   = (const float*)d_in[26]; const float* b1   = (const float*)d_in[27];
    const float* w2   = (const float*)d_in[28]; const float* b2   = (const float*)d_in[29];
    const float* g1w  = (const float*)d_in[30];
    const float* g1as = (const float*)d_in[31]; const float* g1ad = (const float*)d_in[32];
    const float* g1b  = (const float*)d_in[33];
    const float* g2w  = (const float*)d_in[34];
    const float* g2as = (const float*)d_in[35]; const float* g2ad = (const float*)d_in[36];
    const float* g2b  = (const float*)d_in[37];
    const float* ffw  = (const float*)d_in[38]; const float* ffb  = (const float*)d_in[39];
    float* out = (float*)d_out;

    const size_t MiB = 1024u*1024u;
    const bool wide = ws_size >= 48*MiB;

    char* base = (char*)d_ws;
    bf16 *Kb, *Vtb, *CXH1;
    char* gat_base;
    char* mbase;
    if (wide){
        Kb   = (bf16*)(base + 0*MiB);      // 16 MiB
        Vtb  = (bf16*)(base + 16*MiB);     // 16 MiB
        CXH1 = (bf16*)(base + 32*MiB);     // 16 MiB
        gat_base = base;                   // aliases Kb (dead after attn)
        mbase = base + 13*MiB;             // inside dead Kb, past GAT scratch
    } else {
        CXH1 = (bf16*)(base + 0*MiB);      // 16 MiB
        gat_base = base + 16*MiB;          // ~8 MiB (no aliasing)
        Kb   = (bf16*)(base + 26*MiB);     // 0.5 MiB (one slice)
        Vtb  = (bf16*)(base + 26*MiB + 512u*1024u);
        mbase = base + 27*MiB;
    }
    bf16*  Mt   = (bf16*)mbase;                       // 32 KB
    bf16*  wvT  = (bf16*)(mbase + 32*1024);           // 32 KB
    bf16*  woT  = (bf16*)(mbase + 64*1024);           // 32 KB
    bf16*  g1wT = (bf16*)(mbase + 96*1024);           // 32 KB
    bf16*  w1T  = (bf16*)(mbase + 128*1024);          // 64 KB
    bf16*  w2T  = (bf16*)(mbase + 192*1024);          // 64 KB
    float* vkw  = (float*)(mbase + 256*1024);         // 512 B
    float* vqw  = (float*)(mbase + 256*1024 + 512);   // 512 B
    float* sbb  = (float*)(mbase + 256*1024 + 1024);  // 4 B
    bf16*  BH1  = (bf16*)(mbase + 272*1024);          // 42 KB (128x168 bf16)

    // GAT scratch: CSR counters FIRST (zeroed by k_prep), then CSR + buffers
    char* w = gat_base;
    auto alloc = [&](size_t bytes){ void* p = (void*)w; w += (bytes + 255) & ~(size_t)255; return p; };
    int*   cnt  = (int*)  alloc(2048u*sizeof(int));
    int*   fill = (int*)  alloc(2048u*sizeof(int));
    char*  zend = w;                                   // zero region = cnt+fill
    int*   roff = (int*)  alloc(2049u*sizeof(int));
    int*   col  = (int*)  alloc((size_t)NEDGE*sizeof(int));
    float* hr   = (float*)alloc((size_t)NNODE*HID*sizeof(float));   // 4 MiB
    bf16*  hw1  = (bf16*) alloc((size_t)NNODE*HID*sizeof(bf16));    // 2 MiB
    float* als1 = (float*)alloc((size_t)NNODE*NHEADS*sizeof(float));
    float* ald1 = (float*)alloc((size_t)NNODE*NHEADS*sizeof(float));
    bf16*  hw2  = (bf16*) alloc((size_t)NNODE*OUTCH*sizeof(bf16));  // 1 MiB
    float* als2 = (float*)alloc((size_t)NNODE*sizeof(float));
    float* ald2 = (float*)alloc((size_t)NNODE*sizeof(float));
    const int zero_n = (int)((zend - (char*)cnt)/4);

    // ---- trunk ----
    if (wide){
        k_kv<<<PROWS/32, 256, 0, stream>>>(x, ln1g, ln1b, t_wk, t_bk, t_wv, t_bv, 0, Kb, Vtb);
        // 1D grid: in-kernel XCD swizzle (gridDim.y==1 selects wide decode)
        k_attn_mfma<<<BM*NTILE, 256, 0, stream>>>(x, Kb, Vtb, ln1g, ln1b,
                                                  t_wq, t_bq, 0, CXH1);
        // k_prep after attn (writes alias dead Kb), before k_h1 (builds BH1)
        k_prep<<<32, 256, 0, stream>>>(s_wq, s_wk, s_bq, s_bk, s_wv, s_wo, g1w, w1, w2,
                                       t_wo, skw,
                                       Mt, wvT, woT, g1wT, w1T, w2T, BH1,
                                       vkw, vqw, sbb, (float*)cnt, zero_n);
        k_h1<<<dim3(BM, NTILE), 256, 0, stream>>>(x, BH1, t_bo, skb, 0, CXH1);
    } else {
        for (int s = 0; s < BM; ++s){
            k_kv<<<NN/32, 256, 0, stream>>>(x, ln1g, ln1b, t_wk, t_bk, t_wv, t_bv, s*NN, Kb, Vtb);
            k_attn_mfma<<<dim3(1, NTILE), 256, 0, stream>>>(x, Kb, Vtb, ln1g, ln1b,
                                                            t_wq, t_bq, s, CXH1);
        }
        k_prep<<<32, 256, 0, stream>>>(s_wq, s_wk, s_bq, s_bk, s_wv, s_wo, g1w, w1, w2,
                                       t_wo, skw,
                                       Mt, wvT, woT, g1wT, w1T, w2T, BH1,
                                       vkw, vqw, sbb, (float*)cnt, zero_n);
        k_h1<<<dim3(BM, NTILE), 256, 0, stream>>>(x, BH1, t_bo, skb, 0, CXH1);
    }

    // CSR build (cnt/fill zeroed by k_prep; stream-serial ordering)
    k_csr_hist   <<<NEDGE/256, 256, 0, stream>>>(ei, cnt);
    k_csr_scan   <<<1,        256, 0, stream>>>(cnt, roff);
    k_csr_scatter<<<NEDGE/256, 256, 0, stream>>>(ei, roff, fill, col);

    k_mix<<<NNODE/16, 256, 0, stream>>>(CXH1, ln2g, ln2b, Mt, wvT, woT, g1wT, w1T, w2T,
                                        vkw, vqw, sbb, s_bv, s_bo, b1, b2,
                                        ln3g, ln3b, g1as, g1ad, hw1, als1, ald1);

    k_gat_gather1<<<NNODE, 128, 0, stream>>>(roff, col, als1, ald1, hw1, g1b, hr);
    k_gat2_lin   <<<NNODE/4, 256, 0, stream>>>(hr, g2w, g2as, g2ad, hw2, als2, ald2);
    k_gat_gather2f<<<NNODE, 64, 0, stream>>>(roff, col, als2, ald2, hw2, g2b, ffw, ffb, out);
}

// Round 7
// 390.145 us; speedup vs baseline: 1.2022x; 1.0430x over previous
//
#include <hip/hip_runtime.h>
#include <hip/hip_bf16.h>
#include <stdint.h>

// ---------------------------------------------------------------------------
// PFGAT. R25: fuse k_gat_gather1 + k_gat2_lin -> k_gat_g1lin (one wave/node):
//   - gather uses u32 bf16-pair loads (G13: no scalar bf16), accumulates two
//     channels per lane; hr row normalized+ELU'd into wave-private LDS;
//   - 128x64 GEMV + asrc/adst reductions in the same wave; hr buffer (4MB
//     write + 4MB read) and one dispatch eliminated.
// attn kept at R24 (74.4us best-known; XCD swizzle retained, neutral-to-+).
// Everything else identical to R24.
// ---------------------------------------------------------------------------

#define BB     4
#define TT     8
#define NN     2048
#define FIN    16
#define HID    128
#define BM     (BB*TT)            // 32 attention slices
#define PROWS  (BM*NN)            // 65536 rows
#define NHEADS 4
#define OUTCH  64
#define OUTF   14
#define NEDGE  32768
#define NEDGEB (NEDGE*BB)         // 131072
#define NNODE  (BB*NN)            // 8192
#define NETOT  (NEDGEB + NNODE)   // 139264 (edges + self loops)

#define TQ     64                 // query tile (rows per block)
#define NTILE  (NN/TQ)            // 32 query tiles per slice

typedef __hip_bfloat16 bf16;
typedef __attribute__((ext_vector_type(8))) short bf16x8;   // MFMA A/B frag
typedef __attribute__((ext_vector_type(4))) float f32x4;    // MFMA C/D frag

__device__ __forceinline__ float b2f(bf16 v){ return __bfloat162float(v); }
__device__ __forceinline__ bf16  f2b(float f){ return __float2bfloat16(f); }
__device__ __forceinline__ unsigned short bfbits(float f){
    union { bf16 h; unsigned short u; } cv; cv.h = f2b(f); return cv.u;
}

// ---------------------------------------------------------------------------
// K1 (R20): 32 rows/block, 256 threads. LN1 -> K (row-major) + Vt (key-tiled),
// both written as packed u32, fully coalesced.
// ---------------------------------------------------------------------------
__global__ __launch_bounds__(256)
void k_kv(const float* __restrict__ x,
          const float* __restrict__ g1, const float* __restrict__ bb1,
          const float* __restrict__ wk, const float* __restrict__ bk,
          const float* __restrict__ wv, const float* __restrict__ bv,
          int in_off, bf16* __restrict__ K, bf16* __restrict__ Vt)
{
    const int r0 = blockIdx.x * 32;            // first local row of this block
    const int t  = threadIdx.x;

    __shared__ float wk_s[FIN][HID];           // 8 KB
    __shared__ float wv_s[FIN][HID];           // 8 KB
    __shared__ float xr_s[32][FIN+1];          // padded vs bank conflicts
    __shared__ float ln_s[32][FIN+1];

    // stage weights (float4) + x tile
    #pragma unroll
    for (int it = 0; it < 2; ++it){
        const int u = t + it*256;              // 512 float4 = 2048 floats
        ((float4*)wk_s)[u] = ((const float4*)wk)[u];
        ((float4*)wv_s)[u] = ((const float4*)wv)[u];
    }
    #pragma unroll
    for (int it = 0; it < 2; ++it){
        const int u = t + it*256;              // 512 floats = 32 rows x 16
        xr_s[u >> 4][u & 15] = x[(size_t)(r0 + in_off)*FIN + u];
    }
    __syncthreads();

    // LN1 per row (one thread per row)
    if (t < 32){
        float mu = 0.f;
        #pragma unroll
        for (int f = 0; f < FIN; ++f) mu += xr_s[t][f];
        mu *= (1.f/FIN);
        float var = 0.f;
        #pragma unroll
        for (int f = 0; f < FIN; ++f){ float d = xr_s[t][f]-mu; var += d*d; }
        var *= (1.f/FIN);
        const float inv = rsqrtf(var + 1e-5f);
        #pragma unroll
        for (int f = 0; f < FIN; ++f)
            ln_s[t][f] = (xr_s[t][f]-mu)*inv*g1[f] + bb1[f];
    }
    __syncthreads();

    // ---- K: thread covers channel pair hk/hk+1; key varies over passes ----
    {
        const int hk = (t & 63)*2;             // 0..126 even
        const float2 bkv = *(const float2*)&bk[hk];
        #pragma unroll
        for (int pass = 0; pass < 8; ++pass){
            const int key = pass*4 + (t >> 6);
            float a0 = bkv.x, a1 = bkv.y;
            #pragma unroll
            for (int f = 0; f < FIN; ++f){
                const float l = ln_s[key][f];
                const float2 wkv = ((const float2*)&wk_s[f][0])[t & 63];
                a0 += l*wkv.x; a1 += l*wkv.y;
            }
            const unsigned int pk =
                (unsigned int)bfbits(a0) | ((unsigned int)bfbits(a1) << 16);
            *(unsigned int*)(void*)&K[((size_t)(r0 + key))*HID + hk] = pk;
        }
    }

    // ---- V: thread covers key pair kk/kk+1; channel varies over passes ----
    {
        const int slice = r0 >> 11;
        const int kg    = (r0 & (NN-1)) >> 5;  // 32-key group within slice
        const size_t vbase = ((size_t)slice*(NN/32) + kg)*(size_t)HID*32;
        const int kk = (t & 15)*2;
        #pragma unroll
        for (int pass = 0; pass < 8; ++pass){
            const int h = (t >> 4) + 16*pass;
            float a0 = bv[h], a1 = a0;
            #pragma unroll
            for (int f = 0; f < FIN; ++f){
                const float wvf = wv_s[f][h];
                a0 += ln_s[kk  ][f] * wvf;
                a1 += ln_s[kk+1][f] * wvf;
            }
            const unsigned int pk =
                (unsigned int)bfbits(a0) | ((unsigned int)bfbits(a1) << 16);
            *(unsigned int*)(void*)&Vt[vbase + (size_t)h*32 + kk] = pk;
        }
    }
}

// ---------------------------------------------------------------------------
// K2 (MFMA flash, R24): Q staged in KVs overlay; XCD-swizzled 1D grid (wide).
// ---------------------------------------------------------------------------
__global__ __launch_bounds__(256)
void k_attn_mfma(const float* __restrict__ x,
                 const bf16* __restrict__ K, const bf16* __restrict__ Vt,
                 const float* __restrict__ g1, const float* __restrict__ bb1,
                 const float* __restrict__ wq, const float* __restrict__ bq,
                 int slice_off, bf16* __restrict__ CX)
{
    int slice, tile, kvslice;
    if (gridDim.y == 1){
        const int bid = (int)blockIdx.x;
        slice   = (bid & 7)*4 + ((bid >> 3) & 3);
        tile    = (NTILE-1) - (bid >> 5);
        kvslice = slice;
    } else {
        tile    = (NTILE-1) - (int)blockIdx.y;
        slice   = (int)blockIdx.x + slice_off;
        kvslice = (int)blockIdx.x;
    }
    const int q0    = tile*TQ;
    const int t     = threadIdx.x;
    const int w     = t >> 6;
    const int lane  = t & 63;
    const int quad  = lane >> 4;
    const int l16   = lane & 15;
    const int wr0   = w*16;

    // scale * log2(e) folded into Q so the softmax exp is a bare v_exp_f32.
    const float qscale = 0.08838834764831845f * 1.4426950408889634f;

    __shared__ float xs [TQ][FIN+1];               // padded: LN1 per-thread reads
    __shared__ bf16  Ps [4][16][40];
    __shared__ __align__(16) bf16 KVs[32*136 + 128*40];   // Ks | Vs (main loop)
    bf16* Ks = KVs;
    bf16* Vs = KVs + 32*136;
    // overlays (time-multiplexed, barrier-protected):
    bf16 (*wqs)[32] = (bf16(*)[32])(&KVs[0]);      // preamble: [128 ch][32 k]
    bf16 (*xsb)[32] = (bf16(*)[32])(&KVs[4096]);   // preamble: [64 row][32 k]
    bf16 (*Qv)[136] = (bf16(*)[136])(&KVs[0]);     // Q staging + epilogue O

    // ---- issue K/V tile-0 loads immediately (hidden under preamble) ----
    const size_t kb = (size_t)kvslice * NN * HID;
    const size_t vb = (size_t)kvslice * (size_t)(NN/32) * HID*32;
    const bf16* kptr = K  + kb + (size_t)t*8;
    const bf16* vptr = Vt + vb + (size_t)t*8;
    bf16x8 kreg0, kreg1, vreg0, vreg1;
    kreg0 = *(const bf16x8*)(const void*)(kptr);
    kreg1 = *(const bf16x8*)(const void*)(kptr + 2048);
    vreg0 = *(const bf16x8*)(const void*)(vptr);
    vreg1 = *(const bf16x8*)(const void*)(vptr + 2048);

    // ---- stage x (fp32) and wq (bf16, pre-scaled, k-padded to 32) ----
    #pragma unroll
    for (int it = 0; it < 4; ++it){
        const int u = t + it*256;                  // 1024 = 64*16
        xs[u >> 4][u & 15] = x[((size_t)slice*NN + q0)*FIN + u];
    }
    #pragma unroll
    for (int it = 0; it < 8; ++it){
        const int u = t + it*256;                  // 2048 = 16*128
        const int f = u >> 7, ch = u & 127;
        wqs[ch][f] = f2b(wq[u] * qscale);
    }
    {   // zero-pad k = 16..31 of wqs
        const bf16x8 z8 = {0,0,0,0,0,0,0,0};
        const int ch = t >> 1, k0 = 16 + (t & 1)*8;
        *(bf16x8*)(void*)&wqs[ch][k0] = z8;
    }
    __syncthreads();

    // ---- LN1 into xsb (bf16, k-padded) ----
    if (t < TQ){
        float mu = 0.f;
        #pragma unroll
        for (int f = 0; f < FIN; ++f) mu += xs[t][f];
        mu *= (1.f/FIN);
        float var = 0.f;
        #pragma unroll
        for (int f = 0; f < FIN; ++f){ float d = xs[t][f]-mu; var += d*d; }
        var *= (1.f/FIN);
        const float inv = rsqrtf(var + 1e-5f);
        bf16x8 v0, v1;
        #pragma unroll
        for (int f = 0; f < 8; ++f)
            v0[f] = (short)bfbits((xs[t][f]-mu)*inv*g1[f] + bb1[f]);
        #pragma unroll
        for (int f = 0; f < 8; ++f)
            v1[f] = (short)bfbits((xs[t][8+f]-mu)*inv*g1[8+f] + bb1[8+f]);
        const bf16x8 z8 = {0,0,0,0,0,0,0,0};
        *(bf16x8*)(void*)&xsb[t][0]  = v0;
        *(bf16x8*)(void*)&xsb[t][8]  = v1;
        *(bf16x8*)(void*)&xsb[t][16] = z8;
        *(bf16x8*)(void*)&xsb[t][24] = z8;
    }
    __syncthreads();

    // ---- Q projection via MFMA: Qv = (LN1(x) @ wq + bq) * qscale ----
    {
        const bf16x8 af = *(const bf16x8*)(const void*)&xsb[wr0 + l16][quad*8];
        f32x4 Cq[8];
        #pragma unroll
        for (int ct = 0; ct < 8; ++ct){
            const bf16x8 bfv = *(const bf16x8*)(const void*)&wqs[ct*16 + l16][quad*8];
            Cq[ct] = __builtin_amdgcn_mfma_f32_16x16x32_bf16(
                         af, bfv, (f32x4){0.f,0.f,0.f,0.f}, 0, 0, 0);
        }
        __syncthreads();   // all waves done READING wqs/xsb before Qv overwrite
        #pragma unroll
        for (int ct = 0; ct < 8; ++ct){
            const int col = ct*16 + l16;
            const float bqs = bq[col] * qscale;
            #pragma unroll
            for (int r = 0; r < 4; ++r)
                Qv[wr0 + quad*4 + r][col] = f2b(Cq[ct][r] + bqs);
        }
    }
    __syncthreads();   // Qv ready

    bf16x8 qf[4];
    #pragma unroll
    for (int ks = 0; ks < 4; ++ks)
        qf[ks] = *(const bf16x8*)(const void*)&Qv[wr0 + l16][ks*32 + quad*8];
    __syncthreads();   // qf reads done; KVs may be overwritten by K/V staging

    f32x4 O[8];
    #pragma unroll
    for (int ct = 0; ct < 8; ++ct) O[ct] = (f32x4){0.f,0.f,0.f,0.f};
    float l_[4] = {0.f,0.f,0.f,0.f};

    const int jend_blk = q0 + TQ - 1;
    const int my_jmax  = q0 + wr0 + 15;
    const int brow = q0 + wr0 + quad*4;

    // precomputed LDS staging addresses (constant across iterations)
    bf16* ksA = &Ks[((t      ) >> 4)*136 + ((t      ) & 15)*8];
    bf16* ksB = &Ks[((t + 256) >> 4)*136 + ((t + 256) & 15)*8];
    bf16* vsA = &Vs[((t      ) >> 2)*40  + ((t      ) &  3)*8];
    bf16* vsB = &Vs[((t + 256) >> 2)*40  + ((t + 256) &  3)*8];
    const bf16* kr0 = &Ks[(2*l16    )*136 + quad*8];
    const bf16* kr1 = &Ks[(2*l16 + 1)*136 + quad*8];
    const bf16* vr  = &Vs[l16*40 + quad*8];

    for (int j0 = 0; j0 <= jend_blk; j0 += 32){
        // regs -> LDS (waits on the loads issued last iteration)
        *(bf16x8*)(void*)ksA = kreg0;
        *(bf16x8*)(void*)ksB = kreg1;
        *(bf16x8*)(void*)vsA = vreg0;
        *(bf16x8*)(void*)vsB = vreg1;
        __syncthreads();

        // issue next tile's loads (T14: in flight across compute + barrier)
        if (j0 + 32 <= jend_blk){
            const size_t off = (size_t)(j0 + 32)*128;
            kreg0 = *(const bf16x8*)(const void*)(kptr + off);
            kreg1 = *(const bf16x8*)(const void*)(kptr + off + 2048);
            vreg0 = *(const bf16x8*)(const void*)(vptr + off);
            vreg1 = *(const bf16x8*)(const void*)(vptr + off + 2048);
        }

        if (j0 <= my_jmax){
            f32x4 S0 = (f32x4){0.f,0.f,0.f,0.f}, S1 = S0;
            #pragma unroll
            for (int ks = 0; ks < 4; ++ks){
                const bf16x8 kf0 = *(const bf16x8*)(const void*)(kr0 + ks*32);
                const bf16x8 kf1 = *(const bf16x8*)(const void*)(kr1 + ks*32);
                S0 = __builtin_amdgcn_mfma_f32_16x16x32_bf16(qf[ks], kf0, S0, 0, 0, 0);
                S1 = __builtin_amdgcn_mfma_f32_16x16x32_bf16(qf[ks], kf1, S1, 0, 0, 0);
            }
            // lane's two keys are adjacent: c0 = j0+2*l16, c1 = c0+1
            float sv0[4], sv1[4];
            if (j0 + 31 > q0 + wr0){                 // diagonal block: mask
                const int c0j = j0 + 2*l16, c1j = c0j + 1;
                #pragma unroll
                for (int r = 0; r < 4; ++r){
                    sv0[r] = (c0j <= brow + r) ? S0[r] : -1e30f;
                    sv1[r] = (c1j <= brow + r) ? S1[r] : -1e30f;
                }
            } else {                                  // strictly-lower: no mask
                #pragma unroll
                for (int r = 0; r < 4; ++r){ sv0[r] = S0[r]; sv1[r] = S1[r]; }
            }
            #pragma unroll
            for (int r = 0; r < 4; ++r){
                const float e0 = __builtin_amdgcn_exp2f(sv0[r]);
                const float e1 = __builtin_amdgcn_exp2f(sv1[r]);
                l_[r] += e0 + e1;
                const unsigned int pk =
                    (unsigned int)bfbits(e0) | ((unsigned int)bfbits(e1) << 16);
                *(unsigned int*)(void*)&Ps[w][quad*4 + r][2*l16] = pk;
            }
            const bf16x8 pf = *(const bf16x8*)(const void*)&Ps[w][l16][quad*8];
            #pragma unroll
            for (int ct = 0; ct < 8; ++ct){
                const bf16x8 vf = *(const bf16x8*)(const void*)(vr + ct*16*40);
                O[ct] = __builtin_amdgcn_mfma_f32_16x16x32_bf16(pf, vf, O[ct], 0, 0, 0);
            }
        }
        __syncthreads();
    }

    {
        float inv[4];
        #pragma unroll
        for (int r = 0; r < 4; ++r){
            float rs = l_[r];
            rs += __shfl_xor(rs, 1);
            rs += __shfl_xor(rs, 2);
            rs += __shfl_xor(rs, 4);
            rs += __shfl_xor(rs, 8);
            inv[r] = 1.f/rs;
        }
        #pragma unroll
        for (int ct = 0; ct < 8; ++ct)
        #pragma unroll
        for (int r = 0; r < 4; ++r)
            Qv[wr0 + quad*4 + r][ct*16 + l16] = f2b(O[ct][r]*inv[r]);
    }
    __syncthreads();
    {
        const int row = t >> 2, ch0 = (t & 3)*32;
        bf16* dst = CX + ((size_t)slice*NN + q0 + row)*HID + ch0;
        #pragma unroll
        for (int c = 0; c < 4; ++c)
            *(bf16x8*)(void*)(dst + c*8) =
                *(const bf16x8*)(const void*)&Qv[row][ch0 + c*8];
    }
}

// ---------------------------------------------------------------------------
// K_H1 (R22): B fragments read directly from pre-built bf16 BH1 [128][168].
// ---------------------------------------------------------------------------
__global__ __launch_bounds__(256)
void k_h1(const float* __restrict__ x,
          const bf16* __restrict__ BH1,
          const float* __restrict__ t_bo, const float* __restrict__ skb,
          int slice_off, bf16* __restrict__ CXH1)
{
    const int slice = blockIdx.x + slice_off;
    const int q0    = blockIdx.y * TQ;
    const int t     = threadIdx.x;
    const int w     = t >> 6;
    const int lane  = t & 63;
    const int quad  = lane >> 4;
    const int l16   = lane & 15;
    const int wr0   = w*16;

    __shared__ bf16 Aext[TQ][168];

    {
        const bf16* src = CXH1 + ((size_t)slice*NN + q0)*HID;
        #pragma unroll
        for (int it = 0; it < 4; ++it){
            const int c = t + it*256;
            *(bf16x8*)(void*)&Aext[c>>4][(c&15)*8] =
                *(const bf16x8*)(const void*)(src + c*8);
        }
    }
    #pragma unroll
    for (int it = 0; it < 4; ++it){
        const int u = t + it*256;
        const int row = u >> 4, f = u & 15;
        Aext[row][128 + f] = f2b(x[((size_t)slice*NN + q0 + row)*FIN + f]);
    }
    #pragma unroll
    for (int it = 0; it < 4; ++it){
        const int u = t + it*256;
        Aext[u>>4][144 + (u&15)] = f2b(0.f);
    }
    __syncthreads();

    f32x4 O[8];
    #pragma unroll
    for (int ct = 0; ct < 8; ++ct) O[ct] = (f32x4){0.f,0.f,0.f,0.f};
    #pragma unroll
    for (int ks = 0; ks < 5; ++ks){
        const bf16x8 af = *(const bf16x8*)(const void*)&Aext[wr0 + l16][ks*32 + quad*8];
        #pragma unroll
        for (int ct = 0; ct < 8; ++ct){
            const bf16x8 bf = *(const bf16x8*)(const void*)
                (BH1 + (size_t)(ct*16 + l16)*168 + ks*32 + quad*8);
            O[ct] = __builtin_amdgcn_mfma_f32_16x16x32_bf16(af, bf, O[ct], 0, 0, 0);
        }
    }
    __syncthreads();
    #pragma unroll
    for (int ct = 0; ct < 8; ++ct){
        const int col = ct*16 + l16;
        const float bias = t_bo[col] + skb[col];
        #pragma unroll
        for (int r = 0; r < 4; ++r)
            Aext[wr0 + quad*4 + r][col] = f2b(O[ct][r] + bias);
    }
    __syncthreads();
    {
        const int row = t >> 2, ch0 = (t & 3)*32;
        bf16* dst = CXH1 + ((size_t)slice*NN + q0 + row)*HID + ch0;
        #pragma unroll
        for (int c = 0; c < 4; ++c)
            *(bf16x8*)(void*)(dst + c*8) =
                *(const bf16x8*)(const void*)&Aext[row][ch0 + c*8];
    }
}

// ---------------------------------------------------------------------------
// K_PREP: blocks 0-15: Mt; block 16: vk/vq/sbb; 17-21: bf16 transposed weight
// copies; block 22: BH1; all 32 blocks zero the CSR counter region.
// ---------------------------------------------------------------------------
__global__ __launch_bounds__(256)
void k_prep(const float* __restrict__ s_wq, const float* __restrict__ s_wk,
            const float* __restrict__ bq, const float* __restrict__ bk,
            const float* __restrict__ s_wv, const float* __restrict__ s_wo,
            const float* __restrict__ g1w, const float* __restrict__ w1,
            const float* __restrict__ w2,
            const float* __restrict__ t_wo, const float* __restrict__ skw,
            bf16* __restrict__ Mt, bf16* __restrict__ wvT, bf16* __restrict__ woT,
            bf16* __restrict__ g1wT, bf16* __restrict__ w1T, bf16* __restrict__ w2T,
            bf16* __restrict__ BH1,
            float* __restrict__ vk, float* __restrict__ vq, float* __restrict__ sbb,
            float* __restrict__ zp, int zn)
{
    const int b = blockIdx.x;          // 0..31
    const int t = threadIdx.x;
    for (int u = b*256 + t; u < zn; u += 32*256) zp[u] = 0.f;
    __shared__ float wq_s[HID*HID];    // 64 KB
    __shared__ float wk_s[8][HID];
    if (b < 16){
        for (int u = t; u < HID*HID; u += 256) wq_s[u] = s_wq[u];
        for (int u = t; u < 8*HID;   u += 256) ((float*)wk_s)[u] = s_wk[b*8*HID + u];
        __syncthreads();
        #pragma unroll
        for (int i = 0; i < 4; ++i){
            const int e = t + i*256;
            const int cl = e >> 7, a = e & 127;     // Mt row c = b*8+cl, col a
            float acc = 0.f;
            for (int hh = 0; hh < HID; ++hh) acc += wk_s[cl][hh]*wq_s[a*HID + hh];
            Mt[(size_t)(b*8 + cl)*HID + a] = f2b(acc);
        }
    } else if (b == 16){
        if (t < HID){
            float a1 = 0.f, a2 = 0.f;
            for (int hh = 0; hh < HID; ++hh){
                a1 += bq[hh]*s_wk[t*HID + hh];
                a2 += s_wq[t*HID + hh]*bk[hh];
            }
            vk[t] = a1; vq[t] = a2;
            if (t == 0){
                float s = 0.f;
                for (int hh = 0; hh < HID; ++hh) s += bq[hh]*bk[hh];
                *sbb = s;
            }
        }
    } else if (b == 17){
        for (int u = t; u < HID*HID; u += 256){
            const int c = u >> 7, h = u & 127;
            wvT[h*HID + c] = f2b(s_wv[u]);
        }
    } else if (b == 18){
        for (int u = t; u < HID*HID; u += 256){
            const int c = u >> 7, h = u & 127;
            woT[h*HID + c] = f2b(s_wo[u]);
        }
    } else if (b == 19){
        for (int u = t; u < HID*HID; u += 256){
            const int c = u >> 7, h = u & 127;
            g1wT[h*HID + c] = f2b(g1w[u]);
        }
    } else if (b == 20){
        for (int u = t; u < HID*2*HID; u += 256){
            const int k = u >> 8, n = u & 255;
            w1T[n*HID + k] = f2b(w1[u]);
        }
    } else if (b == 21){
        for (int u = t; u < 2*HID*HID; u += 256){
            const int k = u >> 7, n = u & 127;
            w2T[(size_t)n*2*HID + k] = f2b(w2[u]);
        }
    } else if (b == 22){
        // BH1[c][k]: k<128 -> t_wo[k][c]; 128<=k<144 -> skw[k-128][c]; else 0
        for (int u = t; u < HID*168; u += 256){
            const int c = u / 168, k = u - c*168;
            float v = 0.f;
            if (k < 128)      v = t_wo[k*HID + c];
            else if (k < 144) v = skw[(k-128)*HID + c];
            BH1[u] = f2b(v);
        }
    }
}

// ---------------------------------------------------------------------------
// K3 (R18, MFMA): 16 nodes/block, 256 thr (4 waves).
// ---------------------------------------------------------------------------
__global__ __launch_bounds__(256)
void k_mix(const bf16* __restrict__ H1,
           const float* __restrict__ ln2g, const float* __restrict__ ln2b,
           const bf16* __restrict__ Mt, const bf16* __restrict__ wvT,
           const bf16* __restrict__ woT, const bf16* __restrict__ g1wT,
           const bf16* __restrict__ w1T, const bf16* __restrict__ w2T,
           const float* __restrict__ vk, const float* __restrict__ vq,
           const float* __restrict__ sbbp,
           const float* __restrict__ s_bv, const float* __restrict__ s_bo,
           const float* __restrict__ bm1, const float* __restrict__ bm2,
           const float* __restrict__ ln3g, const float* __restrict__ ln3b,
           const float* __restrict__ g1as, const float* __restrict__ g1ad,
           bf16* __restrict__ hw1, float* __restrict__ als1, float* __restrict__ ald1)
{
    const int blk0 = blockIdx.x * 16;         // first node
    const int bb = blk0 >> 11, s0 = blk0 & (NN-1);
    const int t = threadIdx.x;
    const int w = t >> 6;
    const int lane = t & 63;
    const int quad = lane >> 4;
    const int l16  = lane & 15;

    __shared__ bf16  h1s[16][TT][136];   // 34816 B
    __shared__ bf16  ZA [16][136];       // 4352 B (A staging, reused)
    __shared__ bf16  HLs[16][264];       // 8448 B (MLP hidden)
    __shared__ float Cw [16][128];       // 8192 B (fp32 work)
    __shared__ float ln2gs[HID], ln2bs[HID];
    __shared__ float mu_s[16][TT], inv_s[16][TT];
    __shared__ float ps[16][TT];
    __shared__ float sbq_s[16], mu3[16], inv3[16];

    // ---- S1: stage h1 (bf16) + ln2 params ----
    for (int m = 0; m < TT; ++m){
        const bf16* src = H1 + ((size_t)(bb*TT + m)*NN + s0)*HID;
        const int node = t >> 4, c8 = t & 15;
        *(bf16x8*)(void*)&h1s[node][m][c8*8] =
            *(const bf16x8*)(const void*)(src + (size_t)node*HID + c8*8);
    }
    if (t < HID){ ln2gs[t] = ln2g[t]; ln2bs[t] = ln2b[t]; }
    __syncthreads();

    // ---- S2: LN2 stats (pair of threads per (node,m)) ----
    {
        const int idx = t >> 1, half = t & 1;
        const int node = idx >> 3, m = idx & 7;
        float sum = 0.f, sq = 0.f;
        for (int c = half; c < HID; c += 2){
            const float v = b2f(h1s[node][m][c]);
            sum += v; sq += v*v;
        }
        sum += __shfl_xor(sum, 1); sq += __shfl_xor(sq, 1);
        if (half == 0){
            const float mu = sum*(1.f/HID);
            const float var = sq*(1.f/HID) - mu*mu;
            mu_s[node][m] = mu;
            inv_s[node][m] = rsqrtf(var + 1e-5f);
        }
    }
    __syncthreads();

    // ---- S3: Z7 -> ZA; sbq partial ----
    #pragma unroll
    for (int i = 0; i < 8; ++i){
        const int idx = t + i*256;               // 2048
        const int n = idx >> 7, c = idx & 127;
        const float z = (b2f(h1s[n][7][c]) - mu_s[n][7])*inv_s[n][7]*ln2gs[c] + ln2bs[c];
        ZA[n][c] = f2b(z);
    }
    if (t < 128){
        const int node = t >> 3, l8 = t & 7;
        float sp = 0.f;
        for (int c = l8; c < HID; c += 8){
            const float z = (b2f(h1s[node][7][c]) - mu_s[node][7])*inv_s[node][7]*ln2gs[c] + ln2bs[c];
            sp += vq[c]*z;
        }
        sp += __shfl_xor(sp, 1);
        sp += __shfl_xor(sp, 2);
        sp += __shfl_xor(sp, 4);
        if (l8 == 0) sbq_s[node] = sp;
    }
    __syncthreads();

    // ---- S4: G1 rp = Z7@Mt + vk -> Cw ----
    {
        bf16x8 af[4];
        #pragma unroll
        for (int ks = 0; ks < 4; ++ks)
            af[ks] = *(const bf16x8*)(const void*)&ZA[l16][ks*32 + quad*8];
        __syncthreads();
        f32x4 C0 = (f32x4){0,0,0,0}, C1 = C0;
        #pragma unroll
        for (int ks = 0; ks < 4; ++ks){
            const bf16x8 b0 = *(const bf16x8*)(const void*)(Mt + (size_t)(w*32      + l16)*HID + ks*32 + quad*8);
            const bf16x8 b1 = *(const bf16x8*)(const void*)(Mt + (size_t)(w*32 + 16 + l16)*HID + ks*32 + quad*8);
            C0 = __builtin_amdgcn_mfma_f32_16x16x32_bf16(af[ks], b0, C0, 0, 0, 0);
            C1 = __builtin_amdgcn_mfma_f32_16x16x32_bf16(af[ks], b1, C1, 0, 0, 0);
        }
        const int c0 = w*32 + l16, c1 = c0 + 16;
        #pragma unroll
        for (int r = 0; r < 4; ++r){
            Cw[quad*4 + r][c0] = C0[r] + vk[c0];
            Cw[quad*4 + r][c1] = C1[r] + vk[c1];
        }
    }
    __syncthreads();

    // ---- S5: scr -> ps ----
    {
        const int idx = t >> 1, half = t & 1;
        const int node = idx >> 3, m = idx & 7;
        const float mu = mu_s[node][m], iv = inv_s[node][m];
        float d = 0.f;
        for (int c = half; c < HID; c += 2){
            const float z = (b2f(h1s[node][m][c]) - mu)*iv*ln2gs[c] + ln2bs[c];
            d += Cw[node][c]*z;
        }
        d += __shfl_xor(d, 1);
        if (half == 0)
            ps[node][m] = (d + sbq_s[node] + *sbbp) * 0.08838834764831845f;
    }
    __syncthreads();
    // ---- S6: softmax per node ----
    if (t < 16){
        float mx = -1e30f;
        #pragma unroll
        for (int m = 0; m < TT; ++m) mx = fmaxf(mx, ps[t][m]);
        float p[TT], se = 0.f;
        #pragma unroll
        for (int m = 0; m < TT; ++m){ p[m] = __expf(ps[t][m]-mx); se += p[m]; }
        const float isum = 1.f/se;
        #pragma unroll
        for (int m = 0; m < TT; ++m) ps[t][m] = p[m]*isum;
    }
    __syncthreads();
    // ---- S7: zbar -> ZA ----
    #pragma unroll
    for (int i = 0; i < 8; ++i){
        const int idx = t + i*256;
        const int n = idx >> 7, c = idx & 127;
        const float gc = ln2gs[c], bc = ln2bs[c];
        float acc = 0.f;
        #pragma unroll
        for (int m = 0; m < TT; ++m){
            const float z = (b2f(h1s[n][m][c]) - mu_s[n][m])*inv_s[n][m]*gc + bc;
            acc += ps[n][m]*z;
        }
        ZA[n][c] = f2b(acc);
    }
    __syncthreads();

    // ---- S8: G2 cx2 = ZB@wvT + bv -> ZA ----
    {
        bf16x8 af[4];
        #pragma unroll
        for (int ks = 0; ks < 4; ++ks)
            af[ks] = *(const bf16x8*)(const void*)&ZA[l16][ks*32 + quad*8];
        __syncthreads();
        f32x4 C0 = (f32x4){0,0,0,0}, C1 = C0;
        #pragma unroll
        for (int ks = 0; ks < 4; ++ks){
            const bf16x8 b0 = *(const bf16x8*)(const void*)(wvT + (size_t)(w*32      + l16)*HID + ks*32 + quad*8);
            const bf16x8 b1 = *(const bf16x8*)(const void*)(wvT + (size_t)(w*32 + 16 + l16)*HID + ks*32 + quad*8);
            C0 = __builtin_amdgcn_mfma_f32_16x16x32_bf16(af[ks], b0, C0, 0, 0, 0);
            C1 = __builtin_amdgcn_mfma_f32_16x16x32_bf16(af[ks], b1, C1, 0, 0, 0);
        }
        const int c0 = w*32 + l16, c1 = c0 + 16;
        #pragma unroll
        for (int r = 0; r < 4; ++r){
            ZA[quad*4 + r][c0] = f2b(C0[r] + s_bv[c0]);
            ZA[quad*4 + r][c1] = f2b(C1[r] + s_bv[c1]);
        }
    }
    __syncthreads();

    // ---- S9: G3 h2 = cx2@woT + bo + h1[7] -> Cw ----
    {
        bf16x8 af[4];
        #pragma unroll
        for (int ks = 0; ks < 4; ++ks)
            af[ks] = *(const bf16x8*)(const void*)&ZA[l16][ks*32 + quad*8];
        __syncthreads();
        f32x4 C0 = (f32x4){0,0,0,0}, C1 = C0;
        #pragma unroll
        for (int ks = 0; ks < 4; ++ks){
            const bf16x8 b0 = *(const bf16x8*)(const void*)(woT + (size_t)(w*32      + l16)*HID + ks*32 + quad*8);
            const bf16x8 b1 = *(const bf16x8*)(const void*)(woT + (size_t)(w*32 + 16 + l16)*HID + ks*32 + quad*8);
            C0 = __builtin_amdgcn_mfma_f32_16x16x32_bf16(af[ks], b0, C0, 0, 0, 0);
            C1 = __builtin_amdgcn_mfma_f32_16x16x32_bf16(af[ks], b1, C1, 0, 0, 0);
        }
        const int c0 = w*32 + l16, c1 = c0 + 16;
        #pragma unroll
        for (int r = 0; r < 4; ++r){
            const int node = quad*4 + r;
            Cw[node][c0] = C0[r] + s_bo[c0] + b2f(h1s[node][7][c0]);
            Cw[node][c1] = C1[r] + s_bo[c1] + b2f(h1s[node][7][c1]);
        }
    }
    __syncthreads();

    // ---- S10: LN3 stats (16-lane group per node) ----
    {
        const int node = t >> 4, part = t & 15;
        float sum = 0.f, sq = 0.f;
        for (int c = part; c < HID; c += 16){
            const float v = Cw[node][c];
            sum += v; sq += v*v;
        }
        sum += __shfl_xor(sum, 1); sq += __shfl_xor(sq, 1);
        sum += __shfl_xor(sum, 2); sq += __shfl_xor(sq, 2);
        sum += __shfl_xor(sum, 4); sq += __shfl_xor(sq, 4);
        sum += __shfl_xor(sum, 8); sq += __shfl_xor(sq, 8);
        if (part == 0){
            const float mu = sum*(1.f/HID);
            const float var = sq*(1.f/HID) - mu*mu;
            mu3[node] = mu;
            inv3[node] = rsqrtf(var + 1e-5f);
        }
    }
    __syncthreads();
    // ---- S11: z3 -> ZA ----
    #pragma unroll
    for (int i = 0; i < 8; ++i){
        const int idx = t + i*256;
        const int n = idx >> 7, c = idx & 127;
        ZA[n][c] = f2b((Cw[n][c] - mu3[n])*inv3[n]*ln3g[c] + ln3b[c]);
    }
    __syncthreads();

    // ---- S12: G4 hl = relu(z3@w1T + b1) -> HLs (ncols 256) ----
    {
        bf16x8 af[4];
        #pragma unroll
        for (int ks = 0; ks < 4; ++ks)
            af[ks] = *(const bf16x8*)(const void*)&ZA[l16][ks*32 + quad*8];
        __syncthreads();
        f32x4 C[4];
        #pragma unroll
        for (int u = 0; u < 4; ++u) C[u] = (f32x4){0,0,0,0};
        #pragma unroll
        for (int ks = 0; ks < 4; ++ks){
            #pragma unroll
            for (int u = 0; u < 4; ++u){
                const bf16x8 bfv = *(const bf16x8*)(const void*)
                    (w1T + (size_t)(w*64 + u*16 + l16)*HID + ks*32 + quad*8);
                C[u] = __builtin_amdgcn_mfma_f32_16x16x32_bf16(af[ks], bfv, C[u], 0, 0, 0);
            }
        }
        #pragma unroll
        for (int u = 0; u < 4; ++u){
            const int col = w*64 + u*16 + l16;
            const float bias = bm1[col];
            #pragma unroll
            for (int r = 0; r < 4; ++r)
                HLs[quad*4 + r][col] = f2b(fmaxf(C[u][r] + bias, 0.f));
        }
    }
    __syncthreads();

    // ---- S13: G5 hn = hl@w2T + b2 + h2 -> ZA (k=256) ----
    {
        bf16x8 af[8];
        #pragma unroll
        for (int ks = 0; ks < 8; ++ks)
            af[ks] = *(const bf16x8*)(const void*)&HLs[l16][ks*32 + quad*8];
        __syncthreads();
        f32x4 C0 = (f32x4){0,0,0,0}, C1 = C0;
        #pragma unroll
        for (int ks = 0; ks < 8; ++ks){
            const bf16x8 b0 = *(const bf16x8*)(const void*)(w2T + (size_t)(w*32      + l16)*2*HID + ks*32 + quad*8);
            const bf16x8 b1 = *(const bf16x8*)(const void*)(w2T + (size_t)(w*32 + 16 + l16)*2*HID + ks*32 + quad*8);
            C0 = __builtin_amdgcn_mfma_f32_16x16x32_bf16(af[ks], b0, C0, 0, 0, 0);
            C1 = __builtin_amdgcn_mfma_f32_16x16x32_bf16(af[ks], b1, C1, 0, 0, 0);
        }
        const int c0 = w*32 + l16, c1 = c0 + 16;
        #pragma unroll
        for (int r = 0; r < 4; ++r){
            const int node = quad*4 + r;
            ZA[node][c0] = f2b(C0[r] + bm2[c0] + Cw[node][c0]);
            ZA[node][c1] = f2b(C1[r] + bm2[c1] + Cw[node][c1]);
        }
    }
    __syncthreads();

    // ---- S14: G6 a = hn@g1wT -> Cw ----
    {
        bf16x8 af[4];
        #pragma unroll
        for (int ks = 0; ks < 4; ++ks)
            af[ks] = *(const bf16x8*)(const void*)&ZA[l16][ks*32 + quad*8];
        __syncthreads();
        f32x4 C0 = (f32x4){0,0,0,0}, C1 = C0;
        #pragma unroll
        for (int ks = 0; ks < 4; ++ks){
            const bf16x8 b0 = *(const bf16x8*)(const void*)(g1wT + (size_t)(w*32      + l16)*HID + ks*32 + quad*8);
            const bf16x8 b1 = *(const bf16x8*)(const void*)(g1wT + (size_t)(w*32 + 16 + l16)*HID + ks*32 + quad*8);
            C0 = __builtin_amdgcn_mfma_f32_16x16x32_bf16(af[ks], b0, C0, 0, 0, 0);
            C1 = __builtin_amdgcn_mfma_f32_16x16x32_bf16(af[ks], b1, C1, 0, 0, 0);
        }
        const int c0 = w*32 + l16, c1 = c0 + 16;
        #pragma unroll
        for (int r = 0; r < 4; ++r){
            Cw[quad*4 + r][c0] = C0[r];
            Cw[quad*4 + r][c1] = C1[r];
        }
    }
    __syncthreads();

    // ---- S15: outputs ----
    #pragma unroll
    for (int i = 0; i < 8; ++i){
        const int idx = t + i*256;                // node*128 + c
        hw1[(size_t)blk0*HID + idx] = f2b(((const float*)Cw)[idx]);
    }
    if (t < 64){
        const int node = t >> 2, hd = t & 3;
        float s1 = 0.f, s2 = 0.f;
        for (int j = 0; j < 32; ++j){
            const int c = hd*32 + j;
            const float a = Cw[node][c];
            s1 += a*g1as[c];
            s2 += a*g1ad[c];
        }
        als1[(blk0 + node)*NHEADS + hd] = s1;
        ald1[(blk0 + node)*NHEADS + hd] = s2;
    }
}

// ---------------------------------------------------------------------------
// CSR build (R21): edge list is batch-invariant -> build once.
// ---------------------------------------------------------------------------
__global__ void k_csr_hist(const int* __restrict__ ei, int* __restrict__ cnt)
{
    const int e = blockIdx.x*blockDim.x + threadIdx.x;
    if (e >= NEDGE) return;
    const int s = ei[e], d = ei[NEDGE + e];
    if (s != d) atomicAdd(&cnt[d], 1);
}

__global__ __launch_bounds__(256)
void k_csr_scan(const int* __restrict__ cnt, int* __restrict__ roff)
{
    const int t = threadIdx.x;                 // 256; 8 bins each
    __shared__ int part[256];
    int loc[8]; int s = 0;
    #pragma unroll
    for (int i = 0; i < 8; ++i){ loc[i] = s; s += cnt[t*8 + i]; }
    part[t] = s;
    __syncthreads();
    if (t == 0){
        int acc = 0;
        for (int i = 0; i < 256; ++i){ const int v = part[i]; part[i] = acc; acc += v; }
    }
    __syncthreads();
    const int base_ = part[t];
    #pragma unroll
    for (int i = 0; i < 8; ++i) roff[t*8 + i] = base_ + loc[i];
    if (t == 255) roff[2048] = base_ + s;
}

__global__ void k_csr_scatter(const int* __restrict__ ei, const int* __restrict__ roff,
                              int* __restrict__ fill, int* __restrict__ col)
{
    const int e = blockIdx.x*blockDim.x + threadIdx.x;
    if (e >= NEDGE) return;
    const int s = ei[e], d = ei[NEDGE + e];
    if (s != d){
        const int p = roff[d] + atomicAdd(&fill[d], 1);
        col[p] = s;
    }
}

// ---------------------------------------------------------------------------
// Fused GAT layer-1 gather + GAT2 linear (R25): one wave per node.
//   Gather: u32 bf16-pair loads (channels 2c,2c+1 per lane), register accum,
//   normalize + bias + ELU -> wave-private LDS row. GEMV: 64 outputs, one per
//   lane, W rows read coalesced from L2. hr global round-trip eliminated.
// ---------------------------------------------------------------------------
__global__ __launch_bounds__(64)
void k_gat_g1lin(const int* __restrict__ roff, const int* __restrict__ col,
                 const float* __restrict__ als, const float* __restrict__ ald,
                 const bf16* __restrict__ hw, const float* __restrict__ g1b,
                 const float* __restrict__ W,
                 const float* __restrict__ asrc, const float* __restrict__ adst,
                 bf16* __restrict__ hw2, float* __restrict__ al2s, float* __restrict__ al2d)
{
    const int nid = blockIdx.x;                 // 0..NNODE-1
    const int d   = nid & (NN-1);
    const int gb  = nid & ~(NN-1);              // batch node offset
    const int c2  = threadIdx.x;                // 0..63 -> channels 2c2, 2c2+1
    const int hd  = c2 >> 4;                    // (2*c2)>>5, shared by the pair
    const float ad = ald[nid*NHEADS + hd];

    float av0 = 0.f, av1 = 0.f, accd = 0.f;
    const int e0 = roff[d], e1 = roff[d+1];
    int sn = (e0 < e1) ? col[e0] : 0;
    for (int e = e0; e < e1; ++e){
        const int s = sn + gb;
        sn = (e+1 < e1) ? col[e+1] : 0;         // prefetch next col
        float a = als[s*NHEADS + hd] + ad;
        a = a > 0.f ? a : 0.2f*a;
        const float ex = __expf(a);
        const unsigned int pk =
            *(const unsigned int*)(const void*)&hw[(size_t)s*HID + 2*c2];
        av0 += ex * __uint_as_float(pk << 16);            // ch 2c2
        av1 += ex * __uint_as_float(pk & 0xffff0000u);    // ch 2c2+1
        accd += ex;
    }
    {   // self loop
        float a = als[nid*NHEADS + hd] + ad;
        a = a > 0.f ? a : 0.2f*a;
        const float ex = __expf(a);
        const unsigned int pk =
            *(const unsigned int*)(const void*)&hw[(size_t)nid*HID + 2*c2];
        av0 += ex * __uint_as_float(pk << 16);
        av1 += ex * __uint_as_float(pk & 0xffff0000u);
        accd += ex;
    }
    __shared__ float hrs[HID];
    {
        float v0 = av0/accd + g1b[2*c2];
        float v1 = av1/accd + g1b[2*c2+1];
        v0 = v0 > 0.f ? v0 : expm1f(v0);
        v1 = v1 > 0.f ? v1 : expm1f(v1);
        *(float2*)(void*)&hrs[2*c2] = make_float2(v0, v1);
    }
    __syncthreads();   // single wave: compiles to lgkmcnt wait; orders LDS

    const int c = c2;  // output channel 0..63
    float a = 0.f;
    for (int k = 0; k < HID; ++k) a += hrs[k]*W[k*OUTCH + c];
    hw2[(size_t)nid*OUTCH + c] = f2b(a);
    float s1 = a*asrc[c], s2 = a*adst[c];
    #pragma unroll
    for (int off = 32; off > 0; off >>= 1){
        s1 += __shfl_down(s1, off);
        s2 += __shfl_down(s2, off);
    }
    if (c == 0){ al2s[nid] = s1; al2d[nid] = s2; }
}

// ---------------------------------------------------------------------------
// GAT layer 2 gather + final FFN (R21).
// ---------------------------------------------------------------------------
__global__ __launch_bounds__(64)
void k_gat_gather2f(const int* __restrict__ roff, const int* __restrict__ col,
                    const float* __restrict__ als, const float* __restrict__ ald,
                    const bf16* __restrict__ hw2, const float* __restrict__ g2b,
                    const float* __restrict__ fw, const float* __restrict__ fb,
                    float* __restrict__ out)
{
    const int nid = blockIdx.x;
    const int d   = nid & (NN-1);
    const int gb  = nid & ~(NN-1);
    const int c   = threadIdx.x;                // 0..63
    const float ad = ald[nid];

    float accv = 0.f, accd = 0.f;
    const int e0 = roff[d], e1 = roff[d+1];
    int sn = (e0 < e1) ? col[e0] : 0;
    for (int e = e0; e < e1; ++e){
        const int s = sn + gb;
        sn = (e+1 < e1) ? col[e+1] : 0;
        float a = als[s] + ad;
        a = a > 0.f ? a : 0.2f*a;
        const float ex = __expf(a);
        accv += ex * b2f(hw2[(size_t)s*OUTCH + c]);
        accd += ex;
    }
    {   // self loop
        float a = als[nid] + ad;
        a = a > 0.f ? a : 0.2f*a;
        const float ex = __expf(a);
        accv += ex * b2f(hw2[(size_t)nid*OUTCH + c]);
        accd += ex;
    }
    __shared__ float g[OUTCH];
    g[c] = accv/accd + g2b[c];
    __syncthreads();
    if (c < OUTF){
        float o = fb[c];
        #pragma unroll
        for (int k = 0; k < OUTCH; ++k) o += g[k]*fw[k*OUTF + c];
        const int b = nid >> 11, n = nid & (NN-1);
        out[((size_t)b*OUTF + c)*NN + n] = o;
    }
}

// ---------------------------------------------------------------------------
extern "C" void kernel_launch(void* const* d_in, const int* in_sizes, int n_in,
                              void* d_out, int out_size, void* d_ws, size_t ws_size,
                              hipStream_t stream)
{
    const float* x    = (const float*)d_in[0];
    const int*  ei    = (const int*)d_in[1];
    const float* ln1g = (const float*)d_in[2];  const float* ln1b = (const float*)d_in[3];
    const float* t_wq = (const float*)d_in[4];  const float* t_bq = (const float*)d_in[5];
    const float* t_wk = (const float*)d_in[6];  const float* t_bk = (const float*)d_in[7];
    const float* t_wv = (const float*)d_in[8];  const float* t_bv = (const float*)d_in[9];
    const float* t_wo = (const float*)d_in[10]; const float* t_bo = (const float*)d_in[11];
    const float* skw  = (const float*)d_in[12]; const float* skb  = (const float*)d_in[13];
    const float* ln2g = (const float*)d_in[14]; const float* ln2b = (const float*)d_in[15];
    const float* s_wq = (const float*)d_in[16]; const float* s_bq = (const float*)d_in[17];
    const float* s_wk = (const float*)d_in[18]; const float* s_bk = (const float*)d_in[19];
    const float* s_wv = (const float*)d_in[20]; const float* s_bv = (const float*)d_in[21];
    const float* s_wo = (const float*)d_in[22]; const float* s_bo = (const float*)d_in[23];
    const float* ln3g = (const float*)d_in[24]; const float* ln3b = (const float*)d_in[25];
    const float* w1   = (const float*)d_in[26]; const float* b1   = (const float*)d_in[27];
    const float* w2   = (const float*)d_in[28]; const float* b2   = (const float*)d_in[29];
    const float* g1w  = (const float*)d_in[30];
    const float* g1as = (const float*)d_in[31]; const float* g1ad = (const float*)d_in[32];
    const float* g1b  = (const float*)d_in[33];
    const float* g2w  = (const float*)d_in[34];
    const float* g2as = (const float*)d_in[35]; const float* g2ad = (const float*)d_in[36];
    const float* g2b  = (const float*)d_in[37];
    const float* ffw  = (const float*)d_in[38]; const float* ffb  = (const float*)d_in[39];
    float* out = (float*)d_out;

    const size_t MiB = 1024u*1024u;
    const bool wide = ws_size >= 48*MiB;

    char* base = (char*)d_ws;
    bf16 *Kb, *Vtb, *CXH1;
    char* gat_base;
    char* mbase;
    if (wide){
        Kb   = (bf16*)(base + 0*MiB);      // 16 MiB
        Vtb  = (bf16*)(base + 16*MiB);     // 16 MiB
        CXH1 = (bf16*)(base + 32*MiB);     // 16 MiB
        gat_base = base;                   // aliases Kb (dead after attn)
        mbase = base + 13*MiB;             // inside dead Kb, past GAT scratch
    } else {
        CXH1 = (bf16*)(base + 0*MiB);      // 16 MiB
        gat_base = base + 16*MiB;          // ~8 MiB (no aliasing)
        Kb   = (bf16*)(base + 26*MiB);     // 0.5 MiB (one slice)
        Vtb  = (bf16*)(base + 26*MiB + 512u*1024u);
        mbase = base + 27*MiB;
    }
    bf16*  Mt   = (bf16*)mbase;                       // 32 KB
    bf16*  wvT  = (bf16*)(mbase + 32*1024);           // 32 KB
    bf16*  woT  = (bf16*)(mbase + 64*1024);           // 32 KB
    bf16*  g1wT = (bf16*)(mbase + 96*1024);           // 32 KB
    bf16*  w1T  = (bf16*)(mbase + 128*1024);          // 64 KB
    bf16*  w2T  = (bf16*)(mbase + 192*1024);          // 64 KB
    float* vkw  = (float*)(mbase + 256*1024);         // 512 B
    float* vqw  = (float*)(mbase + 256*1024 + 512);   // 512 B
    float* sbb  = (float*)(mbase + 256*1024 + 1024);  // 4 B
    bf16*  BH1  = (bf16*)(mbase + 272*1024);          // 42 KB (128x168 bf16)

    // GAT scratch: CSR counters FIRST (zeroed by k_prep), then CSR + buffers
    char* w = gat_base;
    auto alloc = [&](size_t bytes){ void* p = (void*)w; w += (bytes + 255) & ~(size_t)255; return p; };
    int*   cnt  = (int*)  alloc(2048u*sizeof(int));
    int*   fill = (int*)  alloc(2048u*sizeof(int));
    char*  zend = w;                                   // zero region = cnt+fill
    int*   roff = (int*)  alloc(2049u*sizeof(int));
    int*   col  = (int*)  alloc((size_t)NEDGE*sizeof(int));
    bf16*  hw1  = (bf16*) alloc((size_t)NNODE*HID*sizeof(bf16));    // 2 MiB
    float* als1 = (float*)alloc((size_t)NNODE*NHEADS*sizeof(float));
    float* ald1 = (float*)alloc((size_t)NNODE*NHEADS*sizeof(float));
    bf16*  hw2  = (bf16*) alloc((size_t)NNODE*OUTCH*sizeof(bf16));  // 1 MiB
    float* als2 = (float*)alloc((size_t)NNODE*sizeof(float));
    float* ald2 = (float*)alloc((size_t)NNODE*sizeof(float));
    const int zero_n = (int)((zend - (char*)cnt)/4);

    // ---- trunk ----
    if (wide){
        k_kv<<<PROWS/32, 256, 0, stream>>>(x, ln1g, ln1b, t_wk, t_bk, t_wv, t_bv, 0, Kb, Vtb);
        // 1D grid: in-kernel XCD swizzle (gridDim.y==1 selects wide decode)
        k_attn_mfma<<<BM*NTILE, 256, 0, stream>>>(x, Kb, Vtb, ln1g, ln1b,
                                                  t_wq, t_bq, 0, CXH1);
        // k_prep after attn (writes alias dead Kb), before k_h1 (builds BH1)
        k_prep<<<32, 256, 0, stream>>>(s_wq, s_wk, s_bq, s_bk, s_wv, s_wo, g1w, w1, w2,
                                       t_wo, skw,
                                       Mt, wvT, woT, g1wT, w1T, w2T, BH1,
                                       vkw, vqw, sbb, (float*)cnt, zero_n);
        k_h1<<<dim3(BM, NTILE), 256, 0, stream>>>(x, BH1, t_bo, skb, 0, CXH1);
    } else {
        for (int s = 0; s < BM; ++s){
            k_kv<<<NN/32, 256, 0, stream>>>(x, ln1g, ln1b, t_wk, t_bk, t_wv, t_bv, s*NN, Kb, Vtb);
            k_attn_mfma<<<dim3(1, NTILE), 256, 0, stream>>>(x, Kb, Vtb, ln1g, ln1b,
                                                            t_wq, t_bq, s, CXH1);
        }
        k_prep<<<32, 256, 0, stream>>>(s_wq, s_wk, s_bq, s_bk, s_wv, s_wo, g1w, w1, w2,
                                       t_wo, skw,
                                       Mt, wvT, woT, g1wT, w1T, w2T, BH1,
                                       vkw, vqw, sbb, (float*)cnt, zero_n);
        k_h1<<<dim3(BM, NTILE), 256, 0, stream>>>(x, BH1, t_bo, skb, 0, CXH1);
    }

    // CSR build (cnt/fill zeroed by k_prep; stream-serial ordering)
    k_csr_hist   <<<NEDGE/256, 256, 0, stream>>>(ei, cnt);
    k_csr_scan   <<<1,        256, 0, stream>>>(cnt, roff);
    k_csr_scatter<<<NEDGE/256, 256, 0, stream>>>(ei, roff, fill, col);

    k_mix<<<NNODE/16, 256, 0, stream>>>(CXH1, ln2g, ln2b, Mt, wvT, woT, g1wT, w1T, w2T,
                                        vkw, vqw, sbb, s_bv, s_bo, b1, b2,
                                        ln3g, ln3b, g1as, g1ad, hw1, als1, ald1);

    k_gat_g1lin  <<<NNODE, 64, 0, stream>>>(roff, col, als1, ald1, hw1, g1b,
                                            g2w, g2as, g2ad, hw2, als2, ald2);
    k_gat_gather2f<<<NNODE, 64, 0, stream>>>(roff, col, als2, ald2, hw2, g2b, ffw, ffb, out);
}

// Round 8
// 389.588 us; speedup vs baseline: 1.2039x; 1.0014x over previous
//
#include <hip/hip_runtime.h>
#include <hip/hip_bf16.h>
#include <stdint.h>

// ---------------------------------------------------------------------------
// PFGAT. R26: ONE change vs R25 — XOR-swizzle of the attn Ks tile (T2):
//   16B-chunk index ^= (row>>3)&3 on BOTH the reg->LDS staging writes and the
//   paired-row fragment reads. Keeps 16B alignment (R23's failure mode) and
//   leaves write-conflict structure identical (XOR term constant per wave);
//   K-fragment reads go 4-way-conflicted -> balanced across all 8 bank-quads.
// Rest identical to R25 (390.1us).
// ---------------------------------------------------------------------------

#define BB     4
#define TT     8
#define NN     2048
#define FIN    16
#define HID    128
#define BM     (BB*TT)            // 32 attention slices
#define PROWS  (BM*NN)            // 65536 rows
#define NHEADS 4
#define OUTCH  64
#define OUTF   14
#define NEDGE  32768
#define NEDGEB (NEDGE*BB)         // 131072
#define NNODE  (BB*NN)            // 8192
#define NETOT  (NEDGEB + NNODE)   // 139264 (edges + self loops)

#define TQ     64                 // query tile (rows per block)
#define NTILE  (NN/TQ)            // 32 query tiles per slice

typedef __hip_bfloat16 bf16;
typedef __attribute__((ext_vector_type(8))) short bf16x8;   // MFMA A/B frag
typedef __attribute__((ext_vector_type(4))) float f32x4;    // MFMA C/D frag

__device__ __forceinline__ float b2f(bf16 v){ return __bfloat162float(v); }
__device__ __forceinline__ bf16  f2b(float f){ return __float2bfloat16(f); }
__device__ __forceinline__ unsigned short bfbits(float f){
    union { bf16 h; unsigned short u; } cv; cv.h = f2b(f); return cv.u;
}

// ---------------------------------------------------------------------------
// K1 (R20): 32 rows/block, 256 threads. LN1 -> K (row-major) + Vt (key-tiled),
// both written as packed u32, fully coalesced.
// ---------------------------------------------------------------------------
__global__ __launch_bounds__(256)
void k_kv(const float* __restrict__ x,
          const float* __restrict__ g1, const float* __restrict__ bb1,
          const float* __restrict__ wk, const float* __restrict__ bk,
          const float* __restrict__ wv, const float* __restrict__ bv,
          int in_off, bf16* __restrict__ K, bf16* __restrict__ Vt)
{
    const int r0 = blockIdx.x * 32;            // first local row of this block
    const int t  = threadIdx.x;

    __shared__ float wk_s[FIN][HID];           // 8 KB
    __shared__ float wv_s[FIN][HID];           // 8 KB
    __shared__ float xr_s[32][FIN+1];          // padded vs bank conflicts
    __shared__ float ln_s[32][FIN+1];

    // stage weights (float4) + x tile
    #pragma unroll
    for (int it = 0; it < 2; ++it){
        const int u = t + it*256;              // 512 float4 = 2048 floats
        ((float4*)wk_s)[u] = ((const float4*)wk)[u];
        ((float4*)wv_s)[u] = ((const float4*)wv)[u];
    }
    #pragma unroll
    for (int it = 0; it < 2; ++it){
        const int u = t + it*256;              // 512 floats = 32 rows x 16
        xr_s[u >> 4][u & 15] = x[(size_t)(r0 + in_off)*FIN + u];
    }
    __syncthreads();

    // LN1 per row (one thread per row)
    if (t < 32){
        float mu = 0.f;
        #pragma unroll
        for (int f = 0; f < FIN; ++f) mu += xr_s[t][f];
        mu *= (1.f/FIN);
        float var = 0.f;
        #pragma unroll
        for (int f = 0; f < FIN; ++f){ float d = xr_s[t][f]-mu; var += d*d; }
        var *= (1.f/FIN);
        const float inv = rsqrtf(var + 1e-5f);
        #pragma unroll
        for (int f = 0; f < FIN; ++f)
            ln_s[t][f] = (xr_s[t][f]-mu)*inv*g1[f] + bb1[f];
    }
    __syncthreads();

    // ---- K: thread covers channel pair hk/hk+1; key varies over passes ----
    {
        const int hk = (t & 63)*2;             // 0..126 even
        const float2 bkv = *(const float2*)&bk[hk];
        #pragma unroll
        for (int pass = 0; pass < 8; ++pass){
            const int key = pass*4 + (t >> 6);
            float a0 = bkv.x, a1 = bkv.y;
            #pragma unroll
            for (int f = 0; f < FIN; ++f){
                const float l = ln_s[key][f];
                const float2 wkv = ((const float2*)&wk_s[f][0])[t & 63];
                a0 += l*wkv.x; a1 += l*wkv.y;
            }
            const unsigned int pk =
                (unsigned int)bfbits(a0) | ((unsigned int)bfbits(a1) << 16);
            *(unsigned int*)(void*)&K[((size_t)(r0 + key))*HID + hk] = pk;
        }
    }

    // ---- V: thread covers key pair kk/kk+1; channel varies over passes ----
    {
        const int slice = r0 >> 11;
        const int kg    = (r0 & (NN-1)) >> 5;  // 32-key group within slice
        const size_t vbase = ((size_t)slice*(NN/32) + kg)*(size_t)HID*32;
        const int kk = (t & 15)*2;
        #pragma unroll
        for (int pass = 0; pass < 8; ++pass){
            const int h = (t >> 4) + 16*pass;
            float a0 = bv[h], a1 = a0;
            #pragma unroll
            for (int f = 0; f < FIN; ++f){
                const float wvf = wv_s[f][h];
                a0 += ln_s[kk  ][f] * wvf;
                a1 += ln_s[kk+1][f] * wvf;
            }
            const unsigned int pk =
                (unsigned int)bfbits(a0) | ((unsigned int)bfbits(a1) << 16);
            *(unsigned int*)(void*)&Vt[vbase + (size_t)h*32 + kk] = pk;
        }
    }
}

// ---------------------------------------------------------------------------
// K2 (MFMA flash, R26): R24 + Ks chunk swizzle.
// ---------------------------------------------------------------------------
__global__ __launch_bounds__(256)
void k_attn_mfma(const float* __restrict__ x,
                 const bf16* __restrict__ K, const bf16* __restrict__ Vt,
                 const float* __restrict__ g1, const float* __restrict__ bb1,
                 const float* __restrict__ wq, const float* __restrict__ bq,
                 int slice_off, bf16* __restrict__ CX)
{
    int slice, tile, kvslice;
    if (gridDim.y == 1){
        const int bid = (int)blockIdx.x;
        slice   = (bid & 7)*4 + ((bid >> 3) & 3);
        tile    = (NTILE-1) - (bid >> 5);
        kvslice = slice;
    } else {
        tile    = (NTILE-1) - (int)blockIdx.y;
        slice   = (int)blockIdx.x + slice_off;
        kvslice = (int)blockIdx.x;
    }
    const int q0    = tile*TQ;
    const int t     = threadIdx.x;
    const int w     = t >> 6;
    const int lane  = t & 63;
    const int quad  = lane >> 4;
    const int l16   = lane & 15;
    const int wr0   = w*16;

    // scale * log2(e) folded into Q so the softmax exp is a bare v_exp_f32.
    const float qscale = 0.08838834764831845f * 1.4426950408889634f;

    __shared__ float xs [TQ][FIN+1];               // padded: LN1 per-thread reads
    __shared__ bf16  Ps [4][16][40];
    __shared__ __align__(16) bf16 KVs[32*136 + 128*40];   // Ks | Vs (main loop)
    bf16* Ks = KVs;
    bf16* Vs = KVs + 32*136;
    // overlays (time-multiplexed, barrier-protected):
    bf16 (*wqs)[32] = (bf16(*)[32])(&KVs[0]);      // preamble: [128 ch][32 k]
    bf16 (*xsb)[32] = (bf16(*)[32])(&KVs[4096]);   // preamble: [64 row][32 k]
    bf16 (*Qv)[136] = (bf16(*)[136])(&KVs[0]);     // Q staging + epilogue O

    // ---- issue K/V tile-0 loads immediately (hidden under preamble) ----
    const size_t kb = (size_t)kvslice * NN * HID;
    const size_t vb = (size_t)kvslice * (size_t)(NN/32) * HID*32;
    const bf16* kptr = K  + kb + (size_t)t*8;
    const bf16* vptr = Vt + vb + (size_t)t*8;
    bf16x8 kreg0, kreg1, vreg0, vreg1;
    kreg0 = *(const bf16x8*)(const void*)(kptr);
    kreg1 = *(const bf16x8*)(const void*)(kptr + 2048);
    vreg0 = *(const bf16x8*)(const void*)(vptr);
    vreg1 = *(const bf16x8*)(const void*)(vptr + 2048);

    // ---- stage x (fp32) and wq (bf16, pre-scaled, k-padded to 32) ----
    #pragma unroll
    for (int it = 0; it < 4; ++it){
        const int u = t + it*256;                  // 1024 = 64*16
        xs[u >> 4][u & 15] = x[((size_t)slice*NN + q0)*FIN + u];
    }
    #pragma unroll
    for (int it = 0; it < 8; ++it){
        const int u = t + it*256;                  // 2048 = 16*128
        const int f = u >> 7, ch = u & 127;
        wqs[ch][f] = f2b(wq[u] * qscale);
    }
    {   // zero-pad k = 16..31 of wqs
        const bf16x8 z8 = {0,0,0,0,0,0,0,0};
        const int ch = t >> 1, k0 = 16 + (t & 1)*8;
        *(bf16x8*)(void*)&wqs[ch][k0] = z8;
    }
    __syncthreads();

    // ---- LN1 into xsb (bf16, k-padded) ----
    if (t < TQ){
        float mu = 0.f;
        #pragma unroll
        for (int f = 0; f < FIN; ++f) mu += xs[t][f];
        mu *= (1.f/FIN);
        float var = 0.f;
        #pragma unroll
        for (int f = 0; f < FIN; ++f){ float d = xs[t][f]-mu; var += d*d; }
        var *= (1.f/FIN);
        const float inv = rsqrtf(var + 1e-5f);
        bf16x8 v0, v1;
        #pragma unroll
        for (int f = 0; f < 8; ++f)
            v0[f] = (short)bfbits((xs[t][f]-mu)*inv*g1[f] + bb1[f]);
        #pragma unroll
        for (int f = 0; f < 8; ++f)
            v1[f] = (short)bfbits((xs[t][8+f]-mu)*inv*g1[8+f] + bb1[8+f]);
        const bf16x8 z8 = {0,0,0,0,0,0,0,0};
        *(bf16x8*)(void*)&xsb[t][0]  = v0;
        *(bf16x8*)(void*)&xsb[t][8]  = v1;
        *(bf16x8*)(void*)&xsb[t][16] = z8;
        *(bf16x8*)(void*)&xsb[t][24] = z8;
    }
    __syncthreads();

    // ---- Q projection via MFMA: Qv = (LN1(x) @ wq + bq) * qscale ----
    {
        const bf16x8 af = *(const bf16x8*)(const void*)&xsb[wr0 + l16][quad*8];
        f32x4 Cq[8];
        #pragma unroll
        for (int ct = 0; ct < 8; ++ct){
            const bf16x8 bfv = *(const bf16x8*)(const void*)&wqs[ct*16 + l16][quad*8];
            Cq[ct] = __builtin_amdgcn_mfma_f32_16x16x32_bf16(
                         af, bfv, (f32x4){0.f,0.f,0.f,0.f}, 0, 0, 0);
        }
        __syncthreads();   // all waves done READING wqs/xsb before Qv overwrite
        #pragma unroll
        for (int ct = 0; ct < 8; ++ct){
            const int col = ct*16 + l16;
            const float bqs = bq[col] * qscale;
            #pragma unroll
            for (int r = 0; r < 4; ++r)
                Qv[wr0 + quad*4 + r][col] = f2b(Cq[ct][r] + bqs);
        }
    }
    __syncthreads();   // Qv ready

    bf16x8 qf[4];
    #pragma unroll
    for (int ks = 0; ks < 4; ++ks)
        qf[ks] = *(const bf16x8*)(const void*)&Qv[wr0 + l16][ks*32 + quad*8];
    __syncthreads();   // qf reads done; KVs may be overwritten by K/V staging

    f32x4 O[8];
    #pragma unroll
    for (int ct = 0; ct < 8; ++ct) O[ct] = (f32x4){0.f,0.f,0.f,0.f};
    float l_[4] = {0.f,0.f,0.f,0.f};

    const int jend_blk = q0 + TQ - 1;
    const int my_jmax  = q0 + wr0 + 15;
    const int brow = q0 + wr0 + quad*4;

    // ---- Ks chunk swizzle (T2): chunk' = chunk ^ ((row>>3)&3), 16B chunks.
    // Write side: XOR term is constant within each wave's 4-row span -> write
    // conflict structure unchanged. Read side: paired rows 2*l16 get terms
    // 0..3 across the former 4-way collision group {l16, l16+4, l16+8, l16+12}.
    bf16* ksA; bf16* ksB;
    {
        const int cA = t,       rA = cA >> 4, jA = (cA & 15) ^ ((rA >> 3) & 3);
        const int cB = t + 256, rB = cB >> 4, jB = (cB & 15) ^ ((rB >> 3) & 3);
        ksA = &Ks[rA*136 + jA*8];
        ksB = &Ks[rB*136 + jB*8];
    }
    const int kterm = (l16 >> 2) & 3;               // ((2*l16)>>3)&3 == ((2*l16+1)>>3)&3
    const bf16* kr0 = &Ks[(2*l16    )*136 + (quad ^ kterm)*8];
    const bf16* kr1 = &Ks[(2*l16 + 1)*136 + (quad ^ kterm)*8];

    bf16* vsA = &Vs[((t      ) >> 2)*40  + ((t      ) &  3)*8];
    bf16* vsB = &Vs[((t + 256) >> 2)*40  + ((t + 256) &  3)*8];
    const bf16* vr  = &Vs[l16*40 + quad*8];

    for (int j0 = 0; j0 <= jend_blk; j0 += 32){
        // regs -> LDS (waits on the loads issued last iteration)
        *(bf16x8*)(void*)ksA = kreg0;
        *(bf16x8*)(void*)ksB = kreg1;
        *(bf16x8*)(void*)vsA = vreg0;
        *(bf16x8*)(void*)vsB = vreg1;
        __syncthreads();

        // issue next tile's loads (T14: in flight across compute + barrier)
        if (j0 + 32 <= jend_blk){
            const size_t off = (size_t)(j0 + 32)*128;
            kreg0 = *(const bf16x8*)(const void*)(kptr + off);
            kreg1 = *(const bf16x8*)(const void*)(kptr + off + 2048);
            vreg0 = *(const bf16x8*)(const void*)(vptr + off);
            vreg1 = *(const bf16x8*)(const void*)(vptr + off + 2048);
        }

        if (j0 <= my_jmax){
            f32x4 S0 = (f32x4){0.f,0.f,0.f,0.f}, S1 = S0;
            #pragma unroll
            for (int ks = 0; ks < 4; ++ks){
                const bf16x8 kf0 = *(const bf16x8*)(const void*)(kr0 + ks*32);
                const bf16x8 kf1 = *(const bf16x8*)(const void*)(kr1 + ks*32);
                S0 = __builtin_amdgcn_mfma_f32_16x16x32_bf16(qf[ks], kf0, S0, 0, 0, 0);
                S1 = __builtin_amdgcn_mfma_f32_16x16x32_bf16(qf[ks], kf1, S1, 0, 0, 0);
            }
            // lane's two keys are adjacent: c0 = j0+2*l16, c1 = c0+1
            float sv0[4], sv1[4];
            if (j0 + 31 > q0 + wr0){                 // diagonal block: mask
                const int c0j = j0 + 2*l16, c1j = c0j + 1;
                #pragma unroll
                for (int r = 0; r < 4; ++r){
                    sv0[r] = (c0j <= brow + r) ? S0[r] : -1e30f;
                    sv1[r] = (c1j <= brow + r) ? S1[r] : -1e30f;
                }
            } else {                                  // strictly-lower: no mask
                #pragma unroll
                for (int r = 0; r < 4; ++r){ sv0[r] = S0[r]; sv1[r] = S1[r]; }
            }
            #pragma unroll
            for (int r = 0; r < 4; ++r){
                const float e0 = __builtin_amdgcn_exp2f(sv0[r]);
                const float e1 = __builtin_amdgcn_exp2f(sv1[r]);
                l_[r] += e0 + e1;
                const unsigned int pk =
                    (unsigned int)bfbits(e0) | ((unsigned int)bfbits(e1) << 16);
                *(unsigned int*)(void*)&Ps[w][quad*4 + r][2*l16] = pk;
            }
            const bf16x8 pf = *(const bf16x8*)(const void*)&Ps[w][l16][quad*8];
            #pragma unroll
            for (int ct = 0; ct < 8; ++ct){
                const bf16x8 vf = *(const bf16x8*)(const void*)(vr + ct*16*40);
                O[ct] = __builtin_amdgcn_mfma_f32_16x16x32_bf16(pf, vf, O[ct], 0, 0, 0);
            }
        }
        __syncthreads();
    }

    {
        float inv[4];
        #pragma unroll
        for (int r = 0; r < 4; ++r){
            float rs = l_[r];
            rs += __shfl_xor(rs, 1);
            rs += __shfl_xor(rs, 2);
            rs += __shfl_xor(rs, 4);
            rs += __shfl_xor(rs, 8);
            inv[r] = 1.f/rs;
        }
        #pragma unroll
        for (int ct = 0; ct < 8; ++ct)
        #pragma unroll
        for (int r = 0; r < 4; ++r)
            Qv[wr0 + quad*4 + r][ct*16 + l16] = f2b(O[ct][r]*inv[r]);
    }
    __syncthreads();
    {
        const int row = t >> 2, ch0 = (t & 3)*32;
        bf16* dst = CX + ((size_t)slice*NN + q0 + row)*HID + ch0;
        #pragma unroll
        for (int c = 0; c < 4; ++c)
            *(bf16x8*)(void*)(dst + c*8) =
                *(const bf16x8*)(const void*)&Qv[row][ch0 + c*8];
    }
}

// ---------------------------------------------------------------------------
// K_H1 (R22): B fragments read directly from pre-built bf16 BH1 [128][168].
// ---------------------------------------------------------------------------
__global__ __launch_bounds__(256)
void k_h1(const float* __restrict__ x,
          const bf16* __restrict__ BH1,
          const float* __restrict__ t_bo, const float* __restrict__ skb,
          int slice_off, bf16* __restrict__ CXH1)
{
    const int slice = blockIdx.x + slice_off;
    const int q0    = blockIdx.y * TQ;
    const int t     = threadIdx.x;
    const int w     = t >> 6;
    const int lane  = t & 63;
    const int quad  = lane >> 4;
    const int l16   = lane & 15;
    const int wr0   = w*16;

    __shared__ bf16 Aext[TQ][168];

    {
        const bf16* src = CXH1 + ((size_t)slice*NN + q0)*HID;
        #pragma unroll
        for (int it = 0; it < 4; ++it){
            const int c = t + it*256;
            *(bf16x8*)(void*)&Aext[c>>4][(c&15)*8] =
                *(const bf16x8*)(const void*)(src + c*8);
        }
    }
    #pragma unroll
    for (int it = 0; it < 4; ++it){
        const int u = t + it*256;
        const int row = u >> 4, f = u & 15;
        Aext[row][128 + f] = f2b(x[((size_t)slice*NN + q0 + row)*FIN + f]);
    }
    #pragma unroll
    for (int it = 0; it < 4; ++it){
        const int u = t + it*256;
        Aext[u>>4][144 + (u&15)] = f2b(0.f);
    }
    __syncthreads();

    f32x4 O[8];
    #pragma unroll
    for (int ct = 0; ct < 8; ++ct) O[ct] = (f32x4){0.f,0.f,0.f,0.f};
    #pragma unroll
    for (int ks = 0; ks < 5; ++ks){
        const bf16x8 af = *(const bf16x8*)(const void*)&Aext[wr0 + l16][ks*32 + quad*8];
        #pragma unroll
        for (int ct = 0; ct < 8; ++ct){
            const bf16x8 bf = *(const bf16x8*)(const void*)
                (BH1 + (size_t)(ct*16 + l16)*168 + ks*32 + quad*8);
            O[ct] = __builtin_amdgcn_mfma_f32_16x16x32_bf16(af, bf, O[ct], 0, 0, 0);
        }
    }
    __syncthreads();
    #pragma unroll
    for (int ct = 0; ct < 8; ++ct){
        const int col = ct*16 + l16;
        const float bias = t_bo[col] + skb[col];
        #pragma unroll
        for (int r = 0; r < 4; ++r)
            Aext[wr0 + quad*4 + r][col] = f2b(O[ct][r] + bias);
    }
    __syncthreads();
    {
        const int row = t >> 2, ch0 = (t & 3)*32;
        bf16* dst = CXH1 + ((size_t)slice*NN + q0 + row)*HID + ch0;
        #pragma unroll
        for (int c = 0; c < 4; ++c)
            *(bf16x8*)(void*)(dst + c*8) =
                *(const bf16x8*)(const void*)&Aext[row][ch0 + c*8];
    }
}

// ---------------------------------------------------------------------------
// K_PREP: blocks 0-15: Mt; block 16: vk/vq/sbb; 17-21: bf16 transposed weight
// copies; block 22: BH1; all 32 blocks zero the CSR counter region.
// ---------------------------------------------------------------------------
__global__ __launch_bounds__(256)
void k_prep(const float* __restrict__ s_wq, const float* __restrict__ s_wk,
            const float* __restrict__ bq, const float* __restrict__ bk,
            const float* __restrict__ s_wv, const float* __restrict__ s_wo,
            const float* __restrict__ g1w, const float* __restrict__ w1,
            const float* __restrict__ w2,
            const float* __restrict__ t_wo, const float* __restrict__ skw,
            bf16* __restrict__ Mt, bf16* __restrict__ wvT, bf16* __restrict__ woT,
            bf16* __restrict__ g1wT, bf16* __restrict__ w1T, bf16* __restrict__ w2T,
            bf16* __restrict__ BH1,
            float* __restrict__ vk, float* __restrict__ vq, float* __restrict__ sbb,
            float* __restrict__ zp, int zn)
{
    const int b = blockIdx.x;          // 0..31
    const int t = threadIdx.x;
    for (int u = b*256 + t; u < zn; u += 32*256) zp[u] = 0.f;
    __shared__ float wq_s[HID*HID];    // 64 KB
    __shared__ float wk_s[8][HID];
    if (b < 16){
        for (int u = t; u < HID*HID; u += 256) wq_s[u] = s_wq[u];
        for (int u = t; u < 8*HID;   u += 256) ((float*)wk_s)[u] = s_wk[b*8*HID + u];
        __syncthreads();
        #pragma unroll
        for (int i = 0; i < 4; ++i){
            const int e = t + i*256;
            const int cl = e >> 7, a = e & 127;     // Mt row c = b*8+cl, col a
            float acc = 0.f;
            for (int hh = 0; hh < HID; ++hh) acc += wk_s[cl][hh]*wq_s[a*HID + hh];
            Mt[(size_t)(b*8 + cl)*HID + a] = f2b(acc);
        }
    } else if (b == 16){
        if (t < HID){
            float a1 = 0.f, a2 = 0.f;
            for (int hh = 0; hh < HID; ++hh){
                a1 += bq[hh]*s_wk[t*HID + hh];
                a2 += s_wq[t*HID + hh]*bk[hh];
            }
            vk[t] = a1; vq[t] = a2;
            if (t == 0){
                float s = 0.f;
                for (int hh = 0; hh < HID; ++hh) s += bq[hh]*bk[hh];
                *sbb = s;
            }
        }
    } else if (b == 17){
        for (int u = t; u < HID*HID; u += 256){
            const int c = u >> 7, h = u & 127;
            wvT[h*HID + c] = f2b(s_wv[u]);
        }
    } else if (b == 18){
        for (int u = t; u < HID*HID; u += 256){
            const int c = u >> 7, h = u & 127;
            woT[h*HID + c] = f2b(s_wo[u]);
        }
    } else if (b == 19){
        for (int u = t; u < HID*HID; u += 256){
            const int c = u >> 7, h = u & 127;
            g1wT[h*HID + c] = f2b(g1w[u]);
        }
    } else if (b == 20){
        for (int u = t; u < HID*2*HID; u += 256){
            const int k = u >> 8, n = u & 255;
            w1T[n*HID + k] = f2b(w1[u]);
        }
    } else if (b == 21){
        for (int u = t; u < 2*HID*HID; u += 256){
            const int k = u >> 7, n = u & 127;
            w2T[(size_t)n*2*HID + k] = f2b(w2[u]);
        }
    } else if (b == 22){
        // BH1[c][k]: k<128 -> t_wo[k][c]; 128<=k<144 -> skw[k-128][c]; else 0
        for (int u = t; u < HID*168; u += 256){
            const int c = u / 168, k = u - c*168;
            float v = 0.f;
            if (k < 128)      v = t_wo[k*HID + c];
            else if (k < 144) v = skw[(k-128)*HID + c];
            BH1[u] = f2b(v);
        }
    }
}

// ---------------------------------------------------------------------------
// K3 (R18, MFMA): 16 nodes/block, 256 thr (4 waves).
// ---------------------------------------------------------------------------
__global__ __launch_bounds__(256)
void k_mix(const bf16* __restrict__ H1,
           const float* __restrict__ ln2g, const float* __restrict__ ln2b,
           const bf16* __restrict__ Mt, const bf16* __restrict__ wvT,
           const bf16* __restrict__ woT, const bf16* __restrict__ g1wT,
           const bf16* __restrict__ w1T, const bf16* __restrict__ w2T,
           const float* __restrict__ vk, const float* __restrict__ vq,
           const float* __restrict__ sbbp,
           const float* __restrict__ s_bv, const float* __restrict__ s_bo,
           const float* __restrict__ bm1, const float* __restrict__ bm2,
           const float* __restrict__ ln3g, const float* __restrict__ ln3b,
           const float* __restrict__ g1as, const float* __restrict__ g1ad,
           bf16* __restrict__ hw1, float* __restrict__ als1, float* __restrict__ ald1)
{
    const int blk0 = blockIdx.x * 16;         // first node
    const int bb = blk0 >> 11, s0 = blk0 & (NN-1);
    const int t = threadIdx.x;
    const int w = t >> 6;
    const int lane = t & 63;
    const int quad = lane >> 4;
    const int l16  = lane & 15;

    __shared__ bf16  h1s[16][TT][136];   // 34816 B
    __shared__ bf16  ZA [16][136];       // 4352 B (A staging, reused)
    __shared__ bf16  HLs[16][264];       // 8448 B (MLP hidden)
    __shared__ float Cw [16][128];       // 8192 B (fp32 work)
    __shared__ float ln2gs[HID], ln2bs[HID];
    __shared__ float mu_s[16][TT], inv_s[16][TT];
    __shared__ float ps[16][TT];
    __shared__ float sbq_s[16], mu3[16], inv3[16];

    // ---- S1: stage h1 (bf16) + ln2 params ----
    for (int m = 0; m < TT; ++m){
        const bf16* src = H1 + ((size_t)(bb*TT + m)*NN + s0)*HID;
        const int node = t >> 4, c8 = t & 15;
        *(bf16x8*)(void*)&h1s[node][m][c8*8] =
            *(const bf16x8*)(const void*)(src + (size_t)node*HID + c8*8);
    }
    if (t < HID){ ln2gs[t] = ln2g[t]; ln2bs[t] = ln2b[t]; }
    __syncthreads();

    // ---- S2: LN2 stats (pair of threads per (node,m)) ----
    {
        const int idx = t >> 1, half = t & 1;
        const int node = idx >> 3, m = idx & 7;
        float sum = 0.f, sq = 0.f;
        for (int c = half; c < HID; c += 2){
            const float v = b2f(h1s[node][m][c]);
            sum += v; sq += v*v;
        }
        sum += __shfl_xor(sum, 1); sq += __shfl_xor(sq, 1);
        if (half == 0){
            const float mu = sum*(1.f/HID);
            const float var = sq*(1.f/HID) - mu*mu;
            mu_s[node][m] = mu;
            inv_s[node][m] = rsqrtf(var + 1e-5f);
        }
    }
    __syncthreads();

    // ---- S3: Z7 -> ZA; sbq partial ----
    #pragma unroll
    for (int i = 0; i < 8; ++i){
        const int idx = t + i*256;               // 2048
        const int n = idx >> 7, c = idx & 127;
        const float z = (b2f(h1s[n][7][c]) - mu_s[n][7])*inv_s[n][7]*ln2gs[c] + ln2bs[c];
        ZA[n][c] = f2b(z);
    }
    if (t < 128){
        const int node = t >> 3, l8 = t & 7;
        float sp = 0.f;
        for (int c = l8; c < HID; c += 8){
            const float z = (b2f(h1s[node][7][c]) - mu_s[node][7])*inv_s[node][7]*ln2gs[c] + ln2bs[c];
            sp += vq[c]*z;
        }
        sp += __shfl_xor(sp, 1);
        sp += __shfl_xor(sp, 2);
        sp += __shfl_xor(sp, 4);
        if (l8 == 0) sbq_s[node] = sp;
    }
    __syncthreads();

    // ---- S4: G1 rp = Z7@Mt + vk -> Cw ----
    {
        bf16x8 af[4];
        #pragma unroll
        for (int ks = 0; ks < 4; ++ks)
            af[ks] = *(const bf16x8*)(const void*)&ZA[l16][ks*32 + quad*8];
        __syncthreads();
        f32x4 C0 = (f32x4){0,0,0,0}, C1 = C0;
        #pragma unroll
        for (int ks = 0; ks < 4; ++ks){
            const bf16x8 b0 = *(const bf16x8*)(const void*)(Mt + (size_t)(w*32      + l16)*HID + ks*32 + quad*8);
            const bf16x8 b1 = *(const bf16x8*)(const void*)(Mt + (size_t)(w*32 + 16 + l16)*HID + ks*32 + quad*8);
            C0 = __builtin_amdgcn_mfma_f32_16x16x32_bf16(af[ks], b0, C0, 0, 0, 0);
            C1 = __builtin_amdgcn_mfma_f32_16x16x32_bf16(af[ks], b1, C1, 0, 0, 0);
        }
        const int c0 = w*32 + l16, c1 = c0 + 16;
        #pragma unroll
        for (int r = 0; r < 4; ++r){
            Cw[quad*4 + r][c0] = C0[r] + vk[c0];
            Cw[quad*4 + r][c1] = C1[r] + vk[c1];
        }
    }
    __syncthreads();

    // ---- S5: scr -> ps ----
    {
        const int idx = t >> 1, half = t & 1;
        const int node = idx >> 3, m = idx & 7;
        const float mu = mu_s[node][m], iv = inv_s[node][m];
        float d = 0.f;
        for (int c = half; c < HID; c += 2){
            const float z = (b2f(h1s[node][m][c]) - mu)*iv*ln2gs[c] + ln2bs[c];
            d += Cw[node][c]*z;
        }
        d += __shfl_xor(d, 1);
        if (half == 0)
            ps[node][m] = (d + sbq_s[node] + *sbbp) * 0.08838834764831845f;
    }
    __syncthreads();
    // ---- S6: softmax per node ----
    if (t < 16){
        float mx = -1e30f;
        #pragma unroll
        for (int m = 0; m < TT; ++m) mx = fmaxf(mx, ps[t][m]);
        float p[TT], se = 0.f;
        #pragma unroll
        for (int m = 0; m < TT; ++m){ p[m] = __expf(ps[t][m]-mx); se += p[m]; }
        const float isum = 1.f/se;
        #pragma unroll
        for (int m = 0; m < TT; ++m) ps[t][m] = p[m]*isum;
    }
    __syncthreads();
    // ---- S7: zbar -> ZA ----
    #pragma unroll
    for (int i = 0; i < 8; ++i){
        const int idx = t + i*256;
        const int n = idx >> 7, c = idx & 127;
        const float gc = ln2gs[c], bc = ln2bs[c];
        float acc = 0.f;
        #pragma unroll
        for (int m = 0; m < TT; ++m){
            const float z = (b2f(h1s[n][m][c]) - mu_s[n][m])*inv_s[n][m]*gc + bc;
            acc += ps[n][m]*z;
        }
        ZA[n][c] = f2b(acc);
    }
    __syncthreads();

    // ---- S8: G2 cx2 = ZB@wvT + bv -> ZA ----
    {
        bf16x8 af[4];
        #pragma unroll
        for (int ks = 0; ks < 4; ++ks)
            af[ks] = *(const bf16x8*)(const void*)&ZA[l16][ks*32 + quad*8];
        __syncthreads();
        f32x4 C0 = (f32x4){0,0,0,0}, C1 = C0;
        #pragma unroll
        for (int ks = 0; ks < 4; ++ks){
            const bf16x8 b0 = *(const bf16x8*)(const void*)(wvT + (size_t)(w*32      + l16)*HID + ks*32 + quad*8);
            const bf16x8 b1 = *(const bf16x8*)(const void*)(wvT + (size_t)(w*32 + 16 + l16)*HID + ks*32 + quad*8);
            C0 = __builtin_amdgcn_mfma_f32_16x16x32_bf16(af[ks], b0, C0, 0, 0, 0);
            C1 = __builtin_amdgcn_mfma_f32_16x16x32_bf16(af[ks], b1, C1, 0, 0, 0);
        }
        const int c0 = w*32 + l16, c1 = c0 + 16;
        #pragma unroll
        for (int r = 0; r < 4; ++r){
            ZA[quad*4 + r][c0] = f2b(C0[r] + s_bv[c0]);
            ZA[quad*4 + r][c1] = f2b(C1[r] + s_bv[c1]);
        }
    }
    __syncthreads();

    // ---- S9: G3 h2 = cx2@woT + bo + h1[7] -> Cw ----
    {
        bf16x8 af[4];
        #pragma unroll
        for (int ks = 0; ks < 4; ++ks)
            af[ks] = *(const bf16x8*)(const void*)&ZA[l16][ks*32 + quad*8];
        __syncthreads();
        f32x4 C0 = (f32x4){0,0,0,0}, C1 = C0;
        #pragma unroll
        for (int ks = 0; ks < 4; ++ks){
            const bf16x8 b0 = *(const bf16x8*)(const void*)(woT + (size_t)(w*32      + l16)*HID + ks*32 + quad*8);
            const bf16x8 b1 = *(const bf16x8*)(const void*)(woT + (size_t)(w*32 + 16 + l16)*HID + ks*32 + quad*8);
            C0 = __builtin_amdgcn_mfma_f32_16x16x32_bf16(af[ks], b0, C0, 0, 0, 0);
            C1 = __builtin_amdgcn_mfma_f32_16x16x32_bf16(af[ks], b1, C1, 0, 0, 0);
        }
        const int c0 = w*32 + l16, c1 = c0 + 16;
        #pragma unroll
        for (int r = 0; r < 4; ++r){
            const int node = quad*4 + r;
            Cw[node][c0] = C0[r] + s_bo[c0] + b2f(h1s[node][7][c0]);
            Cw[node][c1] = C1[r] + s_bo[c1] + b2f(h1s[node][7][c1]);
        }
    }
    __syncthreads();

    // ---- S10: LN3 stats (16-lane group per node) ----
    {
        const int node = t >> 4, part = t & 15;
        float sum = 0.f, sq = 0.f;
        for (int c = part; c < HID; c += 16){
            const float v = Cw[node][c];
            sum += v; sq += v*v;
        }
        sum += __shfl_xor(sum, 1); sq += __shfl_xor(sq, 1);
        sum += __shfl_xor(sum, 2); sq += __shfl_xor(sq, 2);
        sum += __shfl_xor(sum, 4); sq += __shfl_xor(sq, 4);
        sum += __shfl_xor(sum, 8); sq += __shfl_xor(sq, 8);
        if (part == 0){
            const float mu = sum*(1.f/HID);
            const float var = sq*(1.f/HID) - mu*mu;
            mu3[node] = mu;
            inv3[node] = rsqrtf(var + 1e-5f);
        }
    }
    __syncthreads();
    // ---- S11: z3 -> ZA ----
    #pragma unroll
    for (int i = 0; i < 8; ++i){
        const int idx = t + i*256;
        const int n = idx >> 7, c = idx & 127;
        ZA[n][c] = f2b((Cw[n][c] - mu3[n])*inv3[n]*ln3g[c] + ln3b[c]);
    }
    __syncthreads();

    // ---- S12: G4 hl = relu(z3@w1T + b1) -> HLs (ncols 256) ----
    {
        bf16x8 af[4];
        #pragma unroll
        for (int ks = 0; ks < 4; ++ks)
            af[ks] = *(const bf16x8*)(const void*)&ZA[l16][ks*32 + quad*8];
        __syncthreads();
        f32x4 C[4];
        #pragma unroll
        for (int u = 0; u < 4; ++u) C[u] = (f32x4){0,0,0,0};
        #pragma unroll
        for (int ks = 0; ks < 4; ++ks){
            #pragma unroll
            for (int u = 0; u < 4; ++u){
                const bf16x8 bfv = *(const bf16x8*)(const void*)
                    (w1T + (size_t)(w*64 + u*16 + l16)*HID + ks*32 + quad*8);
                C[u] = __builtin_amdgcn_mfma_f32_16x16x32_bf16(af[ks], bfv, C[u], 0, 0, 0);
            }
        }
        #pragma unroll
        for (int u = 0; u < 4; ++u){
            const int col = w*64 + u*16 + l16;
            const float bias = bm1[col];
            #pragma unroll
            for (int r = 0; r < 4; ++r)
                HLs[quad*4 + r][col] = f2b(fmaxf(C[u][r] + bias, 0.f));
        }
    }
    __syncthreads();

    // ---- S13: G5 hn = hl@w2T + b2 + h2 -> ZA (k=256) ----
    {
        bf16x8 af[8];
        #pragma unroll
        for (int ks = 0; ks < 8; ++ks)
            af[ks] = *(const bf16x8*)(const void*)&HLs[l16][ks*32 + quad*8];
        __syncthreads();
        f32x4 C0 = (f32x4){0,0,0,0}, C1 = C0;
        #pragma unroll
        for (int ks = 0; ks < 8; ++ks){
            const bf16x8 b0 = *(const bf16x8*)(const void*)(w2T + (size_t)(w*32      + l16)*2*HID + ks*32 + quad*8);
            const bf16x8 b1 = *(const bf16x8*)(const void*)(w2T + (size_t)(w*32 + 16 + l16)*2*HID + ks*32 + quad*8);
            C0 = __builtin_amdgcn_mfma_f32_16x16x32_bf16(af[ks], b0, C0, 0, 0, 0);
            C1 = __builtin_amdgcn_mfma_f32_16x16x32_bf16(af[ks], b1, C1, 0, 0, 0);
        }
        const int c0 = w*32 + l16, c1 = c0 + 16;
        #pragma unroll
        for (int r = 0; r < 4; ++r){
            const int node = quad*4 + r;
            ZA[node][c0] = f2b(C0[r] + bm2[c0] + Cw[node][c0]);
            ZA[node][c1] = f2b(C1[r] + bm2[c1] + Cw[node][c1]);
        }
    }
    __syncthreads();

    // ---- S14: G6 a = hn@g1wT -> Cw ----
    {
        bf16x8 af[4];
        #pragma unroll
        for (int ks = 0; ks < 4; ++ks)
            af[ks] = *(const bf16x8*)(const void*)&ZA[l16][ks*32 + quad*8];
        __syncthreads();
        f32x4 C0 = (f32x4){0,0,0,0}, C1 = C0;
        #pragma unroll
        for (int ks = 0; ks < 4; ++ks){
            const bf16x8 b0 = *(const bf16x8*)(const void*)(g1wT + (size_t)(w*32      + l16)*HID + ks*32 + quad*8);
            const bf16x8 b1 = *(const bf16x8*)(const void*)(g1wT + (size_t)(w*32 + 16 + l16)*HID + ks*32 + quad*8);
            C0 = __builtin_amdgcn_mfma_f32_16x16x32_bf16(af[ks], b0, C0, 0, 0, 0);
            C1 = __builtin_amdgcn_mfma_f32_16x16x32_bf16(af[ks], b1, C1, 0, 0, 0);
        }
        const int c0 = w*32 + l16, c1 = c0 + 16;
        #pragma unroll
        for (int r = 0; r < 4; ++r){
            Cw[quad*4 + r][c0] = C0[r];
            Cw[quad*4 + r][c1] = C1[r];
        }
    }
    __syncthreads();

    // ---- S15: outputs ----
    #pragma unroll
    for (int i = 0; i < 8; ++i){
        const int idx = t + i*256;                // node*128 + c
        hw1[(size_t)blk0*HID + idx] = f2b(((const float*)Cw)[idx]);
    }
    if (t < 64){
        const int node = t >> 2, hd = t & 3;
        float s1 = 0.f, s2 = 0.f;
        for (int j = 0; j < 32; ++j){
            const int c = hd*32 + j;
            const float a = Cw[node][c];
            s1 += a*g1as[c];
            s2 += a*g1ad[c];
        }
        als1[(blk0 + node)*NHEADS + hd] = s1;
        ald1[(blk0 + node)*NHEADS + hd] = s2;
    }
}

// ---------------------------------------------------------------------------
// CSR build (R21): edge list is batch-invariant -> build once.
// ---------------------------------------------------------------------------
__global__ void k_csr_hist(const int* __restrict__ ei, int* __restrict__ cnt)
{
    const int e = blockIdx.x*blockDim.x + threadIdx.x;
    if (e >= NEDGE) return;
    const int s = ei[e], d = ei[NEDGE + e];
    if (s != d) atomicAdd(&cnt[d], 1);
}

__global__ __launch_bounds__(256)
void k_csr_scan(const int* __restrict__ cnt, int* __restrict__ roff)
{
    const int t = threadIdx.x;                 // 256; 8 bins each
    __shared__ int part[256];
    int loc[8]; int s = 0;
    #pragma unroll
    for (int i = 0; i < 8; ++i){ loc[i] = s; s += cnt[t*8 + i]; }
    part[t] = s;
    __syncthreads();
    if (t == 0){
        int acc = 0;
        for (int i = 0; i < 256; ++i){ const int v = part[i]; part[i] = acc; acc += v; }
    }
    __syncthreads();
    const int base_ = part[t];
    #pragma unroll
    for (int i = 0; i < 8; ++i) roff[t*8 + i] = base_ + loc[i];
    if (t == 255) roff[2048] = base_ + s;
}

__global__ void k_csr_scatter(const int* __restrict__ ei, const int* __restrict__ roff,
                              int* __restrict__ fill, int* __restrict__ col)
{
    const int e = blockIdx.x*blockDim.x + threadIdx.x;
    if (e >= NEDGE) return;
    const int s = ei[e], d = ei[NEDGE + e];
    if (s != d){
        const int p = roff[d] + atomicAdd(&fill[d], 1);
        col[p] = s;
    }
}

// ---------------------------------------------------------------------------
// Fused GAT layer-1 gather + GAT2 linear (R25): one wave per node.
// ---------------------------------------------------------------------------
__global__ __launch_bounds__(64)
void k_gat_g1lin(const int* __restrict__ roff, const int* __restrict__ col,
                 const float* __restrict__ als, const float* __restrict__ ald,
                 const bf16* __restrict__ hw, const float* __restrict__ g1b,
                 const float* __restrict__ W,
                 const float* __restrict__ asrc, const float* __restrict__ adst,
                 bf16* __restrict__ hw2, float* __restrict__ al2s, float* __restrict__ al2d)
{
    const int nid = blockIdx.x;                 // 0..NNODE-1
    const int d   = nid & (NN-1);
    const int gb  = nid & ~(NN-1);              // batch node offset
    const int c2  = threadIdx.x;                // 0..63 -> channels 2c2, 2c2+1
    const int hd  = c2 >> 4;                    // (2*c2)>>5, shared by the pair
    const float ad = ald[nid*NHEADS + hd];

    float av0 = 0.f, av1 = 0.f, accd = 0.f;
    const int e0 = roff[d], e1 = roff[d+1];
    int sn = (e0 < e1) ? col[e0] : 0;
    for (int e = e0; e < e1; ++e){
        const int s = sn + gb;
        sn = (e+1 < e1) ? col[e+1] : 0;         // prefetch next col
        float a = als[s*NHEADS + hd] + ad;
        a = a > 0.f ? a : 0.2f*a;
        const float ex = __expf(a);
        const unsigned int pk =
            *(const unsigned int*)(const void*)&hw[(size_t)s*HID + 2*c2];
        av0 += ex * __uint_as_float(pk << 16);            // ch 2c2
        av1 += ex * __uint_as_float(pk & 0xffff0000u);    // ch 2c2+1
        accd += ex;
    }
    {   // self loop
        float a = als[nid*NHEADS + hd] + ad;
        a = a > 0.f ? a : 0.2f*a;
        const float ex = __expf(a);
        const unsigned int pk =
            *(const unsigned int*)(const void*)&hw[(size_t)nid*HID + 2*c2];
        av0 += ex * __uint_as_float(pk << 16);
        av1 += ex * __uint_as_float(pk & 0xffff0000u);
        accd += ex;
    }
    __shared__ float hrs[HID];
    {
        float v0 = av0/accd + g1b[2*c2];
        float v1 = av1/accd + g1b[2*c2+1];
        v0 = v0 > 0.f ? v0 : expm1f(v0);
        v1 = v1 > 0.f ? v1 : expm1f(v1);
        *(float2*)(void*)&hrs[2*c2] = make_float2(v0, v1);
    }
    __syncthreads();   // single wave: compiles to lgkmcnt wait; orders LDS

    const int c = c2;  // output channel 0..63
    float a = 0.f;
    for (int k = 0; k < HID; ++k) a += hrs[k]*W[k*OUTCH + c];
    hw2[(size_t)nid*OUTCH + c] = f2b(a);
    float s1 = a*asrc[c], s2 = a*adst[c];
    #pragma unroll
    for (int off = 32; off > 0; off >>= 1){
        s1 += __shfl_down(s1, off);
        s2 += __shfl_down(s2, off);
    }
    if (c == 0){ al2s[nid] = s1; al2d[nid] = s2; }
}

// ---------------------------------------------------------------------------
// GAT layer 2 gather + final FFN (R21).
// ---------------------------------------------------------------------------
__global__ __launch_bounds__(64)
void k_gat_gather2f(const int* __restrict__ roff, const int* __restrict__ col,
                    const float* __restrict__ als, const float* __restrict__ ald,
                    const bf16* __restrict__ hw2, const float* __restrict__ g2b,
                    const float* __restrict__ fw, const float* __restrict__ fb,
                    float* __restrict__ out)
{
    const int nid = blockIdx.x;
    const int d   = nid & (NN-1);
    const int gb  = nid & ~(NN-1);
    const int c   = threadIdx.x;                // 0..63
    const float ad = ald[nid];

    float accv = 0.f, accd = 0.f;
    const int e0 = roff[d], e1 = roff[d+1];
    int sn = (e0 < e1) ? col[e0] : 0;
    for (int e = e0; e < e1; ++e){
        const int s = sn + gb;
        sn = (e+1 < e1) ? col[e+1] : 0;
        float a = als[s] + ad;
        a = a > 0.f ? a : 0.2f*a;
        const float ex = __expf(a);
        accv += ex * b2f(hw2[(size_t)s*OUTCH + c]);
        accd += ex;
    }
    {   // self loop
        float a = als[nid] + ad;
        a = a > 0.f ? a : 0.2f*a;
        const float ex = __expf(a);
        accv += ex * b2f(hw2[(size_t)nid*OUTCH + c]);
        accd += ex;
    }
    __shared__ float g[OUTCH];
    g[c] = accv/accd + g2b[c];
    __syncthreads();
    if (c < OUTF){
        float o = fb[c];
        #pragma unroll
        for (int k = 0; k < OUTCH; ++k) o += g[k]*fw[k*OUTF + c];
        const int b = nid >> 11, n = nid & (NN-1);
        out[((size_t)b*OUTF + c)*NN + n] = o;
    }
}

// ---------------------------------------------------------------------------
extern "C" void kernel_launch(void* const* d_in, const int* in_sizes, int n_in,
                              void* d_out, int out_size, void* d_ws, size_t ws_size,
                              hipStream_t stream)
{
    const float* x    = (const float*)d_in[0];
    const int*  ei    = (const int*)d_in[1];
    const float* ln1g = (const float*)d_in[2];  const float* ln1b = (const float*)d_in[3];
    const float* t_wq = (const float*)d_in[4];  const float* t_bq = (const float*)d_in[5];
    const float* t_wk = (const float*)d_in[6];  const float* t_bk = (const float*)d_in[7];
    const float* t_wv = (const float*)d_in[8];  const float* t_bv = (const float*)d_in[9];
    const float* t_wo = (const float*)d_in[10]; const float* t_bo = (const float*)d_in[11];
    const float* skw  = (const float*)d_in[12]; const float* skb  = (const float*)d_in[13];
    const float* ln2g = (const float*)d_in[14]; const float* ln2b = (const float*)d_in[15];
    const float* s_wq = (const float*)d_in[16]; const float* s_bq = (const float*)d_in[17];
    const float* s_wk = (const float*)d_in[18]; const float* s_bk = (const float*)d_in[19];
    const float* s_wv = (const float*)d_in[20]; const float* s_bv = (const float*)d_in[21];
    const float* s_wo = (const float*)d_in[22]; const float* s_bo = (const float*)d_in[23];
    const float* ln3g = (const float*)d_in[24]; const float* ln3b = (const float*)d_in[25];
    const float* w1   = (const float*)d_in[26]; const float* b1   = (const float*)d_in[27];
    const float* w2   = (const float*)d_in[28]; const float* b2   = (const float*)d_in[29];
    const float* g1w  = (const float*)d_in[30];
    const float* g1as = (const float*)d_in[31]; const float* g1ad = (const float*)d_in[32];
    const float* g1b  = (const float*)d_in[33];
    const float* g2w  = (const float*)d_in[34];
    const float* g2as = (const float*)d_in[35]; const float* g2ad = (const float*)d_in[36];
    const float* g2b  = (const float*)d_in[37];
    const float* ffw  = (const float*)d_in[38]; const float* ffb  = (const float*)d_in[39];
    float* out = (float*)d_out;

    const size_t MiB = 1024u*1024u;
    const bool wide = ws_size >= 48*MiB;

    char* base = (char*)d_ws;
    bf16 *Kb, *Vtb, *CXH1;
    char* gat_base;
    char* mbase;
    if (wide){
        Kb   = (bf16*)(base + 0*MiB);      // 16 MiB
        Vtb  = (bf16*)(base + 16*MiB);     // 16 MiB
        CXH1 = (bf16*)(base + 32*MiB);     // 16 MiB
        gat_base = base;                   // aliases Kb (dead after attn)
        mbase = base + 13*MiB;             // inside dead Kb, past GAT scratch
    } else {
        CXH1 = (bf16*)(base + 0*MiB);      // 16 MiB
        gat_base = base + 16*MiB;          // ~8 MiB (no aliasing)
        Kb   = (bf16*)(base + 26*MiB);     // 0.5 MiB (one slice)
        Vtb  = (bf16*)(base + 26*MiB + 512u*1024u);
        mbase = base + 27*MiB;
    }
    bf16*  Mt   = (bf16*)mbase;                       // 32 KB
    bf16*  wvT  = (bf16*)(mbase + 32*1024);           // 32 KB
    bf16*  woT  = (bf16*)(mbase + 64*1024);           // 32 KB
    bf16*  g1wT = (bf16*)(mbase + 96*1024);           // 32 KB
    bf16*  w1T  = (bf16*)(mbase + 128*1024);          // 64 KB
    bf16*  w2T  = (bf16*)(mbase + 192*1024);          // 64 KB
    float* vkw  = (float*)(mbase + 256*1024);         // 512 B
    float* vqw  = (float*)(mbase + 256*1024 + 512);   // 512 B
    float* sbb  = (float*)(mbase + 256*1024 + 1024);  // 4 B
    bf16*  BH1  = (bf16*)(mbase + 272*1024);          // 42 KB (128x168 bf16)

    // GAT scratch: CSR counters FIRST (zeroed by k_prep), then CSR + buffers
    char* w = gat_base;
    auto alloc = [&](size_t bytes){ void* p = (void*)w; w += (bytes + 255) & ~(size_t)255; return p; };
    int*   cnt  = (int*)  alloc(2048u*sizeof(int));
    int*   fill = (int*)  alloc(2048u*sizeof(int));
    char*  zend = w;                                   // zero region = cnt+fill
    int*   roff = (int*)  alloc(2049u*sizeof(int));
    int*   col  = (int*)  alloc((size_t)NEDGE*sizeof(int));
    bf16*  hw1  = (bf16*) alloc((size_t)NNODE*HID*sizeof(bf16));    // 2 MiB
    float* als1 = (float*)alloc((size_t)NNODE*NHEADS*sizeof(float));
    float* ald1 = (float*)alloc((size_t)NNODE*NHEADS*sizeof(float));
    bf16*  hw2  = (bf16*) alloc((size_t)NNODE*OUTCH*sizeof(bf16));  // 1 MiB
    float* als2 = (float*)alloc((size_t)NNODE*sizeof(float));
    float* ald2 = (float*)alloc((size_t)NNODE*sizeof(float));
    const int zero_n = (int)((zend - (char*)cnt)/4);

    // ---- trunk ----
    if (wide){
        k_kv<<<PROWS/32, 256, 0, stream>>>(x, ln1g, ln1b, t_wk, t_bk, t_wv, t_bv, 0, Kb, Vtb);
        // 1D grid: in-kernel XCD swizzle (gridDim.y==1 selects wide decode)
        k_attn_mfma<<<BM*NTILE, 256, 0, stream>>>(x, Kb, Vtb, ln1g, ln1b,
                                                  t_wq, t_bq, 0, CXH1);
        // k_prep after attn (writes alias dead Kb), before k_h1 (builds BH1)
        k_prep<<<32, 256, 0, stream>>>(s_wq, s_wk, s_bq, s_bk, s_wv, s_wo, g1w, w1, w2,
                                       t_wo, skw,
                                       Mt, wvT, woT, g1wT, w1T, w2T, BH1,
                                       vkw, vqw, sbb, (float*)cnt, zero_n);
        k_h1<<<dim3(BM, NTILE), 256, 0, stream>>>(x, BH1, t_bo, skb, 0, CXH1);
    } else {
        for (int s = 0; s < BM; ++s){
            k_kv<<<NN/32, 256, 0, stream>>>(x, ln1g, ln1b, t_wk, t_bk, t_wv, t_bv, s*NN, Kb, Vtb);
            k_attn_mfma<<<dim3(1, NTILE), 256, 0, stream>>>(x, Kb, Vtb, ln1g, ln1b,
                                                            t_wq, t_bq, s, CXH1);
        }
        k_prep<<<32, 256, 0, stream>>>(s_wq, s_wk, s_bq, s_bk, s_wv, s_wo, g1w, w1, w2,
                                       t_wo, skw,
                                       Mt, wvT, woT, g1wT, w1T, w2T, BH1,
                                       vkw, vqw, sbb, (float*)cnt, zero_n);
        k_h1<<<dim3(BM, NTILE), 256, 0, stream>>>(x, BH1, t_bo, skb, 0, CXH1);
    }

    // CSR build (cnt/fill zeroed by k_prep; stream-serial ordering)
    k_csr_hist   <<<NEDGE/256, 256, 0, stream>>>(ei, cnt);
    k_csr_scan   <<<1,        256, 0, stream>>>(cnt, roff);
    k_csr_scatter<<<NEDGE/256, 256, 0, stream>>>(ei, roff, fill, col);

    k_mix<<<NNODE/16, 256, 0, stream>>>(CXH1, ln2g, ln2b, Mt, wvT, woT, g1wT, w1T, w2T,
                                        vkw, vqw, sbb, s_bv, s_bo, b1, b2,
                                        ln3g, ln3b, g1as, g1ad, hw1, als1, ald1);

    k_gat_g1lin  <<<NNODE, 64, 0, stream>>>(roff, col, als1, ald1, hw1, g1b,
                                            g2w, g2as, g2ad, hw2, als2, ald2);
    k_gat_gather2f<<<NNODE, 64, 0, stream>>>(roff, col, als2, ald2, hw2, g2b, ffw, ffb, out);
}

// Round 9
// 384.440 us; speedup vs baseline: 1.2200x; 1.0134x over previous
//
#include <hip/hip_runtime.h>
#include <hip/hip_bf16.h>
#include <stdint.h>

// ---------------------------------------------------------------------------
// PFGAT. R27:
//   - REVERT R26 Ks swizzle (conflict counter proved invariant -> wrong model;
//     cost ~6us). Attn loop back to R25 addressing.
//   - FUSE k_h1 into the attn epilogue: unified 24KB SM buffer gains a
//     [64][168] Aext overlay (attn-out | x | 0); h1's 5x8 MFMA runs in-block
//     against prebuilt BH1; CXH1 written once. Saves k_h1 dispatch + 16MB CX
//     write + 16MB read + its staging.
//   - k_prep moved FIRST; its outputs (Mt..w2T, vk/vq/sbb, BH1, ~306KB) live
//     in d_out scratch (dead until the final gather2f write; out=458KB).
//   - CSR cnt/fill zeroing now a hipMemsetAsync after attn (gat region
//     aliases Kb which is live during attn).
// Rest identical to R25.
// ---------------------------------------------------------------------------

#define BB     4
#define TT     8
#define NN     2048
#define FIN    16
#define HID    128
#define BM     (BB*TT)            // 32 attention slices
#define PROWS  (BM*NN)            // 65536 rows
#define NHEADS 4
#define OUTCH  64
#define OUTF   14
#define NEDGE  32768
#define NEDGEB (NEDGE*BB)         // 131072
#define NNODE  (BB*NN)            // 8192
#define NETOT  (NEDGEB + NNODE)   // 139264 (edges + self loops)

#define TQ     64                 // query tile (rows per block)
#define NTILE  (NN/TQ)            // 32 query tiles per slice

typedef __hip_bfloat16 bf16;
typedef __attribute__((ext_vector_type(8))) short bf16x8;   // MFMA A/B frag
typedef __attribute__((ext_vector_type(4))) float f32x4;    // MFMA C/D frag

__device__ __forceinline__ float b2f(bf16 v){ return __bfloat162float(v); }
__device__ __forceinline__ bf16  f2b(float f){ return __float2bfloat16(f); }
__device__ __forceinline__ unsigned short bfbits(float f){
    union { bf16 h; unsigned short u; } cv; cv.h = f2b(f); return cv.u;
}

// ---------------------------------------------------------------------------
// K1 (R20): 32 rows/block, 256 threads. LN1 -> K (row-major) + Vt (key-tiled).
// ---------------------------------------------------------------------------
__global__ __launch_bounds__(256)
void k_kv(const float* __restrict__ x,
          const float* __restrict__ g1, const float* __restrict__ bb1,
          const float* __restrict__ wk, const float* __restrict__ bk,
          const float* __restrict__ wv, const float* __restrict__ bv,
          int in_off, bf16* __restrict__ K, bf16* __restrict__ Vt)
{
    const int r0 = blockIdx.x * 32;            // first local row of this block
    const int t  = threadIdx.x;

    __shared__ float wk_s[FIN][HID];           // 8 KB
    __shared__ float wv_s[FIN][HID];           // 8 KB
    __shared__ float xr_s[32][FIN+1];          // padded vs bank conflicts
    __shared__ float ln_s[32][FIN+1];

    // stage weights (float4) + x tile
    #pragma unroll
    for (int it = 0; it < 2; ++it){
        const int u = t + it*256;              // 512 float4 = 2048 floats
        ((float4*)wk_s)[u] = ((const float4*)wk)[u];
        ((float4*)wv_s)[u] = ((const float4*)wv)[u];
    }
    #pragma unroll
    for (int it = 0; it < 2; ++it){
        const int u = t + it*256;              // 512 floats = 32 rows x 16
        xr_s[u >> 4][u & 15] = x[(size_t)(r0 + in_off)*FIN + u];
    }
    __syncthreads();

    // LN1 per row (one thread per row)
    if (t < 32){
        float mu = 0.f;
        #pragma unroll
        for (int f = 0; f < FIN; ++f) mu += xr_s[t][f];
        mu *= (1.f/FIN);
        float var = 0.f;
        #pragma unroll
        for (int f = 0; f < FIN; ++f){ float d = xr_s[t][f]-mu; var += d*d; }
        var *= (1.f/FIN);
        const float inv = rsqrtf(var + 1e-5f);
        #pragma unroll
        for (int f = 0; f < FIN; ++f)
            ln_s[t][f] = (xr_s[t][f]-mu)*inv*g1[f] + bb1[f];
    }
    __syncthreads();

    // ---- K: thread covers channel pair hk/hk+1; key varies over passes ----
    {
        const int hk = (t & 63)*2;             // 0..126 even
        const float2 bkv = *(const float2*)&bk[hk];
        #pragma unroll
        for (int pass = 0; pass < 8; ++pass){
            const int key = pass*4 + (t >> 6);
            float a0 = bkv.x, a1 = bkv.y;
            #pragma unroll
            for (int f = 0; f < FIN; ++f){
                const float l = ln_s[key][f];
                const float2 wkv = ((const float2*)&wk_s[f][0])[t & 63];
                a0 += l*wkv.x; a1 += l*wkv.y;
            }
            const unsigned int pk =
                (unsigned int)bfbits(a0) | ((unsigned int)bfbits(a1) << 16);
            *(unsigned int*)(void*)&K[((size_t)(r0 + key))*HID + hk] = pk;
        }
    }

    // ---- V: thread covers key pair kk/kk+1; channel varies over passes ----
    {
        const int slice = r0 >> 11;
        const int kg    = (r0 & (NN-1)) >> 5;  // 32-key group within slice
        const size_t vbase = ((size_t)slice*(NN/32) + kg)*(size_t)HID*32;
        const int kk = (t & 15)*2;
        #pragma unroll
        for (int pass = 0; pass < 8; ++pass){
            const int h = (t >> 4) + 16*pass;
            float a0 = bv[h], a1 = a0;
            #pragma unroll
            for (int f = 0; f < FIN; ++f){
                const float wvf = wv_s[f][h];
                a0 += ln_s[kk  ][f] * wvf;
                a1 += ln_s[kk+1][f] * wvf;
            }
            const unsigned int pk =
                (unsigned int)bfbits(a0) | ((unsigned int)bfbits(a1) << 16);
            *(unsigned int*)(void*)&Vt[vbase + (size_t)h*32 + kk] = pk;
        }
    }
}

// ---------------------------------------------------------------------------
// K2 (R27): MFMA flash attn + FUSED h1 epilogue. Unified SM buffer:
//   [ Ps 2560 el | Ks 4352 el | Vs 5120 el ] = 12032 el = 24064 B
//   overlays: preamble wqs/xsb + Qv in Ks+ region; epilogue Aext[64][168]
//   spanning the whole SM. xs (fp32 x tile) stays live for Aext's x columns.
// ---------------------------------------------------------------------------
__global__ __launch_bounds__(256)
void k_attn_mfma(const float* __restrict__ x,
                 const bf16* __restrict__ K, const bf16* __restrict__ Vt,
                 const float* __restrict__ g1, const float* __restrict__ bb1,
                 const float* __restrict__ wq, const float* __restrict__ bq,
                 const bf16* __restrict__ BH1,
                 const float* __restrict__ t_bo, const float* __restrict__ skb,
                 int slice_off, bf16* __restrict__ CXH1)
{
    int slice, tile, kvslice;
    if (gridDim.y == 1){
        const int bid = (int)blockIdx.x;
        slice   = (bid & 7)*4 + ((bid >> 3) & 3);
        tile    = (NTILE-1) - (bid >> 5);
        kvslice = slice;
    } else {
        tile    = (NTILE-1) - (int)blockIdx.y;
        slice   = (int)blockIdx.x + slice_off;
        kvslice = (int)blockIdx.x;
    }
    const int q0    = tile*TQ;
    const int t     = threadIdx.x;
    const int w     = t >> 6;
    const int lane  = t & 63;
    const int quad  = lane >> 4;
    const int l16   = lane & 15;
    const int wr0   = w*16;

    // scale * log2(e) folded into Q so the softmax exp is a bare v_exp_f32.
    const float qscale = 0.08838834764831845f * 1.4426950408889634f;

    __shared__ float xs [TQ][FIN+1];               // 4352 B, live to epilogue
    __shared__ __align__(16) bf16 SM[12032];       // 24064 B unified
    bf16* Psb = SM;                                // [4][16][40]
    bf16* Ks  = SM + 2560;                         // [32][136]
    bf16* Vs  = SM + 6912;                         // [128][40]
    // overlays (time-multiplexed, barrier-protected):
    bf16 (*wqs)[32] = (bf16(*)[32])(SM + 2560);    // preamble [128][32]
    bf16 (*xsb)[32] = (bf16(*)[32])(SM + 6656);    // preamble [64][32]
    bf16 (*Qv)[136] = (bf16(*)[136])(SM + 2560);   // Q staging [64][136]
    bf16* AE  = SM;                                // epilogue [64][168]

    // ---- issue K/V tile-0 loads immediately (hidden under preamble) ----
    const size_t kb = (size_t)kvslice * NN * HID;
    const size_t vb = (size_t)kvslice * (size_t)(NN/32) * HID*32;
    const bf16* kptr = K  + kb + (size_t)t*8;
    const bf16* vptr = Vt + vb + (size_t)t*8;
    bf16x8 kreg0, kreg1, vreg0, vreg1;
    kreg0 = *(const bf16x8*)(const void*)(kptr);
    kreg1 = *(const bf16x8*)(const void*)(kptr + 2048);
    vreg0 = *(const bf16x8*)(const void*)(vptr);
    vreg1 = *(const bf16x8*)(const void*)(vptr + 2048);

    // ---- stage x (fp32) and wq (bf16, pre-scaled, k-padded to 32) ----
    #pragma unroll
    for (int it = 0; it < 4; ++it){
        const int u = t + it*256;                  // 1024 = 64*16
        xs[u >> 4][u & 15] = x[((size_t)slice*NN + q0)*FIN + u];
    }
    #pragma unroll
    for (int it = 0; it < 8; ++it){
        const int u = t + it*256;                  // 2048 = 16*128
        const int f = u >> 7, ch = u & 127;
        wqs[ch][f] = f2b(wq[u] * qscale);
    }
    {   // zero-pad k = 16..31 of wqs
        const bf16x8 z8 = {0,0,0,0,0,0,0,0};
        const int ch = t >> 1, k0 = 16 + (t & 1)*8;
        *(bf16x8*)(void*)&wqs[ch][k0] = z8;
    }
    __syncthreads();

    // ---- LN1 into xsb (bf16, k-padded) ----
    if (t < TQ){
        float mu = 0.f;
        #pragma unroll
        for (int f = 0; f < FIN; ++f) mu += xs[t][f];
        mu *= (1.f/FIN);
        float var = 0.f;
        #pragma unroll
        for (int f = 0; f < FIN; ++f){ float d = xs[t][f]-mu; var += d*d; }
        var *= (1.f/FIN);
        const float inv = rsqrtf(var + 1e-5f);
        bf16x8 v0, v1;
        #pragma unroll
        for (int f = 0; f < 8; ++f)
            v0[f] = (short)bfbits((xs[t][f]-mu)*inv*g1[f] + bb1[f]);
        #pragma unroll
        for (int f = 0; f < 8; ++f)
            v1[f] = (short)bfbits((xs[t][8+f]-mu)*inv*g1[8+f] + bb1[8+f]);
        const bf16x8 z8 = {0,0,0,0,0,0,0,0};
        *(bf16x8*)(void*)&xsb[t][0]  = v0;
        *(bf16x8*)(void*)&xsb[t][8]  = v1;
        *(bf16x8*)(void*)&xsb[t][16] = z8;
        *(bf16x8*)(void*)&xsb[t][24] = z8;
    }
    __syncthreads();

    // ---- Q projection via MFMA: Qv = (LN1(x) @ wq + bq) * qscale ----
    {
        const bf16x8 af = *(const bf16x8*)(const void*)&xsb[wr0 + l16][quad*8];
        f32x4 Cq[8];
        #pragma unroll
        for (int ct = 0; ct < 8; ++ct){
            const bf16x8 bfv = *(const bf16x8*)(const void*)&wqs[ct*16 + l16][quad*8];
            Cq[ct] = __builtin_amdgcn_mfma_f32_16x16x32_bf16(
                         af, bfv, (f32x4){0.f,0.f,0.f,0.f}, 0, 0, 0);
        }
        __syncthreads();   // all waves done READING wqs/xsb before Qv overwrite
        #pragma unroll
        for (int ct = 0; ct < 8; ++ct){
            const int col = ct*16 + l16;
            const float bqs = bq[col] * qscale;
            #pragma unroll
            for (int r = 0; r < 4; ++r)
                Qv[wr0 + quad*4 + r][col] = f2b(Cq[ct][r] + bqs);
        }
    }
    __syncthreads();   // Qv ready

    bf16x8 qf[4];
    #pragma unroll
    for (int ks = 0; ks < 4; ++ks)
        qf[ks] = *(const bf16x8*)(const void*)&Qv[wr0 + l16][ks*32 + quad*8];
    __syncthreads();   // qf reads done; SM may be overwritten by K/V staging

    f32x4 O[8];
    #pragma unroll
    for (int ct = 0; ct < 8; ++ct) O[ct] = (f32x4){0.f,0.f,0.f,0.f};
    float l_[4] = {0.f,0.f,0.f,0.f};

    const int jend_blk = q0 + TQ - 1;
    const int my_jmax  = q0 + wr0 + 15;
    const int brow = q0 + wr0 + quad*4;

    // precomputed LDS staging addresses (constant across iterations)
    bf16* ksA = &Ks[((t      ) >> 4)*136 + ((t      ) & 15)*8];
    bf16* ksB = &Ks[((t + 256) >> 4)*136 + ((t + 256) & 15)*8];
    bf16* vsA = &Vs[((t      ) >> 2)*40  + ((t      ) &  3)*8];
    bf16* vsB = &Vs[((t + 256) >> 2)*40  + ((t + 256) &  3)*8];
    const bf16* kr0 = &Ks[(2*l16    )*136 + quad*8];
    const bf16* kr1 = &Ks[(2*l16 + 1)*136 + quad*8];
    const bf16* vr  = &Vs[l16*40 + quad*8];
    bf16* psw = &Psb[w*640 + (quad*4)*40 + 2*l16];
    const bf16* psr = &Psb[w*640 + l16*40 + quad*8];

    for (int j0 = 0; j0 <= jend_blk; j0 += 32){
        // regs -> LDS (waits on the loads issued last iteration)
        *(bf16x8*)(void*)ksA = kreg0;
        *(bf16x8*)(void*)ksB = kreg1;
        *(bf16x8*)(void*)vsA = vreg0;
        *(bf16x8*)(void*)vsB = vreg1;
        __syncthreads();

        // issue next tile's loads (T14: in flight across compute + barrier)
        if (j0 + 32 <= jend_blk){
            const size_t off = (size_t)(j0 + 32)*128;
            kreg0 = *(const bf16x8*)(const void*)(kptr + off);
            kreg1 = *(const bf16x8*)(const void*)(kptr + off + 2048);
            vreg0 = *(const bf16x8*)(const void*)(vptr + off);
            vreg1 = *(const bf16x8*)(const void*)(vptr + off + 2048);
        }

        if (j0 <= my_jmax){
            f32x4 S0 = (f32x4){0.f,0.f,0.f,0.f}, S1 = S0;
            #pragma unroll
            for (int ks = 0; ks < 4; ++ks){
                const bf16x8 kf0 = *(const bf16x8*)(const void*)(kr0 + ks*32);
                const bf16x8 kf1 = *(const bf16x8*)(const void*)(kr1 + ks*32);
                S0 = __builtin_amdgcn_mfma_f32_16x16x32_bf16(qf[ks], kf0, S0, 0, 0, 0);
                S1 = __builtin_amdgcn_mfma_f32_16x16x32_bf16(qf[ks], kf1, S1, 0, 0, 0);
            }
            // lane's two keys are adjacent: c0 = j0+2*l16, c1 = c0+1
            float sv0[4], sv1[4];
            if (j0 + 31 > q0 + wr0){                 // diagonal block: mask
                const int c0j = j0 + 2*l16, c1j = c0j + 1;
                #pragma unroll
                for (int r = 0; r < 4; ++r){
                    sv0[r] = (c0j <= brow + r) ? S0[r] : -1e30f;
                    sv1[r] = (c1j <= brow + r) ? S1[r] : -1e30f;
                }
            } else {                                  // strictly-lower: no mask
                #pragma unroll
                for (int r = 0; r < 4; ++r){ sv0[r] = S0[r]; sv1[r] = S1[r]; }
            }
            #pragma unroll
            for (int r = 0; r < 4; ++r){
                const float e0 = __builtin_amdgcn_exp2f(sv0[r]);
                const float e1 = __builtin_amdgcn_exp2f(sv1[r]);
                l_[r] += e0 + e1;
                const unsigned int pk =
                    (unsigned int)bfbits(e0) | ((unsigned int)bfbits(e1) << 16);
                *(unsigned int*)(void*)(psw + r*40) = pk;
            }
            const bf16x8 pf = *(const bf16x8*)(const void*)psr;
            #pragma unroll
            for (int ct = 0; ct < 8; ++ct){
                const bf16x8 vf = *(const bf16x8*)(const void*)(vr + ct*16*40);
                O[ct] = __builtin_amdgcn_mfma_f32_16x16x32_bf16(pf, vf, O[ct], 0, 0, 0);
            }
        }
        __syncthreads();
    }

    // ---- epilogue 1: normalize O -> AE cols 0..127 (SM reads all done) ----
    {
        float inv[4];
        #pragma unroll
        for (int r = 0; r < 4; ++r){
            float rs = l_[r];
            rs += __shfl_xor(rs, 1);
            rs += __shfl_xor(rs, 2);
            rs += __shfl_xor(rs, 4);
            rs += __shfl_xor(rs, 8);
            inv[r] = 1.f/rs;
        }
        #pragma unroll
        for (int ct = 0; ct < 8; ++ct)
        #pragma unroll
        for (int r = 0; r < 4; ++r)
            AE[(wr0 + quad*4 + r)*168 + ct*16 + l16] = f2b(O[ct][r]*inv[r]);
    }
    // AE cols 128..143 = x (xs still live); cols 144..167 = 0
    #pragma unroll
    for (int it = 0; it < 4; ++it){
        const int u = t + it*256;                  // 1024 = 64*16
        AE[(u >> 4)*168 + 128 + (u & 15)] = f2b(xs[u >> 4][u & 15]);
    }
    #pragma unroll
    for (int it = 0; it < 6; ++it){
        const int u = t + it*256;                  // 1536 = 64*24
        const int row = u/24;
        AE[row*168 + 144 + (u - row*24)] = f2b(0.f);
    }
    __syncthreads();

    // ---- epilogue 2: fused h1 GEMM: (attn|x|0) @ BH1 + (t_bo+skb) ----
    f32x4 O2[8];
    #pragma unroll
    for (int ct = 0; ct < 8; ++ct) O2[ct] = (f32x4){0.f,0.f,0.f,0.f};
    #pragma unroll
    for (int k5 = 0; k5 < 5; ++k5){
        const bf16x8 af = *(const bf16x8*)(const void*)
            &AE[(wr0 + l16)*168 + k5*32 + quad*8];
        #pragma unroll
        for (int ct = 0; ct < 8; ++ct){
            const bf16x8 bfv = *(const bf16x8*)(const void*)
                (BH1 + (size_t)(ct*16 + l16)*168 + k5*32 + quad*8);
            O2[ct] = __builtin_amdgcn_mfma_f32_16x16x32_bf16(af, bfv, O2[ct], 0, 0, 0);
        }
    }
    __syncthreads();
    #pragma unroll
    for (int ct = 0; ct < 8; ++ct){
        const int col = ct*16 + l16;
        const float bias = t_bo[col] + skb[col];
        #pragma unroll
        for (int r = 0; r < 4; ++r)
            AE[(wr0 + quad*4 + r)*168 + col] = f2b(O2[ct][r] + bias);
    }
    __syncthreads();
    {
        const int row = t >> 2, ch0 = (t & 3)*32;
        bf16* dst = CXH1 + ((size_t)slice*NN + q0 + row)*HID + ch0;
        #pragma unroll
        for (int c = 0; c < 4; ++c)
            *(bf16x8*)(void*)(dst + c*8) =
                *(const bf16x8*)(const void*)&AE[row*168 + ch0 + c*8];
    }
}

// ---------------------------------------------------------------------------
// K_PREP (R27): runs FIRST; outputs to d_out scratch. No zeroing here.
// blocks 0-15: Mt; 16: vk/vq/sbb; 17-21: bf16 transposed weights; 22: BH1.
// ---------------------------------------------------------------------------
__global__ __launch_bounds__(256)
void k_prep(const float* __restrict__ s_wq, const float* __restrict__ s_wk,
            const float* __restrict__ bq, const float* __restrict__ bk,
            const float* __restrict__ s_wv, const float* __restrict__ s_wo,
            const float* __restrict__ g1w, const float* __restrict__ w1,
            const float* __restrict__ w2,
            const float* __restrict__ t_wo, const float* __restrict__ skw,
            bf16* __restrict__ Mt, bf16* __restrict__ wvT, bf16* __restrict__ woT,
            bf16* __restrict__ g1wT, bf16* __restrict__ w1T, bf16* __restrict__ w2T,
            bf16* __restrict__ BH1,
            float* __restrict__ vk, float* __restrict__ vq, float* __restrict__ sbb)
{
    const int b = blockIdx.x;          // 0..31
    const int t = threadIdx.x;
    __shared__ float wq_s[HID*HID];    // 64 KB
    __shared__ float wk_s[8][HID];
    if (b < 16){
        for (int u = t; u < HID*HID; u += 256) wq_s[u] = s_wq[u];
        for (int u = t; u < 8*HID;   u += 256) ((float*)wk_s)[u] = s_wk[b*8*HID + u];
        __syncthreads();
        #pragma unroll
        for (int i = 0; i < 4; ++i){
            const int e = t + i*256;
            const int cl = e >> 7, a = e & 127;     // Mt row c = b*8+cl, col a
            float acc = 0.f;
            for (int hh = 0; hh < HID; ++hh) acc += wk_s[cl][hh]*wq_s[a*HID + hh];
            Mt[(size_t)(b*8 + cl)*HID + a] = f2b(acc);
        }
    } else if (b == 16){
        if (t < HID){
            float a1 = 0.f, a2 = 0.f;
            for (int hh = 0; hh < HID; ++hh){
                a1 += bq[hh]*s_wk[t*HID + hh];
                a2 += s_wq[t*HID + hh]*bk[hh];
            }
            vk[t] = a1; vq[t] = a2;
            if (t == 0){
                float s = 0.f;
                for (int hh = 0; hh < HID; ++hh) s += bq[hh]*bk[hh];
                *sbb = s;
            }
        }
    } else if (b == 17){
        for (int u = t; u < HID*HID; u += 256){
            const int c = u >> 7, h = u & 127;
            wvT[h*HID + c] = f2b(s_wv[u]);
        }
    } else if (b == 18){
        for (int u = t; u < HID*HID; u += 256){
            const int c = u >> 7, h = u & 127;
            woT[h*HID + c] = f2b(s_wo[u]);
        }
    } else if (b == 19){
        for (int u = t; u < HID*HID; u += 256){
            const int c = u >> 7, h = u & 127;
            g1wT[h*HID + c] = f2b(g1w[u]);
        }
    } else if (b == 20){
        for (int u = t; u < HID*2*HID; u += 256){
            const int k = u >> 8, n = u & 255;
            w1T[n*HID + k] = f2b(w1[u]);
        }
    } else if (b == 21){
        for (int u = t; u < 2*HID*HID; u += 256){
            const int k = u >> 7, n = u & 127;
            w2T[(size_t)n*2*HID + k] = f2b(w2[u]);
        }
    } else if (b == 22){
        // BH1[c][k]: k<128 -> t_wo[k][c]; 128<=k<144 -> skw[k-128][c]; else 0
        for (int u = t; u < HID*168; u += 256){
            const int c = u / 168, k = u - c*168;
            float v = 0.f;
            if (k < 128)      v = t_wo[k*HID + c];
            else if (k < 144) v = skw[(k-128)*HID + c];
            BH1[u] = f2b(v);
        }
    }
}

// ---------------------------------------------------------------------------
// K3 (R18, MFMA): 16 nodes/block, 256 thr (4 waves).
// ---------------------------------------------------------------------------
__global__ __launch_bounds__(256)
void k_mix(const bf16* __restrict__ H1,
           const float* __restrict__ ln2g, const float* __restrict__ ln2b,
           const bf16* __restrict__ Mt, const bf16* __restrict__ wvT,
           const bf16* __restrict__ woT, const bf16* __restrict__ g1wT,
           const bf16* __restrict__ w1T, const bf16* __restrict__ w2T,
           const float* __restrict__ vk, const float* __restrict__ vq,
           const float* __restrict__ sbbp,
           const float* __restrict__ s_bv, const float* __restrict__ s_bo,
           const float* __restrict__ bm1, const float* __restrict__ bm2,
           const float* __restrict__ ln3g, const float* __restrict__ ln3b,
           const float* __restrict__ g1as, const float* __restrict__ g1ad,
           bf16* __restrict__ hw1, float* __restrict__ als1, float* __restrict__ ald1)
{
    const int blk0 = blockIdx.x * 16;         // first node
    const int bb = blk0 >> 11, s0 = blk0 & (NN-1);
    const int t = threadIdx.x;
    const int w = t >> 6;
    const int lane = t & 63;
    const int quad = lane >> 4;
    const int l16  = lane & 15;

    __shared__ bf16  h1s[16][TT][136];   // 34816 B
    __shared__ bf16  ZA [16][136];       // 4352 B (A staging, reused)
    __shared__ bf16  HLs[16][264];       // 8448 B (MLP hidden)
    __shared__ float Cw [16][128];       // 8192 B (fp32 work)
    __shared__ float ln2gs[HID], ln2bs[HID];
    __shared__ float mu_s[16][TT], inv_s[16][TT];
    __shared__ float ps[16][TT];
    __shared__ float sbq_s[16], mu3[16], inv3[16];

    // ---- S1: stage h1 (bf16) + ln2 params ----
    for (int m = 0; m < TT; ++m){
        const bf16* src = H1 + ((size_t)(bb*TT + m)*NN + s0)*HID;
        const int node = t >> 4, c8 = t & 15;
        *(bf16x8*)(void*)&h1s[node][m][c8*8] =
            *(const bf16x8*)(const void*)(src + (size_t)node*HID + c8*8);
    }
    if (t < HID){ ln2gs[t] = ln2g[t]; ln2bs[t] = ln2b[t]; }
    __syncthreads();

    // ---- S2: LN2 stats (pair of threads per (node,m)) ----
    {
        const int idx = t >> 1, half = t & 1;
        const int node = idx >> 3, m = idx & 7;
        float sum = 0.f, sq = 0.f;
        for (int c = half; c < HID; c += 2){
            const float v = b2f(h1s[node][m][c]);
            sum += v; sq += v*v;
        }
        sum += __shfl_xor(sum, 1); sq += __shfl_xor(sq, 1);
        if (half == 0){
            const float mu = sum*(1.f/HID);
            const float var = sq*(1.f/HID) - mu*mu;
            mu_s[node][m] = mu;
            inv_s[node][m] = rsqrtf(var + 1e-5f);
        }
    }
    __syncthreads();

    // ---- S3: Z7 -> ZA; sbq partial ----
    #pragma unroll
    for (int i = 0; i < 8; ++i){
        const int idx = t + i*256;               // 2048
        const int n = idx >> 7, c = idx & 127;
        const float z = (b2f(h1s[n][7][c]) - mu_s[n][7])*inv_s[n][7]*ln2gs[c] + ln2bs[c];
        ZA[n][c] = f2b(z);
    }
    if (t < 128){
        const int node = t >> 3, l8 = t & 7;
        float sp = 0.f;
        for (int c = l8; c < HID; c += 8){
            const float z = (b2f(h1s[node][7][c]) - mu_s[node][7])*inv_s[node][7]*ln2gs[c] + ln2bs[c];
            sp += vq[c]*z;
        }
        sp += __shfl_xor(sp, 1);
        sp += __shfl_xor(sp, 2);
        sp += __shfl_xor(sp, 4);
        if (l8 == 0) sbq_s[node] = sp;
    }
    __syncthreads();

    // ---- S4: G1 rp = Z7@Mt + vk -> Cw ----
    {
        bf16x8 af[4];
        #pragma unroll
        for (int ks = 0; ks < 4; ++ks)
            af[ks] = *(const bf16x8*)(const void*)&ZA[l16][ks*32 + quad*8];
        __syncthreads();
        f32x4 C0 = (f32x4){0,0,0,0}, C1 = C0;
        #pragma unroll
        for (int ks = 0; ks < 4; ++ks){
            const bf16x8 b0 = *(const bf16x8*)(const void*)(Mt + (size_t)(w*32      + l16)*HID + ks*32 + quad*8);
            const bf16x8 b1 = *(const bf16x8*)(const void*)(Mt + (size_t)(w*32 + 16 + l16)*HID + ks*32 + quad*8);
            C0 = __builtin_amdgcn_mfma_f32_16x16x32_bf16(af[ks], b0, C0, 0, 0, 0);
            C1 = __builtin_amdgcn_mfma_f32_16x16x32_bf16(af[ks], b1, C1, 0, 0, 0);
        }
        const int c0 = w*32 + l16, c1 = c0 + 16;
        #pragma unroll
        for (int r = 0; r < 4; ++r){
            Cw[quad*4 + r][c0] = C0[r] + vk[c0];
            Cw[quad*4 + r][c1] = C1[r] + vk[c1];
        }
    }
    __syncthreads();

    // ---- S5: scr -> ps ----
    {
        const int idx = t >> 1, half = t & 1;
        const int node = idx >> 3, m = idx & 7;
        const float mu = mu_s[node][m], iv = inv_s[node][m];
        float d = 0.f;
        for (int c = half; c < HID; c += 2){
            const float z = (b2f(h1s[node][m][c]) - mu)*iv*ln2gs[c] + ln2bs[c];
            d += Cw[node][c]*z;
        }
        d += __shfl_xor(d, 1);
        if (half == 0)
            ps[node][m] = (d + sbq_s[node] + *sbbp) * 0.08838834764831845f;
    }
    __syncthreads();
    // ---- S6: softmax per node ----
    if (t < 16){
        float mx = -1e30f;
        #pragma unroll
        for (int m = 0; m < TT; ++m) mx = fmaxf(mx, ps[t][m]);
        float p[TT], se = 0.f;
        #pragma unroll
        for (int m = 0; m < TT; ++m){ p[m] = __expf(ps[t][m]-mx); se += p[m]; }
        const float isum = 1.f/se;
        #pragma unroll
        for (int m = 0; m < TT; ++m) ps[t][m] = p[m]*isum;
    }
    __syncthreads();
    // ---- S7: zbar -> ZA ----
    #pragma unroll
    for (int i = 0; i < 8; ++i){
        const int idx = t + i*256;
        const int n = idx >> 7, c = idx & 127;
        const float gc = ln2gs[c], bc = ln2bs[c];
        float acc = 0.f;
        #pragma unroll
        for (int m = 0; m < TT; ++m){
            const float z = (b2f(h1s[n][m][c]) - mu_s[n][m])*inv_s[n][m]*gc + bc;
            acc += ps[n][m]*z;
        }
        ZA[n][c] = f2b(acc);
    }
    __syncthreads();

    // ---- S8: G2 cx2 = ZB@wvT + bv -> ZA ----
    {
        bf16x8 af[4];
        #pragma unroll
        for (int ks = 0; ks < 4; ++ks)
            af[ks] = *(const bf16x8*)(const void*)&ZA[l16][ks*32 + quad*8];
        __syncthreads();
        f32x4 C0 = (f32x4){0,0,0,0}, C1 = C0;
        #pragma unroll
        for (int ks = 0; ks < 4; ++ks){
            const bf16x8 b0 = *(const bf16x8*)(const void*)(wvT + (size_t)(w*32      + l16)*HID + ks*32 + quad*8);
            const bf16x8 b1 = *(const bf16x8*)(const void*)(wvT + (size_t)(w*32 + 16 + l16)*HID + ks*32 + quad*8);
            C0 = __builtin_amdgcn_mfma_f32_16x16x32_bf16(af[ks], b0, C0, 0, 0, 0);
            C1 = __builtin_amdgcn_mfma_f32_16x16x32_bf16(af[ks], b1, C1, 0, 0, 0);
        }
        const int c0 = w*32 + l16, c1 = c0 + 16;
        #pragma unroll
        for (int r = 0; r < 4; ++r){
            ZA[quad*4 + r][c0] = f2b(C0[r] + s_bv[c0]);
            ZA[quad*4 + r][c1] = f2b(C1[r] + s_bv[c1]);
        }
    }
    __syncthreads();

    // ---- S9: G3 h2 = cx2@woT + bo + h1[7] -> Cw ----
    {
        bf16x8 af[4];
        #pragma unroll
        for (int ks = 0; ks < 4; ++ks)
            af[ks] = *(const bf16x8*)(const void*)&ZA[l16][ks*32 + quad*8];
        __syncthreads();
        f32x4 C0 = (f32x4){0,0,0,0}, C1 = C0;
        #pragma unroll
        for (int ks = 0; ks < 4; ++ks){
            const bf16x8 b0 = *(const bf16x8*)(const void*)(woT + (size_t)(w*32      + l16)*HID + ks*32 + quad*8);
            const bf16x8 b1 = *(const bf16x8*)(const void*)(woT + (size_t)(w*32 + 16 + l16)*HID + ks*32 + quad*8);
            C0 = __builtin_amdgcn_mfma_f32_16x16x32_bf16(af[ks], b0, C0, 0, 0, 0);
            C1 = __builtin_amdgcn_mfma_f32_16x16x32_bf16(af[ks], b1, C1, 0, 0, 0);
        }
        const int c0 = w*32 + l16, c1 = c0 + 16;
        #pragma unroll
        for (int r = 0; r < 4; ++r){
            const int node = quad*4 + r;
            Cw[node][c0] = C0[r] + s_bo[c0] + b2f(h1s[node][7][c0]);
            Cw[node][c1] = C1[r] + s_bo[c1] + b2f(h1s[node][7][c1]);
        }
    }
    __syncthreads();

    // ---- S10: LN3 stats (16-lane group per node) ----
    {
        const int node = t >> 4, part = t & 15;
        float sum = 0.f, sq = 0.f;
        for (int c = part; c < HID; c += 16){
            const float v = Cw[node][c];
            sum += v; sq += v*v;
        }
        sum += __shfl_xor(sum, 1); sq += __shfl_xor(sq, 1);
        sum += __shfl_xor(sum, 2); sq += __shfl_xor(sq, 2);
        sum += __shfl_xor(sum, 4); sq += __shfl_xor(sq, 4);
        sum += __shfl_xor(sum, 8); sq += __shfl_xor(sq, 8);
        if (part == 0){
            const float mu = sum*(1.f/HID);
            const float var = sq*(1.f/HID) - mu*mu;
            mu3[node] = mu;
            inv3[node] = rsqrtf(var + 1e-5f);
        }
    }
    __syncthreads();
    // ---- S11: z3 -> ZA ----
    #pragma unroll
    for (int i = 0; i < 8; ++i){
        const int idx = t + i*256;
        const int n = idx >> 7, c = idx & 127;
        ZA[n][c] = f2b((Cw[n][c] - mu3[n])*inv3[n]*ln3g[c] + ln3b[c]);
    }
    __syncthreads();

    // ---- S12: G4 hl = relu(z3@w1T + b1) -> HLs (ncols 256) ----
    {
        bf16x8 af[4];
        #pragma unroll
        for (int ks = 0; ks < 4; ++ks)
            af[ks] = *(const bf16x8*)(const void*)&ZA[l16][ks*32 + quad*8];
        __syncthreads();
        f32x4 C[4];
        #pragma unroll
        for (int u = 0; u < 4; ++u) C[u] = (f32x4){0,0,0,0};
        #pragma unroll
        for (int ks = 0; ks < 4; ++ks){
            #pragma unroll
            for (int u = 0; u < 4; ++u){
                const bf16x8 bfv = *(const bf16x8*)(const void*)
                    (w1T + (size_t)(w*64 + u*16 + l16)*HID + ks*32 + quad*8);
                C[u] = __builtin_amdgcn_mfma_f32_16x16x32_bf16(af[ks], bfv, C[u], 0, 0, 0);
            }
        }
        #pragma unroll
        for (int u = 0; u < 4; ++u){
            const int col = w*64 + u*16 + l16;
            const float bias = bm1[col];
            #pragma unroll
            for (int r = 0; r < 4; ++r)
                HLs[quad*4 + r][col] = f2b(fmaxf(C[u][r] + bias, 0.f));
        }
    }
    __syncthreads();

    // ---- S13: G5 hn = hl@w2T + b2 + h2 -> ZA (k=256) ----
    {
        bf16x8 af[8];
        #pragma unroll
        for (int ks = 0; ks < 8; ++ks)
            af[ks] = *(const bf16x8*)(const void*)&HLs[l16][ks*32 + quad*8];
        __syncthreads();
        f32x4 C0 = (f32x4){0,0,0,0}, C1 = C0;
        #pragma unroll
        for (int ks = 0; ks < 8; ++ks){
            const bf16x8 b0 = *(const bf16x8*)(const void*)(w2T + (size_t)(w*32      + l16)*2*HID + ks*32 + quad*8);
            const bf16x8 b1 = *(const bf16x8*)(const void*)(w2T + (size_t)(w*32 + 16 + l16)*2*HID + ks*32 + quad*8);
            C0 = __builtin_amdgcn_mfma_f32_16x16x32_bf16(af[ks], b0, C0, 0, 0, 0);
            C1 = __builtin_amdgcn_mfma_f32_16x16x32_bf16(af[ks], b1, C1, 0, 0, 0);
        }
        const int c0 = w*32 + l16, c1 = c0 + 16;
        #pragma unroll
        for (int r = 0; r < 4; ++r){
            const int node = quad*4 + r;
            ZA[node][c0] = f2b(C0[r] + bm2[c0] + Cw[node][c0]);
            ZA[node][c1] = f2b(C1[r] + bm2[c1] + Cw[node][c1]);
        }
    }
    __syncthreads();

    // ---- S14: G6 a = hn@g1wT -> Cw ----
    {
        bf16x8 af[4];
        #pragma unroll
        for (int ks = 0; ks < 4; ++ks)
            af[ks] = *(const bf16x8*)(const void*)&ZA[l16][ks*32 + quad*8];
        __syncthreads();
        f32x4 C0 = (f32x4){0,0,0,0}, C1 = C0;
        #pragma unroll
        for (int ks = 0; ks < 4; ++ks){
            const bf16x8 b0 = *(const bf16x8*)(const void*)(g1wT + (size_t)(w*32      + l16)*HID + ks*32 + quad*8);
            const bf16x8 b1 = *(const bf16x8*)(const void*)(g1wT + (size_t)(w*32 + 16 + l16)*HID + ks*32 + quad*8);
            C0 = __builtin_amdgcn_mfma_f32_16x16x32_bf16(af[ks], b0, C0, 0, 0, 0);
            C1 = __builtin_amdgcn_mfma_f32_16x16x32_bf16(af[ks], b1, C1, 0, 0, 0);
        }
        const int c0 = w*32 + l16, c1 = c0 + 16;
        #pragma unroll
        for (int r = 0; r < 4; ++r){
            Cw[quad*4 + r][c0] = C0[r];
            Cw[quad*4 + r][c1] = C1[r];
        }
    }
    __syncthreads();

    // ---- S15: outputs ----
    #pragma unroll
    for (int i = 0; i < 8; ++i){
        const int idx = t + i*256;                // node*128 + c
        hw1[(size_t)blk0*HID + idx] = f2b(((const float*)Cw)[idx]);
    }
    if (t < 64){
        const int node = t >> 2, hd = t & 3;
        float s1 = 0.f, s2 = 0.f;
        for (int j = 0; j < 32; ++j){
            const int c = hd*32 + j;
            const float a = Cw[node][c];
            s1 += a*g1as[c];
            s2 += a*g1ad[c];
        }
        als1[(blk0 + node)*NHEADS + hd] = s1;
        ald1[(blk0 + node)*NHEADS + hd] = s2;
    }
}

// ---------------------------------------------------------------------------
// CSR build (R21): edge list is batch-invariant -> build once.
// ---------------------------------------------------------------------------
__global__ void k_csr_hist(const int* __restrict__ ei, int* __restrict__ cnt)
{
    const int e = blockIdx.x*blockDim.x + threadIdx.x;
    if (e >= NEDGE) return;
    const int s = ei[e], d = ei[NEDGE + e];
    if (s != d) atomicAdd(&cnt[d], 1);
}

__global__ __launch_bounds__(256)
void k_csr_scan(const int* __restrict__ cnt, int* __restrict__ roff)
{
    const int t = threadIdx.x;                 // 256; 8 bins each
    __shared__ int part[256];
    int loc[8]; int s = 0;
    #pragma unroll
    for (int i = 0; i < 8; ++i){ loc[i] = s; s += cnt[t*8 + i]; }
    part[t] = s;
    __syncthreads();
    if (t == 0){
        int acc = 0;
        for (int i = 0; i < 256; ++i){ const int v = part[i]; part[i] = acc; acc += v; }
    }
    __syncthreads();
    const int base_ = part[t];
    #pragma unroll
    for (int i = 0; i < 8; ++i) roff[t*8 + i] = base_ + loc[i];
    if (t == 255) roff[2048] = base_ + s;
}

__global__ void k_csr_scatter(const int* __restrict__ ei, const int* __restrict__ roff,
                              int* __restrict__ fill, int* __restrict__ col)
{
    const int e = blockIdx.x*blockDim.x + threadIdx.x;
    if (e >= NEDGE) return;
    const int s = ei[e], d = ei[NEDGE + e];
    if (s != d){
        const int p = roff[d] + atomicAdd(&fill[d], 1);
        col[p] = s;
    }
}

// ---------------------------------------------------------------------------
// Fused GAT layer-1 gather + GAT2 linear (R25): one wave per node.
// ---------------------------------------------------------------------------
__global__ __launch_bounds__(64)
void k_gat_g1lin(const int* __restrict__ roff, const int* __restrict__ col,
                 const float* __restrict__ als, const float* __restrict__ ald,
                 const bf16* __restrict__ hw, const float* __restrict__ g1b,
                 const float* __restrict__ W,
                 const float* __restrict__ asrc, const float* __restrict__ adst,
                 bf16* __restrict__ hw2, float* __restrict__ al2s, float* __restrict__ al2d)
{
    const int nid = blockIdx.x;                 // 0..NNODE-1
    const int d   = nid & (NN-1);
    const int gb  = nid & ~(NN-1);              // batch node offset
    const int c2  = threadIdx.x;                // 0..63 -> channels 2c2, 2c2+1
    const int hd  = c2 >> 4;                    // (2*c2)>>5, shared by the pair
    const float ad = ald[nid*NHEADS + hd];

    float av0 = 0.f, av1 = 0.f, accd = 0.f;
    const int e0 = roff[d], e1 = roff[d+1];
    int sn = (e0 < e1) ? col[e0] : 0;
    for (int e = e0; e < e1; ++e){
        const int s = sn + gb;
        sn = (e+1 < e1) ? col[e+1] : 0;         // prefetch next col
        float a = als[s*NHEADS + hd] + ad;
        a = a > 0.f ? a : 0.2f*a;
        const float ex = __expf(a);
        const unsigned int pk =
            *(const unsigned int*)(const void*)&hw[(size_t)s*HID + 2*c2];
        av0 += ex * __uint_as_float(pk << 16);            // ch 2c2
        av1 += ex * __uint_as_float(pk & 0xffff0000u);    // ch 2c2+1
        accd += ex;
    }
    {   // self loop
        float a = als[nid*NHEADS + hd] + ad;
        a = a > 0.f ? a : 0.2f*a;
        const float ex = __expf(a);
        const unsigned int pk =
            *(const unsigned int*)(const void*)&hw[(size_t)nid*HID + 2*c2];
        av0 += ex * __uint_as_float(pk << 16);
        av1 += ex * __uint_as_float(pk & 0xffff0000u);
        accd += ex;
    }
    __shared__ float hrs[HID];
    {
        float v0 = av0/accd + g1b[2*c2];
        float v1 = av1/accd + g1b[2*c2+1];
        v0 = v0 > 0.f ? v0 : expm1f(v0);
        v1 = v1 > 0.f ? v1 : expm1f(v1);
        *(float2*)(void*)&hrs[2*c2] = make_float2(v0, v1);
    }
    __syncthreads();   // single wave: compiles to lgkmcnt wait; orders LDS

    const int c = c2;  // output channel 0..63
    float a = 0.f;
    for (int k = 0; k < HID; ++k) a += hrs[k]*W[k*OUTCH + c];
    hw2[(size_t)nid*OUTCH + c] = f2b(a);
    float s1 = a*asrc[c], s2 = a*adst[c];
    #pragma unroll
    for (int off = 32; off > 0; off >>= 1){
        s1 += __shfl_down(s1, off);
        s2 += __shfl_down(s2, off);
    }
    if (c == 0){ al2s[nid] = s1; al2d[nid] = s2; }
}

// ---------------------------------------------------------------------------
// GAT layer 2 gather + final FFN (R21).
// ---------------------------------------------------------------------------
__global__ __launch_bounds__(64)
void k_gat_gather2f(const int* __restrict__ roff, const int* __restrict__ col,
                    const float* __restrict__ als, const float* __restrict__ ald,
                    const bf16* __restrict__ hw2, const float* __restrict__ g2b,
                    const float* __restrict__ fw, const float* __restrict__ fb,
                    float* __restrict__ out)
{
    const int nid = blockIdx.x;
    const int d   = nid & (NN-1);
    const int gb  = nid & ~(NN-1);
    const int c   = threadIdx.x;                // 0..63
    const float ad = ald[nid];

    float accv = 0.f, accd = 0.f;
    const int e0 = roff[d], e1 = roff[d+1];
    int sn = (e0 < e1) ? col[e0] : 0;
    for (int e = e0; e < e1; ++e){
        const int s = sn + gb;
        sn = (e+1 < e1) ? col[e+1] : 0;
        float a = als[s] + ad;
        a = a > 0.f ? a : 0.2f*a;
        const float ex = __expf(a);
        accv += ex * b2f(hw2[(size_t)s*OUTCH + c]);
        accd += ex;
    }
    {   // self loop
        float a = als[nid] + ad;
        a = a > 0.f ? a : 0.2f*a;
        const float ex = __expf(a);
        accv += ex * b2f(hw2[(size_t)nid*OUTCH + c]);
        accd += ex;
    }
    __shared__ float g[OUTCH];
    g[c] = accv/accd + g2b[c];
    __syncthreads();
    if (c < OUTF){
        float o = fb[c];
        #pragma unroll
        for (int k = 0; k < OUTCH; ++k) o += g[k]*fw[k*OUTF + c];
        const int b = nid >> 11, n = nid & (NN-1);
        out[((size_t)b*OUTF + c)*NN + n] = o;
    }
}

// ---------------------------------------------------------------------------
extern "C" void kernel_launch(void* const* d_in, const int* in_sizes, int n_in,
                              void* d_out, int out_size, void* d_ws, size_t ws_size,
                              hipStream_t stream)
{
    const float* x    = (const float*)d_in[0];
    const int*  ei    = (const int*)d_in[1];
    const float* ln1g = (const float*)d_in[2];  const float* ln1b = (const float*)d_in[3];
    const float* t_wq = (const float*)d_in[4];  const float* t_bq = (const float*)d_in[5];
    const float* t_wk = (const float*)d_in[6];  const float* t_bk = (const float*)d_in[7];
    const float* t_wv = (const float*)d_in[8];  const float* t_bv = (const float*)d_in[9];
    const float* t_wo = (const float*)d_in[10]; const float* t_bo = (const float*)d_in[11];
    const float* skw  = (const float*)d_in[12]; const float* skb  = (const float*)d_in[13];
    const float* ln2g = (const float*)d_in[14]; const float* ln2b = (const float*)d_in[15];
    const float* s_wq = (const float*)d_in[16]; const float* s_bq = (const float*)d_in[17];
    const float* s_wk = (const float*)d_in[18]; const float* s_bk = (const float*)d_in[19];
    const float* s_wv = (const float*)d_in[20]; const float* s_bv = (const float*)d_in[21];
    const float* s_wo = (const float*)d_in[22]; const float* s_bo = (const float*)d_in[23];
    const float* ln3g = (const float*)d_in[24]; const float* ln3b = (const float*)d_in[25];
    const float* w1   = (const float*)d_in[26]; const float* b1   = (const float*)d_in[27];
    const float* w2   = (const float*)d_in[28]; const float* b2   = (const float*)d_in[29];
    const float* g1w  = (const float*)d_in[30];
    const float* g1as = (const float*)d_in[31]; const float* g1ad = (const float*)d_in[32];
    const float* g1b  = (const float*)d_in[33];
    const float* g2w  = (const float*)d_in[34];
    const float* g2as = (const float*)d_in[35]; const float* g2ad = (const float*)d_in[36];
    const float* g2b  = (const float*)d_in[37];
    const float* ffw  = (const float*)d_in[38]; const float* ffb  = (const float*)d_in[39];
    float* out = (float*)d_out;

    const size_t MiB = 1024u*1024u;
    const bool wide = ws_size >= 48*MiB;

    char* base = (char*)d_ws;
    bf16 *Kb, *Vtb, *CXH1;
    char* gat_base;
    if (wide){
        Kb   = (bf16*)(base + 0*MiB);      // 16 MiB
        Vtb  = (bf16*)(base + 16*MiB);     // 16 MiB
        CXH1 = (bf16*)(base + 32*MiB);     // 16 MiB
        gat_base = base;                   // aliases Kb (dead after attn)
    } else {
        CXH1 = (bf16*)(base + 0*MiB);      // 16 MiB
        gat_base = base + 16*MiB;          // no aliasing
        Kb   = (bf16*)(base + 26*MiB);     // 0.5 MiB (one slice)
        Vtb  = (bf16*)(base + 26*MiB + 512u*1024u);
    }

    // prep outputs in d_out scratch (dead until gather2f's final write;
    // out_size = 4*14*2048*4 = 458752 B >= 315.5 KB used)
    char* ob = (char*)d_out;
    bf16*  Mt   = (bf16*)(ob);                        // 32 KB
    bf16*  wvT  = (bf16*)(ob + 32*1024);              // 32 KB
    bf16*  woT  = (bf16*)(ob + 64*1024);              // 32 KB
    bf16*  g1wT = (bf16*)(ob + 96*1024);              // 32 KB
    bf16*  w1T  = (bf16*)(ob + 128*1024);             // 64 KB
    bf16*  w2T  = (bf16*)(ob + 192*1024);             // 64 KB
    float* vkw  = (float*)(ob + 256*1024);            // 512 B
    float* vqw  = (float*)(ob + 256*1024 + 512);      // 512 B
    float* sbb  = (float*)(ob + 256*1024 + 1024);     // 4 B
    bf16*  BH1  = (bf16*)(ob + 272*1024);             // 42 KB (128x168 bf16)

    // GAT scratch (aliases Kb in wide mode; all writes happen post-attn)
    char* w = gat_base;
    auto alloc = [&](size_t bytes){ void* p = (void*)w; w += (bytes + 255) & ~(size_t)255; return p; };
    int*   cnt  = (int*)  alloc(2048u*sizeof(int));
    int*   fill = (int*)  alloc(2048u*sizeof(int));   // contiguous with cnt
    int*   roff = (int*)  alloc(2049u*sizeof(int));
    int*   col  = (int*)  alloc((size_t)NEDGE*sizeof(int));
    bf16*  hw1  = (bf16*) alloc((size_t)NNODE*HID*sizeof(bf16));    // 2 MiB
    float* als1 = (float*)alloc((size_t)NNODE*NHEADS*sizeof(float));
    float* ald1 = (float*)alloc((size_t)NNODE*NHEADS*sizeof(float));
    bf16*  hw2  = (bf16*) alloc((size_t)NNODE*OUTCH*sizeof(bf16));  // 1 MiB
    float* als2 = (float*)alloc((size_t)NNODE*sizeof(float));
    float* ald2 = (float*)alloc((size_t)NNODE*sizeof(float));

    // ---- trunk ----
    k_prep<<<32, 256, 0, stream>>>(s_wq, s_wk, s_bq, s_bk, s_wv, s_wo, g1w, w1, w2,
                                   t_wo, skw,
                                   Mt, wvT, woT, g1wT, w1T, w2T, BH1,
                                   vkw, vqw, sbb);
    if (wide){
        k_kv<<<PROWS/32, 256, 0, stream>>>(x, ln1g, ln1b, t_wk, t_bk, t_wv, t_bv, 0, Kb, Vtb);
        // 1D grid: in-kernel XCD swizzle (gridDim.y==1 selects wide decode)
        k_attn_mfma<<<BM*NTILE, 256, 0, stream>>>(x, Kb, Vtb, ln1g, ln1b,
                                                  t_wq, t_bq, BH1, t_bo, skb, 0, CXH1);
    } else {
        for (int s = 0; s < BM; ++s){
            k_kv<<<NN/32, 256, 0, stream>>>(x, ln1g, ln1b, t_wk, t_bk, t_wv, t_bv, s*NN, Kb, Vtb);
            k_attn_mfma<<<dim3(1, NTILE), 256, 0, stream>>>(x, Kb, Vtb, ln1g, ln1b,
                                                            t_wq, t_bq, BH1, t_bo, skb, s, CXH1);
        }
    }

    // CSR build (cnt/fill zeroed here — their memory aliases Kb, dead now)
    hipMemsetAsync(cnt, 0, 2u*2048u*sizeof(int), stream);
    k_csr_hist   <<<NEDGE/256, 256, 0, stream>>>(ei, cnt);
    k_csr_scan   <<<1,        256, 0, stream>>>(cnt, roff);
    k_csr_scatter<<<NEDGE/256, 256, 0, stream>>>(ei, roff, fill, col);

    k_mix<<<NNODE/16, 256, 0, stream>>>(CXH1, ln2g, ln2b, Mt, wvT, woT, g1wT, w1T, w2T,
                                        vkw, vqw, sbb, s_bv, s_bo, b1, b2,
                                        ln3g, ln3b, g1as, g1ad, hw1, als1, ald1);

    k_gat_g1lin  <<<NNODE, 64, 0, stream>>>(roff, col, als1, ald1, hw1, g1b,
                                            g2w, g2as, g2ad, hw2, als2, ald2);
    k_gat_gather2f<<<NNODE, 64, 0, stream>>>(roff, col, als2, ald2, hw2, g2b, ffw, ffb, out);
}